// Round 4
// baseline (627.403 us; speedup 1.0000x reference)
//
#include <hip/hip_runtime.h>
#include <hip/hip_fp16.h>
#include <cfloat>
#include <cmath>

// GNN_Combo pipeline. Round 4: k_gemm occupancy (1024 blocks = 4/CU),
// register-prefetch pipeline, XOR-swizzled LDS (bank-conflict-free).
// N=16384 nodes, F=64 in-features, H=128 hidden, K=16 neighbors, O=10 classes.

#define N_NODES 16384
#define F_IN    64
#define H_DIM   128
#define K_NN    16
#define O_DIM   10

typedef _Float16 half8  __attribute__((ext_vector_type(8)));
typedef _Float16 half4v __attribute__((ext_vector_type(4)));
typedef float    floatx4 __attribute__((ext_vector_type(4)));

// ---------------------------------------------------------------- k_prep ----
__global__ __launch_bounds__(256) void k_prep(const float* __restrict__ x,
                                              float* __restrict__ sq,
                                              double* __restrict__ sq64,
                                              _Float16* __restrict__ xhl) {
  const int i = blockIdx.x * 256 + threadIdx.x;
  if (i >= N_NODES) return;
  const float4* r = (const float4*)(x + i * F_IN);
  float s = 0.f; double sd = 0.0;
#pragma unroll
  for (int q = 0; q < 16; ++q) {
    const float4 v = r[q];
    s += v.x*v.x + v.y*v.y + v.z*v.z + v.w*v.w;
    sd += (double)v.x*v.x + (double)v.y*v.y + (double)v.z*v.z + (double)v.w*v.w;
    half4v hi, lo;
    hi[0] = (_Float16)v.x; hi[1] = (_Float16)v.y;
    hi[2] = (_Float16)v.z; hi[3] = (_Float16)v.w;
    lo[0] = (_Float16)(v.x - (float)hi[0]); lo[1] = (_Float16)(v.y - (float)hi[1]);
    lo[2] = (_Float16)(v.z - (float)hi[2]); lo[3] = (_Float16)(v.w - (float)hi[3]);
    *(half4v*)(xhl + (size_t)i * 128 + 4 * q)      = hi;
    *(half4v*)(xhl + (size_t)i * 128 + 64 + 4 * q) = lo;
  }
  sq[i] = s; sq64[i] = sd;
}

// ---------------------------------------------------------------- k_gemm ----
// Grid: 128 rowblocks (128 rows) x 8 col-segments (2048 cols) = 1024 blocks
// (= 4 blocks/CU). Block: 256 thr / 4 waves; wave owns 32 rows (2 rowsets).
// Column tiles of 128 staged in LDS with XOR-swizzled 16-B chunks (chunk ^
// (col&15)) -> both write and read patterns are <=2-way bank aliasing (free).
// Register prefetch: tile t+1 is loaded into VGPRs while tile t computes.
// key = sq[col] - 2*dot (row-shift is rank-invariant). Phase 2 uses tau+1e-3
// margin, so phases need not be bit-identical (f16-split key err ~1e-5).
template<int PHASE>
__global__ __launch_bounds__(256, 4) void k_gemm(const _Float16* __restrict__ xhl,
                                                 const float* __restrict__ sq,
                                                 const float* __restrict__ tau,
                                                 float* __restrict__ cmins,
                                                 unsigned* __restrict__ cnt,
                                                 int* __restrict__ cand) {
  __shared__ __align__(16) _Float16 stage[128 * 128];  // 32 KB, swizzled
  __shared__ float sqs[128];
  const int tid = threadIdx.x;
  const int wv = tid >> 6, l = tid & 63;
  const int lane16 = l & 15, quad = l >> 4;
  const int rowblk = (blockIdx.x >> 3) * 128;
  const int seg = blockIdx.x & 7;
  const int rw = rowblk + wv * 32;

  half8 A[2][4];  // [rowset][kb: hi0,hi1,lo0,lo1]
#pragma unroll
  for (int s = 0; s < 2; ++s) {
    const _Float16* ap = xhl + (size_t)(rw + s * 16 + lane16) * 128 + quad * 8;
#pragma unroll
    for (int kb = 0; kb < 4; ++kb) A[s][kb] = *(const half8*)(ap + kb * 32);
  }
  float tau_r[8];
  float rmin[8];
  if (PHASE == 2) {
#pragma unroll
    for (int s = 0; s < 2; ++s)
#pragma unroll
      for (int q = 0; q < 4; ++q)
        tau_r[s * 4 + q] = tau[rw + s * 16 + quad * 4 + q] + 1e-3f;
  } else {
#pragma unroll
    for (int t = 0; t < 8; ++t) rmin[t] = FLT_MAX;
  }

  const int scol = tid >> 1, spart = tid & 1;   // staging: 2 thr/col
  half8 pref[8]; float sqpref;
#define ISSUE(tile_) { \
    const int c0_ = seg * 2048 + (tile_) * 128; \
    const _Float16* g_ = xhl + (size_t)(c0_ + scol) * 128 + spart * 64; \
    _Pragma("unroll") \
    for (int j = 0; j < 8; ++j) pref[j] = *(const half8*)(g_ + j * 8); \
    sqpref = sq[c0_ + (tid & 127)]; }

  ISSUE(0);
  for (int tile = 0; tile < 16; ++tile) {
    const int c0 = seg * 2048 + tile * 128;
    __syncthreads();
    {  // commit prefetched tile to LDS (swizzled chunk position)
      _Float16* d = stage + scol * 128;
#pragma unroll
      for (int j = 0; j < 8; ++j)
        *(half8*)(d + (((spart * 8 + j) ^ (scol & 15)) * 8)) = pref[j];
      if (tid < 128) sqs[tid] = sqpref;
    }
    __syncthreads();
    if (tile < 15) ISSUE(tile + 1);
#pragma unroll 1
    for (int st = 0; st < 8; ++st) {
      const _Float16* base = stage + (st * 16 + lane16) * 128;
      const half8 B0 = *(const half8*)(base + (((quad + 0) ^ lane16) * 8));   // hi 0-31
      const half8 B1 = *(const half8*)(base + (((quad + 4) ^ lane16) * 8));   // hi 32-63
      const half8 B2 = *(const half8*)(base + (((quad + 8) ^ lane16) * 8));   // lo 0-31
      const half8 B3 = *(const half8*)(base + (((quad + 12) ^ lane16) * 8));  // lo 32-63
      const float sqv = sqs[st * 16 + lane16];
      floatx4 acc[2];
#pragma unroll
      for (int s = 0; s < 2; ++s) acc[s] = (floatx4)0.f;
#define MF(s, ab, bb) acc[s] = __builtin_amdgcn_mfma_f32_16x16x32_f16(A[s][ab], bb, acc[s], 0, 0, 0)
#pragma unroll
      for (int s = 0; s < 2; ++s) MF(s, 0, B0);   // hi*hi
#pragma unroll
      for (int s = 0; s < 2; ++s) MF(s, 1, B1);
#pragma unroll
      for (int s = 0; s < 2; ++s) MF(s, 2, B0);   // lo*hi
#pragma unroll
      for (int s = 0; s < 2; ++s) MF(s, 3, B1);
#pragma unroll
      for (int s = 0; s < 2; ++s) MF(s, 0, B2);   // hi*lo
#pragma unroll
      for (int s = 0; s < 2; ++s) MF(s, 1, B3);
#undef MF
      if (PHASE == 1) {
#pragma unroll
        for (int s = 0; s < 2; ++s)
#pragma unroll
          for (int q = 0; q < 4; ++q)
            rmin[s * 4 + q] = fminf(rmin[s * 4 + q], fmaf(-2.f, acc[s][q], sqv));
      } else {
        const int colb = c0 + st * 16 + lane16;
#pragma unroll
        for (int s = 0; s < 2; ++s) {
          const float k0 = fmaf(-2.f, acc[s][0], sqv);
          const float k1 = fmaf(-2.f, acc[s][1], sqv);
          const float k2 = fmaf(-2.f, acc[s][2], sqv);
          const float k3 = fmaf(-2.f, acc[s][3], sqv);
          const float d01 = fminf(k0 - tau_r[s * 4 + 0], k1 - tau_r[s * 4 + 1]);
          const float d23 = fminf(k2 - tau_r[s * 4 + 2], k3 - tau_r[s * 4 + 3]);
          if (__ballot(fminf(d01, d23) <= 0.f)) {
            const int rbase = rw + s * 16 + quad * 4;
            if (k0 <= tau_r[s * 4 + 0]) {
              const unsigned pos = atomicAdd(&cnt[rbase + 0], 1u);
              if (pos < 128u) cand[(size_t)(rbase + 0) * 128 + pos] = colb;
            }
            if (k1 <= tau_r[s * 4 + 1]) {
              const unsigned pos = atomicAdd(&cnt[rbase + 1], 1u);
              if (pos < 128u) cand[(size_t)(rbase + 1) * 128 + pos] = colb;
            }
            if (k2 <= tau_r[s * 4 + 2]) {
              const unsigned pos = atomicAdd(&cnt[rbase + 2], 1u);
              if (pos < 128u) cand[(size_t)(rbase + 2) * 128 + pos] = colb;
            }
            if (k3 <= tau_r[s * 4 + 3]) {
              const unsigned pos = atomicAdd(&cnt[rbase + 3], 1u);
              if (pos < 128u) cand[(size_t)(rbase + 3) * 128 + pos] = colb;
            }
          }
        }
      }
    }
    if (PHASE == 1 && (tile & 3) == 3) {   // chunk boundary (512 cols)
#pragma unroll
      for (int t = 0; t < 8; ++t) {
#pragma unroll
        for (int d = 1; d < 16; d <<= 1)
          rmin[t] = fminf(rmin[t], __shfl_xor(rmin[t], d, 64));
      }
      const int chunk = seg * 4 + (tile >> 2);
      float v = rmin[0];
#pragma unroll
      for (int t = 1; t < 8; ++t) if (lane16 == t) v = rmin[t];
      if (lane16 < 8) {
        const int row = rw + (lane16 >> 2) * 16 + quad * 4 + (lane16 & 3);
        cmins[(size_t)row * 32 + chunk] = v;
      }
#pragma unroll
      for (int t = 0; t < 8; ++t) rmin[t] = FLT_MAX;
    }
  }
#undef ISSUE
}

// ----------------------------------------------------------------- k_tau ----
__global__ __launch_bounds__(256) void k_tau(const float* __restrict__ cmins,
                                             float* __restrict__ tau,
                                             unsigned* __restrict__ cnt) {
  const int r = blockIdx.x * 256 + threadIdx.x;
  if (r >= N_NODES) return;
  float v[32];
#pragma unroll
  for (int j = 0; j < 32; ++j) v[j] = cmins[(size_t)r * 32 + j];
  float t16 = FLT_MAX;
#pragma unroll 1
  for (int j = 0; j < 32; ++j) {
    int rk = 0;
#pragma unroll
    for (int m = 0; m < 32; ++m)
      rk += (v[m] < v[j]) || (v[m] == v[j] && m < j);
    if (rk == 15) t16 = v[j];
  }
  tau[r] = t16;
  cnt[r] = 0;
}

// ------------------------------------------------------------- k_rescore ----
__global__ __launch_bounds__(128) void k_rescore(const float* __restrict__ x,
                                                 const double* __restrict__ sq64,
                                                 const int* __restrict__ cand,
                                                 const unsigned* __restrict__ cnt,
                                                 int* __restrict__ knn) {
  __shared__ float  xi[F_IN];
  __shared__ double keys[128];
  __shared__ int    ids[128];
  const int i = blockIdx.x, t = threadIdx.x;
  const unsigned c = cnt[i];
  const int n = (int)(c < 128u ? c : 128u);
  if (t < F_IN) xi[t] = x[i * F_IN + t];
  __syncthreads();
  double key = 1e300; int id = 0x7fffffff;
  if (t < n) {
    id = cand[(size_t)i * 128 + t];
    const float4* xc4 = (const float4*)(x + (size_t)id * F_IN);
    double d0 = 0.0, d1 = 0.0, d2 = 0.0, d3 = 0.0;
#pragma unroll
    for (int q = 0; q < 16; ++q) {
      const float4 v = xc4[q];
      d0 += (double)xi[4*q+0] * (double)v.x;
      d1 += (double)xi[4*q+1] * (double)v.y;
      d2 += (double)xi[4*q+2] * (double)v.z;
      d3 += (double)xi[4*q+3] * (double)v.w;
    }
    key = sq64[id] - 2.0 * ((d0 + d1) + (d2 + d3));
  }
  keys[t] = key; ids[t] = id;
  __syncthreads();
  int rank = 0;
#pragma unroll 4
  for (int cix = 0; cix < 128; ++cix) {
    const double kc = keys[cix]; const int ic = ids[cix];
    rank += (kc < key) || (kc == key && ic < id);
  }
  if (t < n && rank < K_NN) knn[i * K_NN + rank] = id;
}

// --------------------------------------------------------------- k_lin12 ----
__global__ __launch_bounds__(256, 2) void k_lin12(const float* __restrict__ x,
                                                  const float* __restrict__ w1,
                                                  const float* __restrict__ b1,
                                                  float* __restrict__ P,
                                                  float* __restrict__ Q) {
  __shared__ float wl[2 * F_IN][H_DIM];   // 64 KB
  for (int s = threadIdx.x; s < 2 * F_IN * H_DIM; s += 256) wl[s >> 7][s & 127] = w1[s];
  __syncthreads();
  const int node = blockIdx.x * 32 + (threadIdx.x & 31);
  const int ob = (threadIdx.x >> 5) * 16;   // 8 groups x 16 outs
  float accR[16], accQ[16];
#pragma unroll
  for (int o = 0; o < 16; ++o) { accR[o] = 0.f; accQ[o] = 0.f; }
  const float4* xr = (const float4*)(x + node * F_IN);
#define L1STEP(ff, xs) { \
    const float* wt_ = &wl[(ff)][ob]; \
    const float* wb_ = &wl[(ff) + F_IN][ob]; \
    _Pragma("unroll") \
    for (int o = 0; o < 16; o += 4) { \
      const float4 t4 = *(const float4*)(wt_ + o); \
      const float4 b4 = *(const float4*)(wb_ + o); \
      accR[o+0] = fmaf((xs), t4.x, accR[o+0]); accQ[o+0] = fmaf((xs), b4.x, accQ[o+0]); \
      accR[o+1] = fmaf((xs), t4.y, accR[o+1]); accQ[o+1] = fmaf((xs), b4.y, accQ[o+1]); \
      accR[o+2] = fmaf((xs), t4.z, accR[o+2]); accQ[o+2] = fmaf((xs), b4.z, accQ[o+2]); \
      accR[o+3] = fmaf((xs), t4.w, accR[o+3]); accQ[o+3] = fmaf((xs), b4.w, accQ[o+3]); } }
#pragma unroll 2
  for (int q = 0; q < 16; ++q) {
    const float4 xv = xr[q];
    L1STEP(4*q+0, xv.x); L1STEP(4*q+1, xv.y); L1STEP(4*q+2, xv.z); L1STEP(4*q+3, xv.w);
  }
#undef L1STEP
  float* pp = P + node * H_DIM + ob;
  float* qp = Q + node * H_DIM + ob;
#pragma unroll
  for (int o = 0; o < 16; ++o) {
    pp[o] = accR[o] - accQ[o] + b1[ob + o];
    qp[o] = accQ[o];
  }
}

// ------------------------------------------------------------ k_edgeconv ----
// Wave-per-node (8 nodes/wave, 32/block). W2^T staged once per block as f16
// with XOR-swizzled 16-B chunks (conflict-free). Per node: build A=relu(P+Q)
// in f16 in A-fragment order in per-wave LDS; 8 N-tiles x 4 K-blocks of
// mfma_f32_16x16x32_f16; +b2; log_softmax rows; max over 16 rows.
__global__ __launch_bounds__(256, 3) void k_edgeconv(const float* __restrict__ P,
                                                     const float* __restrict__ Q,
                                                     const float* __restrict__ w2,
                                                     const float* __restrict__ b2,
                                                     const int* __restrict__ knn,
                                                     float* __restrict__ h) {
  __shared__ __align__(16) _Float16 wt[H_DIM * 128];   // 32 KB, swizzled
  __shared__ __align__(16) _Float16 afr[4][2048];      // 16 KB, per-wave A frags
  const int tid = threadIdx.x;
  const int wv = tid >> 6, l = tid & 63;
  const int lane16 = l & 15, quad = l >> 4;

  {  // stage W2^T as f16 (swizzled chunk position)
    const int n = tid >> 1, part = tid & 1;
    const float* wsrc = w2 + n;
    _Float16* wdst = wt + n * 128;
#pragma unroll
    for (int c = 0; c < 8; ++c) {
      half8 hv;
#pragma unroll
      for (int u = 0; u < 8; ++u)
        hv[u] = (_Float16)wsrc[(size_t)(part * 64 + c * 8 + u) * H_DIM];
      *(half8*)(wdst + (((part * 8 + c) ^ (n & 15)) * 8)) = hv;
    }
  }
  __syncthreads();

  float b2r[8];
#pragma unroll
  for (int tile = 0; tile < 8; ++tile) b2r[tile] = b2[tile * 16 + lane16];

  _Float16* aw = afr[wv];
  for (int it = 0; it < 8; ++it) {
    const int i = blockIdx.x * 32 + wv * 8 + it;
    // ---- build A = relu(P_i + Q_j) in fragment order ----
    {
      const int m = lane16, kq = quad;          // lane: message m, k-chunk kq*32
      const int j = knn[i * K_NN + m];
      const float4* pq = (const float4*)(P + (size_t)i * H_DIM + kq * 32);
      const float4* qq = (const float4*)(Q + (size_t)j * H_DIM + kq * 32);
#pragma unroll
      for (int c = 0; c < 4; ++c) {
        const float4 pa = pq[2 * c],     qa = qq[2 * c];
        const float4 pb = pq[2 * c + 1], qb = qq[2 * c + 1];
        half8 hv;
        hv[0] = (_Float16)fmaxf(pa.x + qa.x, 0.f);
        hv[1] = (_Float16)fmaxf(pa.y + qa.y, 0.f);
        hv[2] = (_Float16)fmaxf(pa.z + qa.z, 0.f);
        hv[3] = (_Float16)fmaxf(pa.w + qa.w, 0.f);
        hv[4] = (_Float16)fmaxf(pb.x + qb.x, 0.f);
        hv[5] = (_Float16)fmaxf(pb.y + qb.y, 0.f);
        hv[6] = (_Float16)fmaxf(pb.z + qb.z, 0.f);
        hv[7] = (_Float16)fmaxf(pb.w + qb.w, 0.f);
        *(half8*)(aw + kq * 512 + c * 128 + m * 8) = hv;
      }
    }
    // ---- A-fragment loads (wave-internal LDS dep) ----
    half8 A[4];
#pragma unroll
    for (int kb = 0; kb < 4; ++kb) A[kb] = *(const half8*)(aw + kb * 512 + l * 8);
    // ---- 8 N-tiles x 4 K-blocks MFMA ----
    floatx4 acc[8];
#pragma unroll
    for (int tile = 0; tile < 8; ++tile) acc[tile] = (floatx4)0.f;
#pragma unroll
    for (int kb = 0; kb < 4; ++kb) {
#pragma unroll
      for (int tile = 0; tile < 8; ++tile) {
        const half8 B = *(const half8*)(wt + (tile * 16 + lane16) * 128 +
                                        (((kb * 4 + quad) ^ lane16) * 8));
        acc[tile] = __builtin_amdgcn_mfma_f32_16x16x32_f16(A[kb], B, acc[tile], 0, 0, 0);
      }
    }
    // ---- epilogue: +b2, per-row log_softmax, max over 16 rows ----
    float lse[4];
#pragma unroll
    for (int r = 0; r < 4; ++r) {
      float mx = acc[0][r] + b2r[0];
#pragma unroll
      for (int tile = 1; tile < 8; ++tile) mx = fmaxf(mx, acc[tile][r] + b2r[tile]);
      mx = fmaxf(mx, __shfl_xor(mx, 1, 64));
      mx = fmaxf(mx, __shfl_xor(mx, 2, 64));
      mx = fmaxf(mx, __shfl_xor(mx, 4, 64));
      mx = fmaxf(mx, __shfl_xor(mx, 8, 64));
      float e = 0.f;
#pragma unroll
      for (int tile = 0; tile < 8; ++tile) e += __expf(acc[tile][r] + b2r[tile] - mx);
      e += __shfl_xor(e, 1, 64);
      e += __shfl_xor(e, 2, 64);
      e += __shfl_xor(e, 4, 64);
      e += __shfl_xor(e, 8, 64);
      lse[r] = mx + __logf(e);
    }
#pragma unroll
    for (int tile = 0; tile < 8; ++tile) {
      float v = acc[tile][0] + b2r[tile] - lse[0];
#pragma unroll
      for (int r = 1; r < 4; ++r) v = fmaxf(v, acc[tile][r] + b2r[tile] - lse[r]);
      v = fmaxf(v, __shfl_xor(v, 16, 64));
      v = fmaxf(v, __shfl_xor(v, 32, 64));
      if (quad == 0) h[(size_t)i * H_DIM + tile * 16 + lane16] = v;
    }
  }
}

// ----------------------------------------------------------------- k_hw -----
__global__ __launch_bounds__(256) void k_hw(const float* __restrict__ h,
                                            const float* __restrict__ gw,
                                            float* __restrict__ hw) {
  __shared__ float wl[H_DIM][H_DIM];   // 64 KB
  for (int s = threadIdx.x; s < H_DIM * H_DIM; s += 256) wl[s >> 7][s & 127] = gw[s];
  __syncthreads();
  const int node = blockIdx.x * 32 + (threadIdx.x & 31);
  const int ob = (threadIdx.x >> 5) * 16;
  float acc[16];
#pragma unroll
  for (int o = 0; o < 16; ++o) acc[o] = 0.f;
  const float4* hr = (const float4*)(h + node * H_DIM);
#define HWSTEP(ff, xs) { \
    const float* wr = &wl[(ff)][ob]; \
    _Pragma("unroll") \
    for (int o = 0; o < 16; o += 4) { const float4 w4 = *(const float4*)(wr + o); \
      acc[o+0] = fmaf((xs), w4.x, acc[o+0]); \
      acc[o+1] = fmaf((xs), w4.y, acc[o+1]); \
      acc[o+2] = fmaf((xs), w4.z, acc[o+2]); \
      acc[o+3] = fmaf((xs), w4.w, acc[o+3]); } }
#pragma unroll 2
  for (int q = 0; q < 32; ++q) {
    const float4 hv = hr[q];
    HWSTEP(4*q+0, hv.x); HWSTEP(4*q+1, hv.y); HWSTEP(4*q+2, hv.z); HWSTEP(4*q+3, hv.w);
  }
#undef HWSTEP
  float* dp = hw + node * H_DIM + ob;
#pragma unroll
  for (int o = 0; o < 16; ++o) dp[o] = acc[o];
}

// --------------------------------------------------------------- k_heads ----
__global__ __launch_bounds__(256) void k_heads(const float* __restrict__ hw,
                                               const int* __restrict__ knn,
                                               const float* __restrict__ gb,
                                               const float* __restrict__ gow,
                                               const float* __restrict__ gob,
                                               const float* __restrict__ ow,
                                               const float* __restrict__ obv,
                                               float* __restrict__ out) {
  __shared__ unsigned int wgo[H_DIM][64];  // 32 KB
  __shared__ float hbuf[4][H_DIM];         // 2 KB
  for (int s = threadIdx.x; s < H_DIM * 64; s += 256) {
    const int f = s >> 6, l = s & 63;
    const unsigned short u0 = __half_as_ushort(__float2half(gow[f * H_DIM + l]));
    const unsigned short u1 = __half_as_ushort(__float2half(gow[f * H_DIM + 64 + l]));
    wgo[f][l] = (unsigned int)u0 | ((unsigned int)u1 << 16);
  }
  __syncthreads();
  const int wv = threadIdx.x >> 6, l = threadIdx.x & 63;
  const float gbl = gb[l], gbh = gb[64 + l];
  const float gobl = gob[l], gobh = gob[64 + l];
  for (int it = 0; it < 8; ++it) {
    const int i = blockIdx.x * 32 + wv * 8 + it;
    const int* kr = knn + i * K_NN;
    float s0 = hw[i * H_DIM + l], s1 = hw[i * H_DIM + 64 + l];  // explicit self-loop
#pragma unroll
    for (int m = 0; m < K_NN; ++m) {
      const int j = kr[m];
      s0 += hw[j * H_DIM + l];
      s1 += hw[j * H_DIM + 64 + l];
    }
    // deg == k+1 == 17 for every node by construction -> norm == 1/17
    const float hg0 = s0 * (1.0f / 17.0f) + gbl;
    const float hg1 = s1 * (1.0f / 17.0f) + gbh;
    __syncthreads();
    hbuf[wv][l] = hg0; hbuf[wv][64 + l] = hg1;
    __syncthreads();
    float z0 = gobl, z1 = gobh;
#pragma unroll 4
    for (int f = 0; f < H_DIM; ++f) {
      const float hv = hbuf[wv][f];
      const unsigned int wvv = wgo[f][l];
      const float w0 = __half2float(__ushort_as_half((unsigned short)(wvv & 0xffffu)));
      const float w1 = __half2float(__ushort_as_half((unsigned short)(wvv >> 16)));
      z0 = fmaf(hv, w0, z0);
      z1 = fmaf(hv, w1, z1);
    }
    float mx = fmaxf(z0, z1);
#pragma unroll
    for (int s = 1; s < 64; s <<= 1) mx = fmaxf(mx, __shfl_xor(mx, s, 64));
    const float e0 = __expf(z0 - mx), e1 = __expf(z1 - mx);
    float sm = e0 + e1;
#pragma unroll
    for (int s = 1; s < 64; s <<= 1) sm += __shfl_xor(sm, s, 64);
    const float h20 = e0 / sm, h21 = e1 / sm;
    float zc[O_DIM];
#pragma unroll
    for (int c = 0; c < O_DIM; ++c) {
      float a = h20 * ow[l * O_DIM + c] + h21 * ow[(64 + l) * O_DIM + c];
#pragma unroll
      for (int s = 1; s < 64; s <<= 1) a += __shfl_xor(a, s, 64);
      zc[c] = a + obv[c];
    }
    float m10 = zc[0];
#pragma unroll
    for (int c = 1; c < O_DIM; ++c) m10 = fmaxf(m10, zc[c]);
    float es[O_DIM]; float s10 = 0.f;
#pragma unroll
    for (int c = 0; c < O_DIM; ++c) { es[c] = __expf(zc[c] - m10); s10 += es[c]; }
    const float inv = 1.0f / s10;
    if (l < O_DIM) {
      float v = es[0];
#pragma unroll
      for (int c = 1; c < O_DIM; ++c) if (l == c) v = es[c];
      out[i * O_DIM + l] = v * inv;
    }
  }
}

// ---------------------------------------------------------------------------
extern "C" void kernel_launch(void* const* d_in, const int* in_sizes, int n_in,
                              void* d_out, int out_size, void* d_ws, size_t ws_size,
                              hipStream_t stream) {
  (void)in_sizes; (void)n_in; (void)out_size; (void)ws_size;
  const float* x   = (const float*)d_in[0];
  const float* w1  = (const float*)d_in[2];
  const float* b1  = (const float*)d_in[3];
  const float* w2  = (const float*)d_in[4];
  const float* b2  = (const float*)d_in[5];
  const float* gw  = (const float*)d_in[6];
  const float* gb  = (const float*)d_in[7];
  const float* gow = (const float*)d_in[8];
  const float* gob = (const float*)d_in[9];
  const float* ow  = (const float*)d_in[10];
  const float* obv = (const float*)d_in[11];
  float* out = (float*)d_out;

  char* ws = (char*)d_ws;
  constexpr size_t OFF_SQ   = 0;                                          // 64 KB
  constexpr size_t OFF_SQ64 = OFF_SQ   + (size_t)N_NODES * 4;             // 128 KB
  constexpr size_t OFF_XHL  = OFF_SQ64 + (size_t)N_NODES * 8;             // 4 MB
  constexpr size_t OFF_CMIN = OFF_XHL  + (size_t)N_NODES * 128 * 2;       // 2 MB
  constexpr size_t OFF_TAU  = OFF_CMIN + (size_t)N_NODES * 32 * 4;        // 64 KB
  constexpr size_t OFF_CNT  = OFF_TAU  + (size_t)N_NODES * 4;             // 64 KB
  constexpr size_t OFF_CAND = OFF_CNT  + (size_t)N_NODES * 4;             // 8 MB
  constexpr size_t OFF_KNN  = OFF_CAND + (size_t)N_NODES * 128 * 4;       // 1 MB
  constexpr size_t OFF_Q    = OFF_KNN  + (size_t)N_NODES * K_NN * 4;      // 8 MB
  constexpr size_t OFF_H    = OFF_Q    + (size_t)N_NODES * H_DIM * 4;     // 8 MB
  float*     sq   = (float*)    (ws + OFF_SQ);
  double*    sq64 = (double*)   (ws + OFF_SQ64);
  _Float16*  xhl  = (_Float16*) (ws + OFF_XHL);
  float*     cmin = (float*)    (ws + OFF_CMIN);
  float*     tau  = (float*)    (ws + OFF_TAU);
  unsigned*  cnt  = (unsigned*) (ws + OFF_CNT);
  int*       cand = (int*)      (ws + OFF_CAND);
  int*       knn  = (int*)      (ws + OFF_KNN);
  float*     Q    = (float*)    (ws + OFF_Q);
  float*     h    = (float*)    (ws + OFF_H);
  float*     P    = (float*)    (ws + OFF_CAND);  // P aliases cand (dead after rescore)
  float*     hw   = P;                            // hw aliases P (dead after edgeconv)

  k_prep    <<<N_NODES / 256, 256, 0, stream>>>(x, sq, sq64, xhl);
  k_gemm<1> <<<1024,          256, 0, stream>>>(xhl, sq, tau, cmin, cnt, cand);
  k_tau     <<<N_NODES / 256, 256, 0, stream>>>(cmin, tau, cnt);
  k_gemm<2> <<<1024,          256, 0, stream>>>(xhl, sq, tau, cmin, cnt, cand);
  k_rescore <<<N_NODES,       128, 0, stream>>>(x, sq64, cand, cnt, knn);
  k_lin12   <<<N_NODES / 32,  256, 0, stream>>>(x, w1, b1, P, Q);
  k_edgeconv<<<N_NODES / 32,  256, 0, stream>>>(P, Q, w2, b2, knn, h);
  k_hw      <<<N_NODES / 32,  256, 0, stream>>>(h, gw, hw);
  k_heads   <<<N_NODES / 32,  256, 0, stream>>>(hw, knn, gb, gow, gob, ow, obv, out);
}

// Round 5
// 611.109 us; speedup vs baseline: 1.0267x; 1.0267x over previous
//
#include <hip/hip_runtime.h>
#include <hip/hip_fp16.h>
#include <cfloat>
#include <cmath>

// GNN_Combo pipeline. Round 5: k_gemm staging via global_load_lds (width 16,
// no VGPR round-trip -> no spills), 64 rows/wave (2x arithmetic intensity),
// 1024 blocks (16 col-segs x 64 row-blocks).
// N=16384 nodes, F=64 in-features, H=128 hidden, K=16 neighbors, O=10 classes.

#define N_NODES 16384
#define F_IN    64
#define H_DIM   128
#define K_NN    16
#define O_DIM   10

typedef _Float16 half8  __attribute__((ext_vector_type(8)));
typedef _Float16 half4v __attribute__((ext_vector_type(4)));
typedef float    floatx4 __attribute__((ext_vector_type(4)));

__device__ __forceinline__ void async_copy16(void* lds, const void* g) {
  __builtin_amdgcn_global_load_lds(
      (const __attribute__((address_space(1))) unsigned int*)g,
      (__attribute__((address_space(3))) unsigned int*)lds, 16, 0, 0);
}

// ---------------------------------------------------------------- k_prep ----
__global__ __launch_bounds__(256) void k_prep(const float* __restrict__ x,
                                              float* __restrict__ sq,
                                              double* __restrict__ sq64,
                                              _Float16* __restrict__ xhl) {
  const int i = blockIdx.x * 256 + threadIdx.x;
  if (i >= N_NODES) return;
  const float4* r = (const float4*)(x + i * F_IN);
  float s = 0.f; double sd = 0.0;
#pragma unroll
  for (int q = 0; q < 16; ++q) {
    const float4 v = r[q];
    s += v.x*v.x + v.y*v.y + v.z*v.z + v.w*v.w;
    sd += (double)v.x*v.x + (double)v.y*v.y + (double)v.z*v.z + (double)v.w*v.w;
    half4v hi, lo;
    hi[0] = (_Float16)v.x; hi[1] = (_Float16)v.y;
    hi[2] = (_Float16)v.z; hi[3] = (_Float16)v.w;
    lo[0] = (_Float16)(v.x - (float)hi[0]); lo[1] = (_Float16)(v.y - (float)hi[1]);
    lo[2] = (_Float16)(v.z - (float)hi[2]); lo[3] = (_Float16)(v.w - (float)hi[3]);
    *(half4v*)(xhl + (size_t)i * 128 + 4 * q)      = hi;
    *(half4v*)(xhl + (size_t)i * 128 + 64 + 4 * q) = lo;
  }
  sq[i] = s; sq64[i] = sd;
}

// ---------------------------------------------------------------- k_gemm ----
// Grid: 64 rowblocks (256 rows) x 16 col-segments (1024 cols) = 1024 blocks.
// Block: 256 thr / 4 waves; wave owns 64 rows (4 rowsets) -> 192 MFMA per
// 32 KB column tile staged. Staging via global_load_lds width=16: linear
// 16-B chunk c = (wv*8+q)*64 + lane holds global chunk (col=c>>4,
// kc=(c&15)^(col&15)) -> read side sees the XOR-swizzled layout
// (conflict-free per 8-lane phase), and the LDS dest is wave-uniform base +
// lane*16 as the instruction requires. No staging VGPRs -> no spills.
// key = sq[col] - 2*dot (row-shift is rank-invariant). Phase 2 uses tau+1e-3
// margin (f16-split key err ~1e-5 << margin << order-stat gaps).
template<int PHASE>
__global__ __launch_bounds__(256, 3) void k_gemm(const _Float16* __restrict__ xhl,
                                                 const float* __restrict__ sq,
                                                 const float* __restrict__ tau,
                                                 float* __restrict__ cmins,
                                                 unsigned* __restrict__ cnt,
                                                 int* __restrict__ cand) {
  __shared__ __align__(16) _Float16 stage[128 * 128];  // 32 KB, swizzled
  __shared__ float sqs[128];
  const int tid = threadIdx.x;
  const int wv = tid >> 6, l = tid & 63;
  const int lane16 = l & 15, quad = l >> 4;
  const int rowblk = (blockIdx.x >> 4) * 256;   // 64 rowblocks
  const int seg = blockIdx.x & 15;              // 16 col-segments of 1024
  const int rw = rowblk + wv * 64;

  half8 A[4][4];  // [rowset][kb: hi0,hi1,lo0,lo1]
#pragma unroll
  for (int s = 0; s < 4; ++s) {
    const _Float16* ap = xhl + (size_t)(rw + s * 16 + lane16) * 128 + quad * 8;
#pragma unroll
    for (int kb = 0; kb < 4; ++kb) A[s][kb] = *(const half8*)(ap + kb * 32);
  }
  float tau_r[16];
  float rmin[16];
  if (PHASE == 2) {
#pragma unroll
    for (int s = 0; s < 4; ++s)
#pragma unroll
      for (int q = 0; q < 4; ++q)
        tau_r[s * 4 + q] = tau[rw + s * 16 + quad * 4 + q] + 1e-3f;
  } else {
#pragma unroll
    for (int t = 0; t < 16; ++t) rmin[t] = FLT_MAX;
  }

  for (int tile = 0; tile < 8; ++tile) {
    const int c0 = seg * 1024 + tile * 128;
    __syncthreads();   // prior tile's compute done before overwrite
    if (tid < 128) sqs[tid] = sq[c0 + tid];
    {  // async staging: 8 issues/wave, 1024 B each
#pragma unroll
      for (int q = 0; q < 8; ++q) {
        const int col = (wv * 8 + q) * 4 + quad;
        const int kc  = lane16 ^ ((q & 3) * 4 + quad);
        async_copy16(stage + (wv * 8 + q) * 512,
                     xhl + (size_t)(c0 + col) * 128 + kc * 8);
      }
    }
    __syncthreads();   // drains vmcnt (global_load_lds) + lgkm
#pragma unroll 1
    for (int st = 0; st < 8; ++st) {
      const _Float16* base = stage + (st * 16 + lane16) * 128;
      const half8 B0 = *(const half8*)(base + (((quad + 0) ^ lane16) * 8));   // hi 0-31
      const half8 B1 = *(const half8*)(base + (((quad + 4) ^ lane16) * 8));   // hi 32-63
      const half8 B2 = *(const half8*)(base + (((quad + 8) ^ lane16) * 8));   // lo 0-31
      const half8 B3 = *(const half8*)(base + (((quad + 12) ^ lane16) * 8));  // lo 32-63
      const float sqv = sqs[st * 16 + lane16];
      floatx4 acc[4];
#pragma unroll
      for (int s = 0; s < 4; ++s) acc[s] = (floatx4)0.f;
#define MF(s, ab, bb) acc[s] = __builtin_amdgcn_mfma_f32_16x16x32_f16(A[s][ab], bb, acc[s], 0, 0, 0)
#pragma unroll
      for (int s = 0; s < 4; ++s) MF(s, 0, B0);   // hi*hi
#pragma unroll
      for (int s = 0; s < 4; ++s) MF(s, 1, B1);
#pragma unroll
      for (int s = 0; s < 4; ++s) MF(s, 2, B0);   // lo*hi
#pragma unroll
      for (int s = 0; s < 4; ++s) MF(s, 3, B1);
#pragma unroll
      for (int s = 0; s < 4; ++s) MF(s, 0, B2);   // hi*lo
#pragma unroll
      for (int s = 0; s < 4; ++s) MF(s, 1, B3);
#undef MF
      if (PHASE == 1) {
#pragma unroll
        for (int s = 0; s < 4; ++s)
#pragma unroll
          for (int q = 0; q < 4; ++q)
            rmin[s * 4 + q] = fminf(rmin[s * 4 + q], fmaf(-2.f, acc[s][q], sqv));
      } else {
        const int colb = c0 + st * 16 + lane16;
#pragma unroll
        for (int s = 0; s < 4; ++s) {
          const float k0 = fmaf(-2.f, acc[s][0], sqv);
          const float k1 = fmaf(-2.f, acc[s][1], sqv);
          const float k2 = fmaf(-2.f, acc[s][2], sqv);
          const float k3 = fmaf(-2.f, acc[s][3], sqv);
          const float d01 = fminf(k0 - tau_r[s * 4 + 0], k1 - tau_r[s * 4 + 1]);
          const float d23 = fminf(k2 - tau_r[s * 4 + 2], k3 - tau_r[s * 4 + 3]);
          if (__ballot(fminf(d01, d23) <= 0.f)) {
            const int rbase = rw + s * 16 + quad * 4;
            if (k0 <= tau_r[s * 4 + 0]) {
              const unsigned pos = atomicAdd(&cnt[rbase + 0], 1u);
              if (pos < 128u) cand[(size_t)(rbase + 0) * 128 + pos] = colb;
            }
            if (k1 <= tau_r[s * 4 + 1]) {
              const unsigned pos = atomicAdd(&cnt[rbase + 1], 1u);
              if (pos < 128u) cand[(size_t)(rbase + 1) * 128 + pos] = colb;
            }
            if (k2 <= tau_r[s * 4 + 2]) {
              const unsigned pos = atomicAdd(&cnt[rbase + 2], 1u);
              if (pos < 128u) cand[(size_t)(rbase + 2) * 128 + pos] = colb;
            }
            if (k3 <= tau_r[s * 4 + 3]) {
              const unsigned pos = atomicAdd(&cnt[rbase + 3], 1u);
              if (pos < 128u) cand[(size_t)(rbase + 3) * 128 + pos] = colb;
            }
          }
        }
      }
    }
    if (PHASE == 1 && (tile & 3) == 3) {   // chunk boundary (512 cols)
#pragma unroll
      for (int t = 0; t < 16; ++t) {
#pragma unroll
        for (int d = 1; d < 16; d <<= 1)
          rmin[t] = fminf(rmin[t], __shfl_xor(rmin[t], d, 64));
      }
      const int chunk = seg * 2 + (tile >> 2);
      float v = rmin[0];
#pragma unroll
      for (int t = 1; t < 16; ++t) if (lane16 == t) v = rmin[t];
      const int row = rw + (lane16 >> 2) * 16 + quad * 4 + (lane16 & 3);
      cmins[(size_t)row * 32 + chunk] = v;
#pragma unroll
      for (int t = 0; t < 16; ++t) rmin[t] = FLT_MAX;
    }
  }
}

// ----------------------------------------------------------------- k_tau ----
__global__ __launch_bounds__(256) void k_tau(const float* __restrict__ cmins,
                                             float* __restrict__ tau,
                                             unsigned* __restrict__ cnt) {
  const int r = blockIdx.x * 256 + threadIdx.x;
  if (r >= N_NODES) return;
  float v[32];
#pragma unroll
  for (int j = 0; j < 32; ++j) v[j] = cmins[(size_t)r * 32 + j];
  float t16 = FLT_MAX;
#pragma unroll 1
  for (int j = 0; j < 32; ++j) {
    int rk = 0;
#pragma unroll
    for (int m = 0; m < 32; ++m)
      rk += (v[m] < v[j]) || (v[m] == v[j] && m < j);
    if (rk == 15) t16 = v[j];
  }
  tau[r] = t16;
  cnt[r] = 0;
}

// ------------------------------------------------------------- k_rescore ----
__global__ __launch_bounds__(128) void k_rescore(const float* __restrict__ x,
                                                 const double* __restrict__ sq64,
                                                 const int* __restrict__ cand,
                                                 const unsigned* __restrict__ cnt,
                                                 int* __restrict__ knn) {
  __shared__ float  xi[F_IN];
  __shared__ double keys[128];
  __shared__ int    ids[128];
  const int i = blockIdx.x, t = threadIdx.x;
  const unsigned c = cnt[i];
  const int n = (int)(c < 128u ? c : 128u);
  if (t < F_IN) xi[t] = x[i * F_IN + t];
  __syncthreads();
  double key = 1e300; int id = 0x7fffffff;
  if (t < n) {
    id = cand[(size_t)i * 128 + t];
    const float4* xc4 = (const float4*)(x + (size_t)id * F_IN);
    double d0 = 0.0, d1 = 0.0, d2 = 0.0, d3 = 0.0;
#pragma unroll
    for (int q = 0; q < 16; ++q) {
      const float4 v = xc4[q];
      d0 += (double)xi[4*q+0] * (double)v.x;
      d1 += (double)xi[4*q+1] * (double)v.y;
      d2 += (double)xi[4*q+2] * (double)v.z;
      d3 += (double)xi[4*q+3] * (double)v.w;
    }
    key = sq64[id] - 2.0 * ((d0 + d1) + (d2 + d3));
  }
  keys[t] = key; ids[t] = id;
  __syncthreads();
  int rank = 0;
#pragma unroll 4
  for (int cix = 0; cix < 128; ++cix) {
    const double kc = keys[cix]; const int ic = ids[cix];
    rank += (kc < key) || (kc == key && ic < id);
  }
  if (t < n && rank < K_NN) knn[i * K_NN + rank] = id;
}

// --------------------------------------------------------------- k_lin12 ----
__global__ __launch_bounds__(256, 2) void k_lin12(const float* __restrict__ x,
                                                  const float* __restrict__ w1,
                                                  const float* __restrict__ b1,
                                                  float* __restrict__ P,
                                                  float* __restrict__ Q) {
  __shared__ float wl[2 * F_IN][H_DIM];   // 64 KB
  for (int s = threadIdx.x; s < 2 * F_IN * H_DIM; s += 256) wl[s >> 7][s & 127] = w1[s];
  __syncthreads();
  const int node = blockIdx.x * 32 + (threadIdx.x & 31);
  const int ob = (threadIdx.x >> 5) * 16;   // 8 groups x 16 outs
  float accR[16], accQ[16];
#pragma unroll
  for (int o = 0; o < 16; ++o) { accR[o] = 0.f; accQ[o] = 0.f; }
  const float4* xr = (const float4*)(x + node * F_IN);
#define L1STEP(ff, xs) { \
    const float* wt_ = &wl[(ff)][ob]; \
    const float* wb_ = &wl[(ff) + F_IN][ob]; \
    _Pragma("unroll") \
    for (int o = 0; o < 16; o += 4) { \
      const float4 t4 = *(const float4*)(wt_ + o); \
      const float4 b4 = *(const float4*)(wb_ + o); \
      accR[o+0] = fmaf((xs), t4.x, accR[o+0]); accQ[o+0] = fmaf((xs), b4.x, accQ[o+0]); \
      accR[o+1] = fmaf((xs), t4.y, accR[o+1]); accQ[o+1] = fmaf((xs), b4.y, accQ[o+1]); \
      accR[o+2] = fmaf((xs), t4.z, accR[o+2]); accQ[o+2] = fmaf((xs), b4.z, accQ[o+2]); \
      accR[o+3] = fmaf((xs), t4.w, accR[o+3]); accQ[o+3] = fmaf((xs), b4.w, accQ[o+3]); } }
#pragma unroll 2
  for (int q = 0; q < 16; ++q) {
    const float4 xv = xr[q];
    L1STEP(4*q+0, xv.x); L1STEP(4*q+1, xv.y); L1STEP(4*q+2, xv.z); L1STEP(4*q+3, xv.w);
  }
#undef L1STEP
  float* pp = P + node * H_DIM + ob;
  float* qp = Q + node * H_DIM + ob;
#pragma unroll
  for (int o = 0; o < 16; ++o) {
    pp[o] = accR[o] - accQ[o] + b1[ob + o];
    qp[o] = accQ[o];
  }
}

// ------------------------------------------------------------ k_edgeconv ----
__global__ __launch_bounds__(256, 3) void k_edgeconv(const float* __restrict__ P,
                                                     const float* __restrict__ Q,
                                                     const float* __restrict__ w2,
                                                     const float* __restrict__ b2,
                                                     const int* __restrict__ knn,
                                                     float* __restrict__ h) {
  __shared__ __align__(16) _Float16 wt[H_DIM * 128];   // 32 KB, swizzled
  __shared__ __align__(16) _Float16 afr[4][2048];      // 16 KB, per-wave A frags
  const int tid = threadIdx.x;
  const int wv = tid >> 6, l = tid & 63;
  const int lane16 = l & 15, quad = l >> 4;

  {  // stage W2^T as f16 (swizzled chunk position)
    const int n = tid >> 1, part = tid & 1;
    const float* wsrc = w2 + n;
    _Float16* wdst = wt + n * 128;
#pragma unroll
    for (int c = 0; c < 8; ++c) {
      half8 hv;
#pragma unroll
      for (int u = 0; u < 8; ++u)
        hv[u] = (_Float16)wsrc[(size_t)(part * 64 + c * 8 + u) * H_DIM];
      *(half8*)(wdst + (((part * 8 + c) ^ (n & 15)) * 8)) = hv;
    }
  }
  __syncthreads();

  float b2r[8];
#pragma unroll
  for (int tile = 0; tile < 8; ++tile) b2r[tile] = b2[tile * 16 + lane16];

  _Float16* aw = afr[wv];
  for (int it = 0; it < 8; ++it) {
    const int i = blockIdx.x * 32 + wv * 8 + it;
    // ---- build A = relu(P_i + Q_j) in fragment order ----
    {
      const int m = lane16, kq = quad;          // lane: message m, k-chunk kq*32
      const int j = knn[i * K_NN + m];
      const float4* pq = (const float4*)(P + (size_t)i * H_DIM + kq * 32);
      const float4* qq = (const float4*)(Q + (size_t)j * H_DIM + kq * 32);
#pragma unroll
      for (int c = 0; c < 4; ++c) {
        const float4 pa = pq[2 * c],     qa = qq[2 * c];
        const float4 pb = pq[2 * c + 1], qb = qq[2 * c + 1];
        half8 hv;
        hv[0] = (_Float16)fmaxf(pa.x + qa.x, 0.f);
        hv[1] = (_Float16)fmaxf(pa.y + qa.y, 0.f);
        hv[2] = (_Float16)fmaxf(pa.z + qa.z, 0.f);
        hv[3] = (_Float16)fmaxf(pa.w + qa.w, 0.f);
        hv[4] = (_Float16)fmaxf(pb.x + qb.x, 0.f);
        hv[5] = (_Float16)fmaxf(pb.y + qb.y, 0.f);
        hv[6] = (_Float16)fmaxf(pb.z + qb.z, 0.f);
        hv[7] = (_Float16)fmaxf(pb.w + qb.w, 0.f);
        *(half8*)(aw + kq * 512 + c * 128 + m * 8) = hv;
      }
    }
    // ---- A-fragment loads (wave-internal LDS dep) ----
    half8 A[4];
#pragma unroll
    for (int kb = 0; kb < 4; ++kb) A[kb] = *(const half8*)(aw + kb * 512 + l * 8);
    // ---- 8 N-tiles x 4 K-blocks MFMA ----
    floatx4 acc[8];
#pragma unroll
    for (int tile = 0; tile < 8; ++tile) acc[tile] = (floatx4)0.f;
#pragma unroll
    for (int kb = 0; kb < 4; ++kb) {
#pragma unroll
      for (int tile = 0; tile < 8; ++tile) {
        const half8 B = *(const half8*)(wt + (tile * 16 + lane16) * 128 +
                                        (((kb * 4 + quad) ^ lane16) * 8));
        acc[tile] = __builtin_amdgcn_mfma_f32_16x16x32_f16(A[kb], B, acc[tile], 0, 0, 0);
      }
    }
    // ---- epilogue: +b2, per-row log_softmax, max over 16 rows ----
    float lse[4];
#pragma unroll
    for (int r = 0; r < 4; ++r) {
      float mx = acc[0][r] + b2r[0];
#pragma unroll
      for (int tile = 1; tile < 8; ++tile) mx = fmaxf(mx, acc[tile][r] + b2r[tile]);
      mx = fmaxf(mx, __shfl_xor(mx, 1, 64));
      mx = fmaxf(mx, __shfl_xor(mx, 2, 64));
      mx = fmaxf(mx, __shfl_xor(mx, 4, 64));
      mx = fmaxf(mx, __shfl_xor(mx, 8, 64));
      float e = 0.f;
#pragma unroll
      for (int tile = 0; tile < 8; ++tile) e += __expf(acc[tile][r] + b2r[tile] - mx);
      e += __shfl_xor(e, 1, 64);
      e += __shfl_xor(e, 2, 64);
      e += __shfl_xor(e, 4, 64);
      e += __shfl_xor(e, 8, 64);
      lse[r] = mx + __logf(e);
    }
#pragma unroll
    for (int tile = 0; tile < 8; ++tile) {
      float v = acc[tile][0] + b2r[tile] - lse[0];
#pragma unroll
      for (int r = 1; r < 4; ++r) v = fmaxf(v, acc[tile][r] + b2r[tile] - lse[r]);
      v = fmaxf(v, __shfl_xor(v, 16, 64));
      v = fmaxf(v, __shfl_xor(v, 32, 64));
      if (quad == 0) h[(size_t)i * H_DIM + tile * 16 + lane16] = v;
    }
  }
}

// ----------------------------------------------------------------- k_hw -----
__global__ __launch_bounds__(256) void k_hw(const float* __restrict__ h,
                                            const float* __restrict__ gw,
                                            float* __restrict__ hw) {
  __shared__ float wl[H_DIM][H_DIM];   // 64 KB
  for (int s = threadIdx.x; s < H_DIM * H_DIM; s += 256) wl[s >> 7][s & 127] = gw[s];
  __syncthreads();
  const int node = blockIdx.x * 32 + (threadIdx.x & 31);
  const int ob = (threadIdx.x >> 5) * 16;
  float acc[16];
#pragma unroll
  for (int o = 0; o < 16; ++o) acc[o] = 0.f;
  const float4* hr = (const float4*)(h + node * H_DIM);
#define HWSTEP(ff, xs) { \
    const float* wr = &wl[(ff)][ob]; \
    _Pragma("unroll") \
    for (int o = 0; o < 16; o += 4) { const float4 w4 = *(const float4*)(wr + o); \
      acc[o+0] = fmaf((xs), w4.x, acc[o+0]); \
      acc[o+1] = fmaf((xs), w4.y, acc[o+1]); \
      acc[o+2] = fmaf((xs), w4.z, acc[o+2]); \
      acc[o+3] = fmaf((xs), w4.w, acc[o+3]); } }
#pragma unroll 2
  for (int q = 0; q < 32; ++q) {
    const float4 hv = hr[q];
    HWSTEP(4*q+0, hv.x); HWSTEP(4*q+1, hv.y); HWSTEP(4*q+2, hv.z); HWSTEP(4*q+3, hv.w);
  }
#undef HWSTEP
  float* dp = hw + node * H_DIM + ob;
#pragma unroll
  for (int o = 0; o < 16; ++o) dp[o] = acc[o];
}

// --------------------------------------------------------------- k_heads ----
__global__ __launch_bounds__(256) void k_heads(const float* __restrict__ hw,
                                               const int* __restrict__ knn,
                                               const float* __restrict__ gb,
                                               const float* __restrict__ gow,
                                               const float* __restrict__ gob,
                                               const float* __restrict__ ow,
                                               const float* __restrict__ obv,
                                               float* __restrict__ out) {
  __shared__ unsigned int wgo[H_DIM][64];  // 32 KB
  __shared__ float hbuf[4][H_DIM];         // 2 KB
  for (int s = threadIdx.x; s < H_DIM * 64; s += 256) {
    const int f = s >> 6, l = s & 63;
    const unsigned short u0 = __half_as_ushort(__float2half(gow[f * H_DIM + l]));
    const unsigned short u1 = __half_as_ushort(__float2half(gow[f * H_DIM + 64 + l]));
    wgo[f][l] = (unsigned int)u0 | ((unsigned int)u1 << 16);
  }
  __syncthreads();
  const int wv = threadIdx.x >> 6, l = threadIdx.x & 63;
  const float gbl = gb[l], gbh = gb[64 + l];
  const float gobl = gob[l], gobh = gob[64 + l];
  for (int it = 0; it < 8; ++it) {
    const int i = blockIdx.x * 32 + wv * 8 + it;
    const int* kr = knn + i * K_NN;
    float s0 = hw[i * H_DIM + l], s1 = hw[i * H_DIM + 64 + l];  // explicit self-loop
#pragma unroll
    for (int m = 0; m < K_NN; ++m) {
      const int j = kr[m];
      s0 += hw[j * H_DIM + l];
      s1 += hw[j * H_DIM + 64 + l];
    }
    // deg == k+1 == 17 for every node by construction -> norm == 1/17
    const float hg0 = s0 * (1.0f / 17.0f) + gbl;
    const float hg1 = s1 * (1.0f / 17.0f) + gbh;
    __syncthreads();
    hbuf[wv][l] = hg0; hbuf[wv][64 + l] = hg1;
    __syncthreads();
    float z0 = gobl, z1 = gobh;
#pragma unroll 4
    for (int f = 0; f < H_DIM; ++f) {
      const float hv = hbuf[wv][f];
      const unsigned int wvv = wgo[f][l];
      const float w0 = __half2float(__ushort_as_half((unsigned short)(wvv & 0xffffu)));
      const float w1 = __half2float(__ushort_as_half((unsigned short)(wvv >> 16)));
      z0 = fmaf(hv, w0, z0);
      z1 = fmaf(hv, w1, z1);
    }
    float mx = fmaxf(z0, z1);
#pragma unroll
    for (int s = 1; s < 64; s <<= 1) mx = fmaxf(mx, __shfl_xor(mx, s, 64));
    const float e0 = __expf(z0 - mx), e1 = __expf(z1 - mx);
    float sm = e0 + e1;
#pragma unroll
    for (int s = 1; s < 64; s <<= 1) sm += __shfl_xor(sm, s, 64);
    const float h20 = e0 / sm, h21 = e1 / sm;
    float zc[O_DIM];
#pragma unroll
    for (int c = 0; c < O_DIM; ++c) {
      float a = h20 * ow[l * O_DIM + c] + h21 * ow[(64 + l) * O_DIM + c];
#pragma unroll
      for (int s = 1; s < 64; s <<= 1) a += __shfl_xor(a, s, 64);
      zc[c] = a + obv[c];
    }
    float m10 = zc[0];
#pragma unroll
    for (int c = 1; c < O_DIM; ++c) m10 = fmaxf(m10, zc[c]);
    float es[O_DIM]; float s10 = 0.f;
#pragma unroll
    for (int c = 0; c < O_DIM; ++c) { es[c] = __expf(zc[c] - m10); s10 += es[c]; }
    const float inv = 1.0f / s10;
    if (l < O_DIM) {
      float v = es[0];
#pragma unroll
      for (int c = 1; c < O_DIM; ++c) if (l == c) v = es[c];
      out[i * O_DIM + l] = v * inv;
    }
  }
}

// ---------------------------------------------------------------------------
extern "C" void kernel_launch(void* const* d_in, const int* in_sizes, int n_in,
                              void* d_out, int out_size, void* d_ws, size_t ws_size,
                              hipStream_t stream) {
  (void)in_sizes; (void)n_in; (void)out_size; (void)ws_size;
  const float* x   = (const float*)d_in[0];
  const float* w1  = (const float*)d_in[2];
  const float* b1  = (const float*)d_in[3];
  const float* w2  = (const float*)d_in[4];
  const float* b2  = (const float*)d_in[5];
  const float* gw  = (const float*)d_in[6];
  const float* gb  = (const float*)d_in[7];
  const float* gow = (const float*)d_in[8];
  const float* gob = (const float*)d_in[9];
  const float* ow  = (const float*)d_in[10];
  const float* obv = (const float*)d_in[11];
  float* out = (float*)d_out;

  char* ws = (char*)d_ws;
  constexpr size_t OFF_SQ   = 0;                                          // 64 KB
  constexpr size_t OFF_SQ64 = OFF_SQ   + (size_t)N_NODES * 4;             // 128 KB
  constexpr size_t OFF_XHL  = OFF_SQ64 + (size_t)N_NODES * 8;             // 4 MB
  constexpr size_t OFF_CMIN = OFF_XHL  + (size_t)N_NODES * 128 * 2;       // 2 MB
  constexpr size_t OFF_TAU  = OFF_CMIN + (size_t)N_NODES * 32 * 4;        // 64 KB
  constexpr size_t OFF_CNT  = OFF_TAU  + (size_t)N_NODES * 4;             // 64 KB
  constexpr size_t OFF_CAND = OFF_CNT  + (size_t)N_NODES * 4;             // 8 MB
  constexpr size_t OFF_KNN  = OFF_CAND + (size_t)N_NODES * 128 * 4;       // 1 MB
  constexpr size_t OFF_Q    = OFF_KNN  + (size_t)N_NODES * K_NN * 4;      // 8 MB
  constexpr size_t OFF_H    = OFF_Q    + (size_t)N_NODES * H_DIM * 4;     // 8 MB
  float*     sq   = (float*)    (ws + OFF_SQ);
  double*    sq64 = (double*)   (ws + OFF_SQ64);
  _Float16*  xhl  = (_Float16*) (ws + OFF_XHL);
  float*     cmin = (float*)    (ws + OFF_CMIN);
  float*     tau  = (float*)    (ws + OFF_TAU);
  unsigned*  cnt  = (unsigned*) (ws + OFF_CNT);
  int*       cand = (int*)      (ws + OFF_CAND);
  int*       knn  = (int*)      (ws + OFF_KNN);
  float*     Q    = (float*)    (ws + OFF_Q);
  float*     h    = (float*)    (ws + OFF_H);
  float*     P    = (float*)    (ws + OFF_CAND);  // P aliases cand (dead after rescore)
  float*     hw   = P;                            // hw aliases P (dead after edgeconv)

  k_prep    <<<N_NODES / 256, 256, 0, stream>>>(x, sq, sq64, xhl);
  k_gemm<1> <<<1024,          256, 0, stream>>>(xhl, sq, tau, cmin, cnt, cand);
  k_tau     <<<N_NODES / 256, 256, 0, stream>>>(cmin, tau, cnt);
  k_gemm<2> <<<1024,          256, 0, stream>>>(xhl, sq, tau, cmin, cnt, cand);
  k_rescore <<<N_NODES,       128, 0, stream>>>(x, sq64, cand, cnt, knn);
  k_lin12   <<<N_NODES / 32,  256, 0, stream>>>(x, w1, b1, P, Q);
  k_edgeconv<<<N_NODES / 32,  256, 0, stream>>>(P, Q, w2, b2, knn, h);
  k_hw      <<<N_NODES / 32,  256, 0, stream>>>(h, gw, hw);
  k_heads   <<<N_NODES / 32,  256, 0, stream>>>(hw, knn, gb, gow, gob, ow, obv, out);
}

// Round 6
// 480.868 us; speedup vs baseline: 1.3047x; 1.2708x over previous
//
#include <hip/hip_runtime.h>
#include <hip/hip_fp16.h>
#include <cfloat>
#include <cmath>

// GNN_Combo pipeline. Round 6: single-term f16 distance GEMM (no hi/lo split)
// -- the fp64 rescore + tau margin absorbs the f16 error (delta ~0.05 <<
// margin 0.25 << neighbor gaps). 3x less MFMA, half the staging, half A-regs.
// N=16384 nodes, F=64 in-features, H=128 hidden, K=16 neighbors, O=10 classes.

#define N_NODES 16384
#define F_IN    64
#define H_DIM   128
#define K_NN    16
#define O_DIM   10

typedef _Float16 half8  __attribute__((ext_vector_type(8)));
typedef _Float16 half4v __attribute__((ext_vector_type(4)));
typedef float    floatx4 __attribute__((ext_vector_type(4)));

__device__ __forceinline__ void async_copy16(void* lds, const void* g) {
  __builtin_amdgcn_global_load_lds(
      (const __attribute__((address_space(1))) unsigned int*)g,
      (__attribute__((address_space(3))) unsigned int*)lds, 16, 0, 0);
}

// ---------------------------------------------------------------- k_prep ----
__global__ __launch_bounds__(256) void k_prep(const float* __restrict__ x,
                                              float* __restrict__ sq,
                                              double* __restrict__ sq64,
                                              _Float16* __restrict__ xh) {
  const int i = blockIdx.x * 256 + threadIdx.x;
  if (i >= N_NODES) return;
  const float4* r = (const float4*)(x + i * F_IN);
  float s = 0.f; double sd = 0.0;
#pragma unroll
  for (int q = 0; q < 16; ++q) {
    const float4 v = r[q];
    s += v.x*v.x + v.y*v.y + v.z*v.z + v.w*v.w;
    sd += (double)v.x*v.x + (double)v.y*v.y + (double)v.z*v.z + (double)v.w*v.w;
    half4v hv;
    hv[0] = (_Float16)v.x; hv[1] = (_Float16)v.y;
    hv[2] = (_Float16)v.z; hv[3] = (_Float16)v.w;
    *(half4v*)(xh + (size_t)i * F_IN + 4 * q) = hv;
  }
  sq[i] = s; sq64[i] = sd;
}

// ---------------------------------------------------------------- k_gemm ----
// Grid: 64 rowblocks (256 rows) x 16 col-segments (1024 cols) = 1024 blocks.
// Block: 256 thr / 4 waves; wave owns 64 rows (4 rowsets), single f16 term
// (K=64, 2 k-blocks) -> 8 MFMA per 16-col subtile. Column tile = 128 cols x
// 128 B (16 KB) staged via global_load_lds width=16 (4 instr/wave, linear LDS
// -> conflict-free writes). LDS layout: col*64 halves, 16-B chunk stored at
// chunk^(col&7) -> B-frag reads are 2-way max (free). key = sq[col] - 2*dot
// (fp32 acc; |key - exact| <~ 0.05). Phase 1: per-(row,512-col-chunk) min.
// Phase 2: collect approx_key <= tau + 0.25 (margin >= 2*delta guarantees the
// true top-16 are collected; fp64 rescore finalizes exactly).
template<int PHASE>
__global__ __launch_bounds__(256) void k_gemm(const _Float16* __restrict__ xh,
                                              const float* __restrict__ sq,
                                              const float* __restrict__ tau,
                                              float* __restrict__ cmins,
                                              unsigned* __restrict__ cnt,
                                              int* __restrict__ cand) {
  __shared__ __align__(16) _Float16 stage[128 * 64];  // 16 KB, swizzled
  __shared__ float sqs[128];
  const int tid = threadIdx.x;
  const int wv = tid >> 6, l = tid & 63;
  const int lane16 = l & 15, quad = l >> 4;
  const int rowblk = (blockIdx.x >> 4) * 256;   // 64 rowblocks
  const int seg = blockIdx.x & 15;              // 16 col-segments of 1024
  const int rw = rowblk + wv * 64;

  half8 A[4][2];  // [rowset][kb]
#pragma unroll
  for (int s = 0; s < 4; ++s) {
    const _Float16* ap = xh + (size_t)(rw + s * 16 + lane16) * F_IN + quad * 8;
    A[s][0] = *(const half8*)(ap);
    A[s][1] = *(const half8*)(ap + 32);
  }
  float tau_r[16];
  float rmin[16];
  if (PHASE == 2) {
#pragma unroll
    for (int s = 0; s < 4; ++s)
#pragma unroll
      for (int q = 0; q < 4; ++q)
        tau_r[s * 4 + q] = tau[rw + s * 16 + quad * 4 + q] + 0.25f;
  } else {
#pragma unroll
    for (int t = 0; t < 16; ++t) rmin[t] = FLT_MAX;
  }

  // staging lane constants: slot g = (wv*4+q)*64 + l; col = g>>3;
  // chunk = (l&7) ^ (l>>3)  (col&7 == l>>3)
  const int lcol8 = l >> 3;                  // col offset within 8-col group
  const int lchk  = (l & 7) ^ lcol8;         // swizzled chunk (const per lane)
  const size_t lgoff = (size_t)lcol8 * F_IN + lchk * 8;

  for (int tile = 0; tile < 8; ++tile) {
    const int c0 = seg * 1024 + tile * 128;
    __syncthreads();   // prior tile's compute done before overwrite
    if (tid < 128) sqs[tid] = sq[c0 + tid];
    {  // async staging: 4 issues/wave, 1 KB each, LDS-linear
#pragma unroll
      for (int q = 0; q < 4; ++q) {
        const int grp = wv * 4 + q;          // 8-col group 0..15
        async_copy16(stage + grp * 512,
                     xh + (size_t)(c0 + grp * 8) * F_IN + lgoff);
      }
    }
    __syncthreads();   // drains vmcnt (global_load_lds) + lgkm
#pragma unroll 1
    for (int st = 0; st < 8; ++st) {
      const _Float16* base = stage + (st * 16 + lane16) * 64;
      const int sw = lane16 & 7;
      const half8 B0 = *(const half8*)(base + ((quad ^ sw) * 8));        // k 0-31
      const half8 B1 = *(const half8*)(base + (((4 + quad) ^ sw) * 8));  // k 32-63
      const float sqv = sqs[st * 16 + lane16];
      floatx4 acc[4];
#pragma unroll
      for (int s = 0; s < 4; ++s) acc[s] = (floatx4)0.f;
#pragma unroll
      for (int s = 0; s < 4; ++s)
        acc[s] = __builtin_amdgcn_mfma_f32_16x16x32_f16(A[s][0], B0, acc[s], 0, 0, 0);
#pragma unroll
      for (int s = 0; s < 4; ++s)
        acc[s] = __builtin_amdgcn_mfma_f32_16x16x32_f16(A[s][1], B1, acc[s], 0, 0, 0);
      if (PHASE == 1) {
#pragma unroll
        for (int s = 0; s < 4; ++s)
#pragma unroll
          for (int q = 0; q < 4; ++q)
            rmin[s * 4 + q] = fminf(rmin[s * 4 + q], fmaf(-2.f, acc[s][q], sqv));
      } else {
        const int colb = c0 + st * 16 + lane16;
#pragma unroll
        for (int s = 0; s < 4; ++s) {
          const float k0 = fmaf(-2.f, acc[s][0], sqv);
          const float k1 = fmaf(-2.f, acc[s][1], sqv);
          const float k2 = fmaf(-2.f, acc[s][2], sqv);
          const float k3 = fmaf(-2.f, acc[s][3], sqv);
          const float d01 = fminf(k0 - tau_r[s * 4 + 0], k1 - tau_r[s * 4 + 1]);
          const float d23 = fminf(k2 - tau_r[s * 4 + 2], k3 - tau_r[s * 4 + 3]);
          if (__ballot(fminf(d01, d23) <= 0.f)) {
            const int rbase = rw + s * 16 + quad * 4;
            if (k0 <= tau_r[s * 4 + 0]) {
              const unsigned pos = atomicAdd(&cnt[rbase + 0], 1u);
              if (pos < 128u) cand[(size_t)(rbase + 0) * 128 + pos] = colb;
            }
            if (k1 <= tau_r[s * 4 + 1]) {
              const unsigned pos = atomicAdd(&cnt[rbase + 1], 1u);
              if (pos < 128u) cand[(size_t)(rbase + 1) * 128 + pos] = colb;
            }
            if (k2 <= tau_r[s * 4 + 2]) {
              const unsigned pos = atomicAdd(&cnt[rbase + 2], 1u);
              if (pos < 128u) cand[(size_t)(rbase + 2) * 128 + pos] = colb;
            }
            if (k3 <= tau_r[s * 4 + 3]) {
              const unsigned pos = atomicAdd(&cnt[rbase + 3], 1u);
              if (pos < 128u) cand[(size_t)(rbase + 3) * 128 + pos] = colb;
            }
          }
        }
      }
    }
    if (PHASE == 1 && (tile & 3) == 3) {   // chunk boundary (512 cols)
#pragma unroll
      for (int t = 0; t < 16; ++t) {
#pragma unroll
        for (int d = 1; d < 16; d <<= 1)
          rmin[t] = fminf(rmin[t], __shfl_xor(rmin[t], d, 64));
      }
      const int chunk = seg * 2 + (tile >> 2);
      float v = rmin[0];
#pragma unroll
      for (int t = 1; t < 16; ++t) if (lane16 == t) v = rmin[t];
      const int row = rw + (lane16 >> 2) * 16 + quad * 4 + (lane16 & 3);
      cmins[(size_t)row * 32 + chunk] = v;
#pragma unroll
      for (int t = 0; t < 16; ++t) rmin[t] = FLT_MAX;
    }
  }
}

// ----------------------------------------------------------------- k_tau ----
__global__ __launch_bounds__(256) void k_tau(const float* __restrict__ cmins,
                                             float* __restrict__ tau,
                                             unsigned* __restrict__ cnt) {
  const int r = blockIdx.x * 256 + threadIdx.x;
  if (r >= N_NODES) return;
  float v[32];
#pragma unroll
  for (int j = 0; j < 32; ++j) v[j] = cmins[(size_t)r * 32 + j];
  float t16 = FLT_MAX;
#pragma unroll 1
  for (int j = 0; j < 32; ++j) {
    int rk = 0;
#pragma unroll
    for (int m = 0; m < 32; ++m)
      rk += (v[m] < v[j]) || (v[m] == v[j] && m < j);
    if (rk == 15) t16 = v[j];
  }
  tau[r] = t16;
  cnt[r] = 0;
}

// ------------------------------------------------------------- k_rescore ----
__global__ __launch_bounds__(128) void k_rescore(const float* __restrict__ x,
                                                 const double* __restrict__ sq64,
                                                 const int* __restrict__ cand,
                                                 const unsigned* __restrict__ cnt,
                                                 int* __restrict__ knn) {
  __shared__ float  xi[F_IN];
  __shared__ double keys[128];
  __shared__ int    ids[128];
  const int i = blockIdx.x, t = threadIdx.x;
  const unsigned c = cnt[i];
  const int n = (int)(c < 128u ? c : 128u);
  if (t < F_IN) xi[t] = x[i * F_IN + t];
  __syncthreads();
  double key = 1e300; int id = 0x7fffffff;
  if (t < n) {
    id = cand[(size_t)i * 128 + t];
    const float4* xc4 = (const float4*)(x + (size_t)id * F_IN);
    double d0 = 0.0, d1 = 0.0, d2 = 0.0, d3 = 0.0;
#pragma unroll
    for (int q = 0; q < 16; ++q) {
      const float4 v = xc4[q];
      d0 += (double)xi[4*q+0] * (double)v.x;
      d1 += (double)xi[4*q+1] * (double)v.y;
      d2 += (double)xi[4*q+2] * (double)v.z;
      d3 += (double)xi[4*q+3] * (double)v.w;
    }
    key = sq64[id] - 2.0 * ((d0 + d1) + (d2 + d3));
  }
  keys[t] = key; ids[t] = id;
  __syncthreads();
  int rank = 0;
#pragma unroll 4
  for (int cix = 0; cix < 128; ++cix) {
    const double kc = keys[cix]; const int ic = ids[cix];
    rank += (kc < key) || (kc == key && ic < id);
  }
  if (t < n && rank < K_NN) knn[i * K_NN + rank] = id;
}

// --------------------------------------------------------------- k_lin12 ----
__global__ __launch_bounds__(256, 2) void k_lin12(const float* __restrict__ x,
                                                  const float* __restrict__ w1,
                                                  const float* __restrict__ b1,
                                                  float* __restrict__ P,
                                                  float* __restrict__ Q) {
  __shared__ float wl[2 * F_IN][H_DIM];   // 64 KB
  for (int s = threadIdx.x; s < 2 * F_IN * H_DIM; s += 256) wl[s >> 7][s & 127] = w1[s];
  __syncthreads();
  const int node = blockIdx.x * 32 + (threadIdx.x & 31);
  const int ob = (threadIdx.x >> 5) * 16;   // 8 groups x 16 outs
  float accR[16], accQ[16];
#pragma unroll
  for (int o = 0; o < 16; ++o) { accR[o] = 0.f; accQ[o] = 0.f; }
  const float4* xr = (const float4*)(x + node * F_IN);
#define L1STEP(ff, xs) { \
    const float* wt_ = &wl[(ff)][ob]; \
    const float* wb_ = &wl[(ff) + F_IN][ob]; \
    _Pragma("unroll") \
    for (int o = 0; o < 16; o += 4) { \
      const float4 t4 = *(const float4*)(wt_ + o); \
      const float4 b4 = *(const float4*)(wb_ + o); \
      accR[o+0] = fmaf((xs), t4.x, accR[o+0]); accQ[o+0] = fmaf((xs), b4.x, accQ[o+0]); \
      accR[o+1] = fmaf((xs), t4.y, accR[o+1]); accQ[o+1] = fmaf((xs), b4.y, accQ[o+1]); \
      accR[o+2] = fmaf((xs), t4.z, accR[o+2]); accQ[o+2] = fmaf((xs), b4.z, accQ[o+2]); \
      accR[o+3] = fmaf((xs), t4.w, accR[o+3]); accQ[o+3] = fmaf((xs), b4.w, accQ[o+3]); } }
#pragma unroll 2
  for (int q = 0; q < 16; ++q) {
    const float4 xv = xr[q];
    L1STEP(4*q+0, xv.x); L1STEP(4*q+1, xv.y); L1STEP(4*q+2, xv.z); L1STEP(4*q+3, xv.w);
  }
#undef L1STEP
  float* pp = P + node * H_DIM + ob;
  float* qp = Q + node * H_DIM + ob;
#pragma unroll
  for (int o = 0; o < 16; ++o) {
    pp[o] = accR[o] - accQ[o] + b1[ob + o];
    qp[o] = accQ[o];
  }
}

// ------------------------------------------------------------ k_edgeconv ----
__global__ __launch_bounds__(256, 3) void k_edgeconv(const float* __restrict__ P,
                                                     const float* __restrict__ Q,
                                                     const float* __restrict__ w2,
                                                     const float* __restrict__ b2,
                                                     const int* __restrict__ knn,
                                                     float* __restrict__ h) {
  __shared__ __align__(16) _Float16 wt[H_DIM * 128];   // 32 KB, swizzled
  __shared__ __align__(16) _Float16 afr[4][2048];      // 16 KB, per-wave A frags
  const int tid = threadIdx.x;
  const int wv = tid >> 6, l = tid & 63;
  const int lane16 = l & 15, quad = l >> 4;

  {  // stage W2^T as f16 (swizzled chunk position)
    const int n = tid >> 1, part = tid & 1;
    const float* wsrc = w2 + n;
    _Float16* wdst = wt + n * 128;
#pragma unroll
    for (int c = 0; c < 8; ++c) {
      half8 hv;
#pragma unroll
      for (int u = 0; u < 8; ++u)
        hv[u] = (_Float16)wsrc[(size_t)(part * 64 + c * 8 + u) * H_DIM];
      *(half8*)(wdst + (((part * 8 + c) ^ (n & 15)) * 8)) = hv;
    }
  }
  __syncthreads();

  float b2r[8];
#pragma unroll
  for (int tile = 0; tile < 8; ++tile) b2r[tile] = b2[tile * 16 + lane16];

  _Float16* aw = afr[wv];
  for (int it = 0; it < 8; ++it) {
    const int i = blockIdx.x * 32 + wv * 8 + it;
    // ---- build A = relu(P_i + Q_j) in fragment order ----
    {
      const int m = lane16, kq = quad;          // lane: message m, k-chunk kq*32
      const int j = knn[i * K_NN + m];
      const float4* pq = (const float4*)(P + (size_t)i * H_DIM + kq * 32);
      const float4* qq = (const float4*)(Q + (size_t)j * H_DIM + kq * 32);
#pragma unroll
      for (int c = 0; c < 4; ++c) {
        const float4 pa = pq[2 * c],     qa = qq[2 * c];
        const float4 pb = pq[2 * c + 1], qb = qq[2 * c + 1];
        half8 hv;
        hv[0] = (_Float16)fmaxf(pa.x + qa.x, 0.f);
        hv[1] = (_Float16)fmaxf(pa.y + qa.y, 0.f);
        hv[2] = (_Float16)fmaxf(pa.z + qa.z, 0.f);
        hv[3] = (_Float16)fmaxf(pa.w + qa.w, 0.f);
        hv[4] = (_Float16)fmaxf(pb.x + qb.x, 0.f);
        hv[5] = (_Float16)fmaxf(pb.y + qb.y, 0.f);
        hv[6] = (_Float16)fmaxf(pb.z + qb.z, 0.f);
        hv[7] = (_Float16)fmaxf(pb.w + qb.w, 0.f);
        *(half8*)(aw + kq * 512 + c * 128 + m * 8) = hv;
      }
    }
    // ---- A-fragment loads (wave-internal LDS dep) ----
    half8 A[4];
#pragma unroll
    for (int kb = 0; kb < 4; ++kb) A[kb] = *(const half8*)(aw + kb * 512 + l * 8);
    // ---- 8 N-tiles x 4 K-blocks MFMA ----
    floatx4 acc[8];
#pragma unroll
    for (int tile = 0; tile < 8; ++tile) acc[tile] = (floatx4)0.f;
#pragma unroll
    for (int kb = 0; kb < 4; ++kb) {
#pragma unroll
      for (int tile = 0; tile < 8; ++tile) {
        const half8 B = *(const half8*)(wt + (tile * 16 + lane16) * 128 +
                                        (((kb * 4 + quad) ^ lane16) * 8));
        acc[tile] = __builtin_amdgcn_mfma_f32_16x16x32_f16(A[kb], B, acc[tile], 0, 0, 0);
      }
    }
    // ---- epilogue: +b2, per-row log_softmax, max over 16 rows ----
    float lse[4];
#pragma unroll
    for (int r = 0; r < 4; ++r) {
      float mx = acc[0][r] + b2r[0];
#pragma unroll
      for (int tile = 1; tile < 8; ++tile) mx = fmaxf(mx, acc[tile][r] + b2r[tile]);
      mx = fmaxf(mx, __shfl_xor(mx, 1, 64));
      mx = fmaxf(mx, __shfl_xor(mx, 2, 64));
      mx = fmaxf(mx, __shfl_xor(mx, 4, 64));
      mx = fmaxf(mx, __shfl_xor(mx, 8, 64));
      float e = 0.f;
#pragma unroll
      for (int tile = 0; tile < 8; ++tile) e += __expf(acc[tile][r] + b2r[tile] - mx);
      e += __shfl_xor(e, 1, 64);
      e += __shfl_xor(e, 2, 64);
      e += __shfl_xor(e, 4, 64);
      e += __shfl_xor(e, 8, 64);
      lse[r] = mx + __logf(e);
    }
#pragma unroll
    for (int tile = 0; tile < 8; ++tile) {
      float v = acc[tile][0] + b2r[tile] - lse[0];
#pragma unroll
      for (int r = 1; r < 4; ++r) v = fmaxf(v, acc[tile][r] + b2r[tile] - lse[r]);
      v = fmaxf(v, __shfl_xor(v, 16, 64));
      v = fmaxf(v, __shfl_xor(v, 32, 64));
      if (quad == 0) h[(size_t)i * H_DIM + tile * 16 + lane16] = v;
    }
  }
}

// ----------------------------------------------------------------- k_hw -----
__global__ __launch_bounds__(256) void k_hw(const float* __restrict__ h,
                                            const float* __restrict__ gw,
                                            float* __restrict__ hw) {
  __shared__ float wl[H_DIM][H_DIM];   // 64 KB
  for (int s = threadIdx.x; s < H_DIM * H_DIM; s += 256) wl[s >> 7][s & 127] = gw[s];
  __syncthreads();
  const int node = blockIdx.x * 32 + (threadIdx.x & 31);
  const int ob = (threadIdx.x >> 5) * 16;
  float acc[16];
#pragma unroll
  for (int o = 0; o < 16; ++o) acc[o] = 0.f;
  const float4* hr = (const float4*)(h + node * H_DIM);
#define HWSTEP(ff, xs) { \
    const float* wr = &wl[(ff)][ob]; \
    _Pragma("unroll") \
    for (int o = 0; o < 16; o += 4) { const float4 w4 = *(const float4*)(wr + o); \
      acc[o+0] = fmaf((xs), w4.x, acc[o+0]); \
      acc[o+1] = fmaf((xs), w4.y, acc[o+1]); \
      acc[o+2] = fmaf((xs), w4.z, acc[o+2]); \
      acc[o+3] = fmaf((xs), w4.w, acc[o+3]); } }
#pragma unroll 2
  for (int q = 0; q < 32; ++q) {
    const float4 hv = hr[q];
    HWSTEP(4*q+0, hv.x); HWSTEP(4*q+1, hv.y); HWSTEP(4*q+2, hv.z); HWSTEP(4*q+3, hv.w);
  }
#undef HWSTEP
  float* dp = hw + node * H_DIM + ob;
#pragma unroll
  for (int o = 0; o < 16; ++o) dp[o] = acc[o];
}

// --------------------------------------------------------------- k_heads ----
__global__ __launch_bounds__(256) void k_heads(const float* __restrict__ hw,
                                               const int* __restrict__ knn,
                                               const float* __restrict__ gb,
                                               const float* __restrict__ gow,
                                               const float* __restrict__ gob,
                                               const float* __restrict__ ow,
                                               const float* __restrict__ obv,
                                               float* __restrict__ out) {
  __shared__ unsigned int wgo[H_DIM][64];  // 32 KB
  __shared__ float hbuf[4][H_DIM];         // 2 KB
  for (int s = threadIdx.x; s < H_DIM * 64; s += 256) {
    const int f = s >> 6, l = s & 63;
    const unsigned short u0 = __half_as_ushort(__float2half(gow[f * H_DIM + l]));
    const unsigned short u1 = __half_as_ushort(__float2half(gow[f * H_DIM + 64 + l]));
    wgo[f][l] = (unsigned int)u0 | ((unsigned int)u1 << 16);
  }
  __syncthreads();
  const int wv = threadIdx.x >> 6, l = threadIdx.x & 63;
  const float gbl = gb[l], gbh = gb[64 + l];
  const float gobl = gob[l], gobh = gob[64 + l];
  for (int it = 0; it < 8; ++it) {
    const int i = blockIdx.x * 32 + wv * 8 + it;
    const int* kr = knn + i * K_NN;
    float s0 = hw[i * H_DIM + l], s1 = hw[i * H_DIM + 64 + l];  // explicit self-loop
#pragma unroll
    for (int m = 0; m < K_NN; ++m) {
      const int j = kr[m];
      s0 += hw[j * H_DIM + l];
      s1 += hw[j * H_DIM + 64 + l];
    }
    // deg == k+1 == 17 for every node by construction -> norm == 1/17
    const float hg0 = s0 * (1.0f / 17.0f) + gbl;
    const float hg1 = s1 * (1.0f / 17.0f) + gbh;
    __syncthreads();
    hbuf[wv][l] = hg0; hbuf[wv][64 + l] = hg1;
    __syncthreads();
    float z0 = gobl, z1 = gobh;
#pragma unroll 4
    for (int f = 0; f < H_DIM; ++f) {
      const float hv = hbuf[wv][f];
      const unsigned int wvv = wgo[f][l];
      const float w0 = __half2float(__ushort_as_half((unsigned short)(wvv & 0xffffu)));
      const float w1 = __half2float(__ushort_as_half((unsigned short)(wvv >> 16)));
      z0 = fmaf(hv, w0, z0);
      z1 = fmaf(hv, w1, z1);
    }
    float mx = fmaxf(z0, z1);
#pragma unroll
    for (int s = 1; s < 64; s <<= 1) mx = fmaxf(mx, __shfl_xor(mx, s, 64));
    const float e0 = __expf(z0 - mx), e1 = __expf(z1 - mx);
    float sm = e0 + e1;
#pragma unroll
    for (int s = 1; s < 64; s <<= 1) sm += __shfl_xor(sm, s, 64);
    const float h20 = e0 / sm, h21 = e1 / sm;
    float zc[O_DIM];
#pragma unroll
    for (int c = 0; c < O_DIM; ++c) {
      float a = h20 * ow[l * O_DIM + c] + h21 * ow[(64 + l) * O_DIM + c];
#pragma unroll
      for (int s = 1; s < 64; s <<= 1) a += __shfl_xor(a, s, 64);
      zc[c] = a + obv[c];
    }
    float m10 = zc[0];
#pragma unroll
    for (int c = 1; c < O_DIM; ++c) m10 = fmaxf(m10, zc[c]);
    float es[O_DIM]; float s10 = 0.f;
#pragma unroll
    for (int c = 0; c < O_DIM; ++c) { es[c] = __expf(zc[c] - m10); s10 += es[c]; }
    const float inv = 1.0f / s10;
    if (l < O_DIM) {
      float v = es[0];
#pragma unroll
      for (int c = 1; c < O_DIM; ++c) if (l == c) v = es[c];
      out[i * O_DIM + l] = v * inv;
    }
  }
}

// ---------------------------------------------------------------------------
extern "C" void kernel_launch(void* const* d_in, const int* in_sizes, int n_in,
                              void* d_out, int out_size, void* d_ws, size_t ws_size,
                              hipStream_t stream) {
  (void)in_sizes; (void)n_in; (void)out_size; (void)ws_size;
  const float* x   = (const float*)d_in[0];
  const float* w1  = (const float*)d_in[2];
  const float* b1  = (const float*)d_in[3];
  const float* w2  = (const float*)d_in[4];
  const float* b2  = (const float*)d_in[5];
  const float* gw  = (const float*)d_in[6];
  const float* gb  = (const float*)d_in[7];
  const float* gow = (const float*)d_in[8];
  const float* gob = (const float*)d_in[9];
  const float* ow  = (const float*)d_in[10];
  const float* obv = (const float*)d_in[11];
  float* out = (float*)d_out;

  char* ws = (char*)d_ws;
  constexpr size_t OFF_SQ   = 0;                                          // 64 KB
  constexpr size_t OFF_SQ64 = OFF_SQ   + (size_t)N_NODES * 4;             // 128 KB
  constexpr size_t OFF_XH   = OFF_SQ64 + (size_t)N_NODES * 8;             // 2 MB
  constexpr size_t OFF_CMIN = OFF_XH   + (size_t)N_NODES * F_IN * 2;      // 2 MB
  constexpr size_t OFF_TAU  = OFF_CMIN + (size_t)N_NODES * 32 * 4;        // 64 KB
  constexpr size_t OFF_CNT  = OFF_TAU  + (size_t)N_NODES * 4;             // 64 KB
  constexpr size_t OFF_CAND = OFF_CNT  + (size_t)N_NODES * 4;             // 8 MB
  constexpr size_t OFF_KNN  = OFF_CAND + (size_t)N_NODES * 128 * 4;       // 1 MB
  constexpr size_t OFF_Q    = OFF_KNN  + (size_t)N_NODES * K_NN * 4;      // 8 MB
  constexpr size_t OFF_H    = OFF_Q    + (size_t)N_NODES * H_DIM * 4;     // 8 MB
  float*     sq   = (float*)    (ws + OFF_SQ);
  double*    sq64 = (double*)   (ws + OFF_SQ64);
  _Float16*  xh   = (_Float16*) (ws + OFF_XH);
  float*     cmin = (float*)    (ws + OFF_CMIN);
  float*     tau  = (float*)    (ws + OFF_TAU);
  unsigned*  cnt  = (unsigned*) (ws + OFF_CNT);
  int*       cand = (int*)      (ws + OFF_CAND);
  int*       knn  = (int*)      (ws + OFF_KNN);
  float*     Q    = (float*)    (ws + OFF_Q);
  float*     h    = (float*)    (ws + OFF_H);
  float*     P    = (float*)    (ws + OFF_CAND);  // P aliases cand (dead after rescore)
  float*     hw   = P;                            // hw aliases P (dead after edgeconv)

  k_prep    <<<N_NODES / 256, 256, 0, stream>>>(x, sq, sq64, xh);
  k_gemm<1> <<<1024,          256, 0, stream>>>(xh, sq, tau, cmin, cnt, cand);
  k_tau     <<<N_NODES / 256, 256, 0, stream>>>(cmin, tau, cnt);
  k_gemm<2> <<<1024,          256, 0, stream>>>(xh, sq, tau, cmin, cnt, cand);
  k_rescore <<<N_NODES,       128, 0, stream>>>(x, sq64, cand, cnt, knn);
  k_lin12   <<<N_NODES / 32,  256, 0, stream>>>(x, w1, b1, P, Q);
  k_edgeconv<<<N_NODES / 32,  256, 0, stream>>>(P, Q, w2, b2, knn, h);
  k_hw      <<<N_NODES / 32,  256, 0, stream>>>(h, gw, hw);
  k_heads   <<<N_NODES / 32,  256, 0, stream>>>(hw, knn, gb, gow, gob, ow, obv, out);
}

// Round 8
// 396.625 us; speedup vs baseline: 1.5819x; 1.2124x over previous
//
#include <hip/hip_runtime.h>
#include <hip/hip_fp16.h>
#include <cfloat>
#include <cmath>
#include <string.h>

// GNN_Combo pipeline. Round 7b: ONE distance GEMM (transposed MFMA layout)
// emitting per-(row,16-col-subtile) f16 mins; wave-per-row filter kernel
// derives tau (16th of 64 chunk-mins), rescans only ~25 subtiles/row with
// f16-input fp32 dots, appends candidates; fp64 rescore finalizes exactly.
// (7b: fix pack2h — plain _Float16 casts instead of cvt_pkrtz intrinsic.)
// N=16384 nodes, F=64 in-features, H=128 hidden, K=16 neighbors, O=10 classes.

#define N_NODES 16384
#define F_IN    64
#define H_DIM   128
#define K_NN    16
#define O_DIM   10

typedef _Float16 half8  __attribute__((ext_vector_type(8)));
typedef _Float16 half4v __attribute__((ext_vector_type(4)));
typedef _Float16 half2v __attribute__((ext_vector_type(2)));
typedef float    floatx4 __attribute__((ext_vector_type(4)));

__device__ __forceinline__ void async_copy16(void* lds, const void* g) {
  __builtin_amdgcn_global_load_lds(
      (const __attribute__((address_space(1))) unsigned int*)g,
      (__attribute__((address_space(3))) unsigned int*)lds, 16, 0, 0);
}

__device__ __forceinline__ unsigned pack2h(float a, float b) {
  half2v p; p[0] = (_Float16)a; p[1] = (_Float16)b;
  unsigned u; __builtin_memcpy(&u, &p, 4); return u;
}
__device__ __forceinline__ float unpacklo(unsigned u) {
  half2v p; __builtin_memcpy(&p, &u, 4); return (float)p[0];
}
__device__ __forceinline__ float unpackhi(unsigned u) {
  half2v p; __builtin_memcpy(&p, &u, 4); return (float)p[1];
}

// ---------------------------------------------------------------- k_prep ----
__global__ __launch_bounds__(256) void k_prep(const float* __restrict__ x,
                                              float* __restrict__ sq,
                                              double* __restrict__ sq64,
                                              _Float16* __restrict__ xh,
                                              unsigned* __restrict__ cnt) {
  const int i = blockIdx.x * 256 + threadIdx.x;
  if (i >= N_NODES) return;
  const float4* r = (const float4*)(x + i * F_IN);
  float s = 0.f; double sd = 0.0;
#pragma unroll
  for (int q = 0; q < 16; ++q) {
    const float4 v = r[q];
    s += v.x*v.x + v.y*v.y + v.z*v.z + v.w*v.w;
    sd += (double)v.x*v.x + (double)v.y*v.y + (double)v.z*v.z + (double)v.w*v.w;
    half4v hv;
    hv[0] = (_Float16)v.x; hv[1] = (_Float16)v.y;
    hv[2] = (_Float16)v.z; hv[3] = (_Float16)v.w;
    *(half4v*)(xh + (size_t)i * F_IN + 4 * q) = hv;
  }
  sq[i] = s; sq64[i] = sd; cnt[i] = 0;
}

// ---------------------------------------------------------------- k_gemm ----
// Transposed MFMA: A = staged column tile (LDS, round-6 swizzle -> conflict-
// free), B = 64 rows/wave in regs (4 rowsets). acc: cols in regs (quad*4+q),
// rows in lane16 -> per-16-col submin = 3 reg mins + shfl_xor(16,32).
// Grid: 64 rowblocks (256 rows) x 32 col-segments (512 cols) = 2048 blocks.
// Output: subg[row][1024] f16 subtile mins (packed pairs).
__global__ __launch_bounds__(256) void k_gemm(const _Float16* __restrict__ xh,
                                              const float* __restrict__ sq,
                                              char* __restrict__ subg) {
  __shared__ __align__(16) _Float16 stage[128 * 64];  // 16 KB, swizzled
  __shared__ float sqs[128];
  const int tid = threadIdx.x;
  const int wv = tid >> 6, l = tid & 63;
  const int lane16 = l & 15, quad = l >> 4;
  const int rowblk = (blockIdx.x >> 5) * 256;   // 64 rowblocks
  const int seg = blockIdx.x & 31;              // 32 col-segments of 512
  const int rw = rowblk + wv * 64;

  half8 B[4][2];  // row fragments: [rowset][kb]; B[k][n=lane16=row]
#pragma unroll
  for (int s = 0; s < 4; ++s) {
    const _Float16* bp = xh + (size_t)(rw + s * 16 + lane16) * F_IN + quad * 8;
    B[s][0] = *(const half8*)(bp);
    B[s][1] = *(const half8*)(bp + 32);
  }

  // staging lane constants (identical to round 6; proven conflict-free)
  const int lcol8 = l >> 3;
  const int lchk  = (l & 7) ^ lcol8;
  const size_t lgoff = (size_t)lcol8 * F_IN + lchk * 8;

  for (int tile = 0; tile < 4; ++tile) {
    const int c0 = seg * 512 + tile * 128;
    __syncthreads();
    if (tid < 128) sqs[tid] = sq[c0 + tid];
#pragma unroll
    for (int q = 0; q < 4; ++q) {
      const int grp = wv * 4 + q;
      async_copy16(stage + grp * 512,
                   xh + (size_t)(c0 + grp * 8) * F_IN + lgoff);
    }
    __syncthreads();

    float sprev[4];
    unsigned pk[4][4];
#pragma unroll
    for (int st = 0; st < 8; ++st) {
      const _Float16* base = stage + (st * 16 + lane16) * 64;
      const int sw = lane16 & 7;
      const half8 A0 = *(const half8*)(base + ((quad ^ sw) * 8));        // k 0-31
      const half8 A1 = *(const half8*)(base + (((4 + quad) ^ sw) * 8));  // k 32-63
      const floatx4 sq4 = *(const floatx4*)(sqs + st * 16 + quad * 4);
      floatx4 acc[4];
#pragma unroll
      for (int s = 0; s < 4; ++s) acc[s] = (floatx4)0.f;
#pragma unroll
      for (int s = 0; s < 4; ++s)
        acc[s] = __builtin_amdgcn_mfma_f32_16x16x32_f16(A0, B[s][0], acc[s], 0, 0, 0);
#pragma unroll
      for (int s = 0; s < 4; ++s)
        acc[s] = __builtin_amdgcn_mfma_f32_16x16x32_f16(A1, B[s][1], acc[s], 0, 0, 0);
#pragma unroll
      for (int s = 0; s < 4; ++s) {
        // keys for cols st*16+quad*4+q, row rw+s*16+lane16
        const float k0 = fmaf(-2.f, acc[s][0], sq4[0]);
        const float k1 = fmaf(-2.f, acc[s][1], sq4[1]);
        const float k2 = fmaf(-2.f, acc[s][2], sq4[2]);
        const float k3 = fmaf(-2.f, acc[s][3], sq4[3]);
        float m = fminf(fminf(k0, k1), fminf(k2, k3));
        m = fminf(m, __shfl_xor(m, 16, 64));   // min over quads -> 16 cols
        m = fminf(m, __shfl_xor(m, 32, 64));
        if ((st & 1) == 0) sprev[s] = m;
        else pk[s][st >> 1] = pack2h(sprev[s], m);
      }
    }
    // quad q stores rowset q's 8 packed submins (16 B) for its lane16 row
    unsigned o0 = pk[0][0], o1 = pk[0][1], o2 = pk[0][2], o3 = pk[0][3];
    if (quad == 1) { o0 = pk[1][0]; o1 = pk[1][1]; o2 = pk[1][2]; o3 = pk[1][3]; }
    if (quad == 2) { o0 = pk[2][0]; o1 = pk[2][1]; o2 = pk[2][2]; o3 = pk[2][3]; }
    if (quad == 3) { o0 = pk[3][0]; o1 = pk[3][1]; o2 = pk[3][2]; o3 = pk[3][3]; }
    const int row = rw + quad * 16 + lane16;
    uint4 ov; ov.x = o0; ov.y = o1; ov.z = o2; ov.w = o3;
    *(uint4*)(subg + ((size_t)row * 1024 + seg * 32 + tile * 8) * 2) = ov;
  }
}

// -------------------------------------------------------------- k_filter ----
// One wave per row. Load 1024 f16 submins (16/lane); chunk-min (256 cols) per
// lane; tau = rank-15 of 64 chunk-mins (all-pairs shfl rank, tie by lane);
// select subtiles with submin <= tau+0.25 (~25/row); cooperatively rescore
// each (16 cols x 4 lanes/col, f16-input fp32 dots); compacted single-atomic
// append of cols with key <= tau+0.25. fp64 rescore finalizes.
__global__ __launch_bounds__(256) void k_filter(const _Float16* __restrict__ xh,
                                                const float* __restrict__ sq,
                                                const char* __restrict__ subg,
                                                unsigned* __restrict__ cnt,
                                                int* __restrict__ cand) {
  const int l = threadIdx.x & 63;
  const int i = blockIdx.x * 4 + (threadIdx.x >> 6);
  const int part = l & 3, c = l >> 2;

  // xi fragment: dims [part*16, part*16+16) as f32
  float xi[16];
  {
    const half8* xp = (const half8*)(xh + (size_t)i * F_IN + part * 16);
    const half8 a = xp[0], b = xp[1];
#pragma unroll
    for (int j = 0; j < 8; ++j) { xi[j] = (float)a[j]; xi[8 + j] = (float)b[j]; }
  }
  // 16 submins for this lane's subtiles [l*16, l*16+16)
  float subs[16];
  {
    const uint4 a = *(const uint4*)(subg + ((size_t)i * 1024 + l * 16) * 2);
    const uint4 b = *(const uint4*)(subg + ((size_t)i * 1024 + l * 16) * 2 + 16);
    subs[0] = unpacklo(a.x); subs[1] = unpackhi(a.x);
    subs[2] = unpacklo(a.y); subs[3] = unpackhi(a.y);
    subs[4] = unpacklo(a.z); subs[5] = unpackhi(a.z);
    subs[6] = unpacklo(a.w); subs[7] = unpackhi(a.w);
    subs[8] = unpacklo(b.x); subs[9] = unpackhi(b.x);
    subs[10] = unpacklo(b.y); subs[11] = unpackhi(b.y);
    subs[12] = unpacklo(b.z); subs[13] = unpackhi(b.z);
    subs[14] = unpacklo(b.w); subs[15] = unpackhi(b.w);
  }
  float cmin = subs[0];
#pragma unroll
  for (int t = 1; t < 16; ++t) cmin = fminf(cmin, subs[t]);
  // tau = value of rank 15 among the 64 chunk-mins (ties by lane index)
  int rank = 0;
#pragma unroll 4
  for (int j = 0; j < 64; ++j) {
    const float vj = __shfl(cmin, j, 64);
    rank += (vj < cmin) || (vj == cmin && j < l);
  }
  const unsigned long long rm = __ballot(rank == 15);
  const int srcl = __ffsll((long long)rm) - 1;
  const float thr = __shfl(cmin, srcl, 64) + 0.25f;

  unsigned selmask = 0;
#pragma unroll
  for (int t = 0; t < 16; ++t) selmask |= (subs[t] <= thr) ? (1u << t) : 0u;

  unsigned long long act;
  while ((act = __ballot(selmask != 0)) != 0ull) {
    const int src = __ffsll((long long)act) - 1;
    unsigned m = __shfl(selmask, src, 64);   // uniform
    if (l == src) selmask = 0;
    while (m) {
      const int b = __ffs(m) - 1; m &= m - 1;
      const int sid = src * 16 + b;          // subtile index in this row
      const int cg = sid * 16 + c;           // this lane's column
      float d = 0.f;
      {
        const half8* gp = (const half8*)(xh + (size_t)cg * F_IN + part * 16);
        const half8 g0 = gp[0], g1 = gp[1];
#pragma unroll
        for (int j = 0; j < 8; ++j) {
          d = fmaf(xi[j], (float)g0[j], d);
          d = fmaf(xi[8 + j], (float)g1[j], d);
        }
      }
      d += __shfl_xor(d, 1, 64);
      d += __shfl_xor(d, 2, 64);
      const float key = fmaf(-2.f, d, sq[cg]);
      const bool pred = (part == 0) && (key <= thr);
      const unsigned long long am = __ballot(pred);
      if (am) {
        const int ldr = __ffsll((long long)am) - 1;
        unsigned base = 0;
        if (l == ldr) base = atomicAdd(&cnt[i], (unsigned)__popcll(am));
        base = __shfl(base, ldr, 64);
        if (pred) {
          const unsigned idx = base + (unsigned)__popcll(am & ((1ull << l) - 1ull));
          if (idx < 128u) cand[(size_t)i * 128 + idx] = cg;
        }
      }
    }
  }
}

// ------------------------------------------------------------- k_rescore ----
__global__ __launch_bounds__(128) void k_rescore(const float* __restrict__ x,
                                                 const double* __restrict__ sq64,
                                                 const int* __restrict__ cand,
                                                 const unsigned* __restrict__ cnt,
                                                 int* __restrict__ knn) {
  __shared__ float  xi[F_IN];
  __shared__ double keys[128];
  __shared__ int    ids[128];
  const int i = blockIdx.x, t = threadIdx.x;
  const unsigned cv = cnt[i];
  const int n = (int)(cv < 128u ? cv : 128u);
  if (t < F_IN) xi[t] = x[i * F_IN + t];
  __syncthreads();
  double key = 1e300; int id = 0x7fffffff;
  if (t < n) {
    id = cand[(size_t)i * 128 + t];
    const float4* xc4 = (const float4*)(x + (size_t)id * F_IN);
    double d0 = 0.0, d1 = 0.0, d2 = 0.0, d3 = 0.0;
#pragma unroll
    for (int q = 0; q < 16; ++q) {
      const float4 v = xc4[q];
      d0 += (double)xi[4*q+0] * (double)v.x;
      d1 += (double)xi[4*q+1] * (double)v.y;
      d2 += (double)xi[4*q+2] * (double)v.z;
      d3 += (double)xi[4*q+3] * (double)v.w;
    }
    key = sq64[id] - 2.0 * ((d0 + d1) + (d2 + d3));
  }
  keys[t] = key; ids[t] = id;
  __syncthreads();
  int rank = 0;
  for (int cix = 0; cix < n; ++cix) {
    const double kc = keys[cix]; const int ic = ids[cix];
    rank += (kc < key) || (kc == key && ic < id);
  }
  if (t < n && rank < K_NN) knn[i * K_NN + rank] = id;
}

// --------------------------------------------------------------- k_lin12 ----
__global__ __launch_bounds__(256, 2) void k_lin12(const float* __restrict__ x,
                                                  const float* __restrict__ w1,
                                                  const float* __restrict__ b1,
                                                  float* __restrict__ P,
                                                  float* __restrict__ Q) {
  __shared__ float wl[2 * F_IN][H_DIM];   // 64 KB
  for (int s = threadIdx.x; s < 2 * F_IN * H_DIM; s += 256) wl[s >> 7][s & 127] = w1[s];
  __syncthreads();
  const int node = blockIdx.x * 32 + (threadIdx.x & 31);
  const int ob = (threadIdx.x >> 5) * 16;   // 8 groups x 16 outs
  float accR[16], accQ[16];
#pragma unroll
  for (int o = 0; o < 16; ++o) { accR[o] = 0.f; accQ[o] = 0.f; }
  const float4* xr = (const float4*)(x + node * F_IN);
#define L1STEP(ff, xs) { \
    const float* wt_ = &wl[(ff)][ob]; \
    const float* wb_ = &wl[(ff) + F_IN][ob]; \
    _Pragma("unroll") \
    for (int o = 0; o < 16; o += 4) { \
      const float4 t4 = *(const float4*)(wt_ + o); \
      const float4 b4 = *(const float4*)(wb_ + o); \
      accR[o+0] = fmaf((xs), t4.x, accR[o+0]); accQ[o+0] = fmaf((xs), b4.x, accQ[o+0]); \
      accR[o+1] = fmaf((xs), t4.y, accR[o+1]); accQ[o+1] = fmaf((xs), b4.y, accQ[o+1]); \
      accR[o+2] = fmaf((xs), t4.z, accR[o+2]); accQ[o+2] = fmaf((xs), b4.z, accQ[o+2]); \
      accR[o+3] = fmaf((xs), t4.w, accR[o+3]); accQ[o+3] = fmaf((xs), b4.w, accQ[o+3]); } }
#pragma unroll 2
  for (int q = 0; q < 16; ++q) {
    const float4 xv = xr[q];
    L1STEP(4*q+0, xv.x); L1STEP(4*q+1, xv.y); L1STEP(4*q+2, xv.z); L1STEP(4*q+3, xv.w);
  }
#undef L1STEP
  float* pp = P + node * H_DIM + ob;
  float* qp = Q + node * H_DIM + ob;
#pragma unroll
  for (int o = 0; o < 16; ++o) {
    pp[o] = accR[o] - accQ[o] + b1[ob + o];
    qp[o] = accQ[o];
  }
}

// ------------------------------------------------------------ k_edgeconv ----
__global__ __launch_bounds__(256, 3) void k_edgeconv(const float* __restrict__ P,
                                                     const float* __restrict__ Q,
                                                     const float* __restrict__ w2,
                                                     const float* __restrict__ b2,
                                                     const int* __restrict__ knn,
                                                     float* __restrict__ h) {
  __shared__ __align__(16) _Float16 wt[H_DIM * 128];   // 32 KB, swizzled
  __shared__ __align__(16) _Float16 afr[4][2048];      // 16 KB, per-wave A frags
  const int tid = threadIdx.x;
  const int wv = tid >> 6, l = tid & 63;
  const int lane16 = l & 15, quad = l >> 4;

  {  // stage W2^T as f16 (swizzled chunk position)
    const int n = tid >> 1, part = tid & 1;
    const float* wsrc = w2 + n;
    _Float16* wdst = wt + n * 128;
#pragma unroll
    for (int c = 0; c < 8; ++c) {
      half8 hv;
#pragma unroll
      for (int u = 0; u < 8; ++u)
        hv[u] = (_Float16)wsrc[(size_t)(part * 64 + c * 8 + u) * H_DIM];
      *(half8*)(wdst + (((part * 8 + c) ^ (n & 15)) * 8)) = hv;
    }
  }
  __syncthreads();

  float b2r[8];
#pragma unroll
  for (int tile = 0; tile < 8; ++tile) b2r[tile] = b2[tile * 16 + lane16];

  _Float16* aw = afr[wv];
  for (int it = 0; it < 8; ++it) {
    const int i = blockIdx.x * 32 + wv * 8 + it;
    {
      const int m = lane16, kq = quad;
      const int j = knn[i * K_NN + m];
      const float4* pq = (const float4*)(P + (size_t)i * H_DIM + kq * 32);
      const float4* qq = (const float4*)(Q + (size_t)j * H_DIM + kq * 32);
#pragma unroll
      for (int c = 0; c < 4; ++c) {
        const float4 pa = pq[2 * c],     qa = qq[2 * c];
        const float4 pb = pq[2 * c + 1], qb = qq[2 * c + 1];
        half8 hv;
        hv[0] = (_Float16)fmaxf(pa.x + qa.x, 0.f);
        hv[1] = (_Float16)fmaxf(pa.y + qa.y, 0.f);
        hv[2] = (_Float16)fmaxf(pa.z + qa.z, 0.f);
        hv[3] = (_Float16)fmaxf(pa.w + qa.w, 0.f);
        hv[4] = (_Float16)fmaxf(pb.x + qb.x, 0.f);
        hv[5] = (_Float16)fmaxf(pb.y + qb.y, 0.f);
        hv[6] = (_Float16)fmaxf(pb.z + qb.z, 0.f);
        hv[7] = (_Float16)fmaxf(pb.w + qb.w, 0.f);
        *(half8*)(aw + kq * 512 + c * 128 + m * 8) = hv;
      }
    }
    half8 A[4];
#pragma unroll
    for (int kb = 0; kb < 4; ++kb) A[kb] = *(const half8*)(aw + kb * 512 + l * 8);
    floatx4 acc[8];
#pragma unroll
    for (int tile = 0; tile < 8; ++tile) acc[tile] = (floatx4)0.f;
#pragma unroll
    for (int kb = 0; kb < 4; ++kb) {
#pragma unroll
      for (int tile = 0; tile < 8; ++tile) {
        const half8 B = *(const half8*)(wt + (tile * 16 + lane16) * 128 +
                                        (((kb * 4 + quad) ^ lane16) * 8));
        acc[tile] = __builtin_amdgcn_mfma_f32_16x16x32_f16(A[kb], B, acc[tile], 0, 0, 0);
      }
    }
    float lse[4];
#pragma unroll
    for (int r = 0; r < 4; ++r) {
      float mx = acc[0][r] + b2r[0];
#pragma unroll
      for (int tile = 1; tile < 8; ++tile) mx = fmaxf(mx, acc[tile][r] + b2r[tile]);
      mx = fmaxf(mx, __shfl_xor(mx, 1, 64));
      mx = fmaxf(mx, __shfl_xor(mx, 2, 64));
      mx = fmaxf(mx, __shfl_xor(mx, 4, 64));
      mx = fmaxf(mx, __shfl_xor(mx, 8, 64));
      float e = 0.f;
#pragma unroll
      for (int tile = 0; tile < 8; ++tile) e += __expf(acc[tile][r] + b2r[tile] - mx);
      e += __shfl_xor(e, 1, 64);
      e += __shfl_xor(e, 2, 64);
      e += __shfl_xor(e, 4, 64);
      e += __shfl_xor(e, 8, 64);
      lse[r] = mx + __logf(e);
    }
#pragma unroll
    for (int tile = 0; tile < 8; ++tile) {
      float v = acc[tile][0] + b2r[tile] - lse[0];
#pragma unroll
      for (int r = 1; r < 4; ++r) v = fmaxf(v, acc[tile][r] + b2r[tile] - lse[r]);
      v = fmaxf(v, __shfl_xor(v, 16, 64));
      v = fmaxf(v, __shfl_xor(v, 32, 64));
      if (quad == 0) h[(size_t)i * H_DIM + tile * 16 + lane16] = v;
    }
  }
}

// ----------------------------------------------------------------- k_hw -----
__global__ __launch_bounds__(256) void k_hw(const float* __restrict__ h,
                                            const float* __restrict__ gw,
                                            float* __restrict__ hw) {
  __shared__ float wl[H_DIM][H_DIM];   // 64 KB
  for (int s = threadIdx.x; s < H_DIM * H_DIM; s += 256) wl[s >> 7][s & 127] = gw[s];
  __syncthreads();
  const int node = blockIdx.x * 32 + (threadIdx.x & 31);
  const int ob = (threadIdx.x >> 5) * 16;
  float acc[16];
#pragma unroll
  for (int o = 0; o < 16; ++o) acc[o] = 0.f;
  const float4* hr = (const float4*)(h + node * H_DIM);
#define HWSTEP(ff, xs) { \
    const float* wr = &wl[(ff)][ob]; \
    _Pragma("unroll") \
    for (int o = 0; o < 16; o += 4) { const float4 w4 = *(const float4*)(wr + o); \
      acc[o+0] = fmaf((xs), w4.x, acc[o+0]); \
      acc[o+1] = fmaf((xs), w4.y, acc[o+1]); \
      acc[o+2] = fmaf((xs), w4.z, acc[o+2]); \
      acc[o+3] = fmaf((xs), w4.w, acc[o+3]); } }
#pragma unroll 2
  for (int q = 0; q < 32; ++q) {
    const float4 hv = hr[q];
    HWSTEP(4*q+0, hv.x); HWSTEP(4*q+1, hv.y); HWSTEP(4*q+2, hv.z); HWSTEP(4*q+3, hv.w);
  }
#undef HWSTEP
  float* dp = hw + node * H_DIM + ob;
#pragma unroll
  for (int o = 0; o < 16; ++o) dp[o] = acc[o];
}

// --------------------------------------------------------------- k_heads ----
__global__ __launch_bounds__(256) void k_heads(const float* __restrict__ hw,
                                               const int* __restrict__ knn,
                                               const float* __restrict__ gb,
                                               const float* __restrict__ gow,
                                               const float* __restrict__ gob,
                                               const float* __restrict__ ow,
                                               const float* __restrict__ obv,
                                               float* __restrict__ out) {
  __shared__ unsigned int wgo[H_DIM][64];  // 32 KB
  __shared__ float hbuf[4][H_DIM];         // 2 KB
  for (int s = threadIdx.x; s < H_DIM * 64; s += 256) {
    const int f = s >> 6, l = s & 63;
    const unsigned short u0 = __half_as_ushort(__float2half(gow[f * H_DIM + l]));
    const unsigned short u1 = __half_as_ushort(__float2half(gow[f * H_DIM + 64 + l]));
    wgo[f][l] = (unsigned int)u0 | ((unsigned int)u1 << 16);
  }
  __syncthreads();
  const int wv = threadIdx.x >> 6, l = threadIdx.x & 63;
  const float gbl = gb[l], gbh = gb[64 + l];
  const float gobl = gob[l], gobh = gob[64 + l];
  for (int it = 0; it < 8; ++it) {
    const int i = blockIdx.x * 32 + wv * 8 + it;
    const int* kr = knn + i * K_NN;
    float s0 = hw[i * H_DIM + l], s1 = hw[i * H_DIM + 64 + l];  // self-loop
#pragma unroll
    for (int m = 0; m < K_NN; ++m) {
      const int j = kr[m];
      s0 += hw[j * H_DIM + l];
      s1 += hw[j * H_DIM + 64 + l];
    }
    const float hg0 = s0 * (1.0f / 17.0f) + gbl;   // deg == 17 by construction
    const float hg1 = s1 * (1.0f / 17.0f) + gbh;
    __syncthreads();
    hbuf[wv][l] = hg0; hbuf[wv][64 + l] = hg1;
    __syncthreads();
    float z0 = gobl, z1 = gobh;
#pragma unroll 4
    for (int f = 0; f < H_DIM; ++f) {
      const float hv = hbuf[wv][f];
      const unsigned int wvv = wgo[f][l];
      const float w0 = __half2float(__ushort_as_half((unsigned short)(wvv & 0xffffu)));
      const float w1 = __half2float(__ushort_as_half((unsigned short)(wvv >> 16)));
      z0 = fmaf(hv, w0, z0);
      z1 = fmaf(hv, w1, z1);
    }
    float mx = fmaxf(z0, z1);
#pragma unroll
    for (int s = 1; s < 64; s <<= 1) mx = fmaxf(mx, __shfl_xor(mx, s, 64));
    const float e0 = __expf(z0 - mx), e1 = __expf(z1 - mx);
    float sm = e0 + e1;
#pragma unroll
    for (int s = 1; s < 64; s <<= 1) sm += __shfl_xor(sm, s, 64);
    const float h20 = e0 / sm, h21 = e1 / sm;
    float zc[O_DIM];
#pragma unroll
    for (int c = 0; c < O_DIM; ++c) {
      float a = h20 * ow[l * O_DIM + c] + h21 * ow[(64 + l) * O_DIM + c];
#pragma unroll
      for (int s = 1; s < 64; s <<= 1) a += __shfl_xor(a, s, 64);
      zc[c] = a + obv[c];
    }
    float m10 = zc[0];
#pragma unroll
    for (int c = 1; c < O_DIM; ++c) m10 = fmaxf(m10, zc[c]);
    float es[O_DIM]; float s10 = 0.f;
#pragma unroll
    for (int c = 0; c < O_DIM; ++c) { es[c] = __expf(zc[c] - m10); s10 += es[c]; }
    const float inv = 1.0f / s10;
    if (l < O_DIM) {
      float v = es[0];
#pragma unroll
      for (int c = 1; c < O_DIM; ++c) if (l == c) v = es[c];
      out[i * O_DIM + l] = v * inv;
    }
  }
}

// ---------------------------------------------------------------------------
extern "C" void kernel_launch(void* const* d_in, const int* in_sizes, int n_in,
                              void* d_out, int out_size, void* d_ws, size_t ws_size,
                              hipStream_t stream) {
  (void)in_sizes; (void)n_in; (void)out_size; (void)ws_size;
  const float* x   = (const float*)d_in[0];
  const float* w1  = (const float*)d_in[2];
  const float* b1  = (const float*)d_in[3];
  const float* w2  = (const float*)d_in[4];
  const float* b2  = (const float*)d_in[5];
  const float* gw  = (const float*)d_in[6];
  const float* gb  = (const float*)d_in[7];
  const float* gow = (const float*)d_in[8];
  const float* gob = (const float*)d_in[9];
  const float* ow  = (const float*)d_in[10];
  const float* obv = (const float*)d_in[11];
  float* out = (float*)d_out;

  char* ws = (char*)d_ws;
  constexpr size_t OFF_SQ   = 0;                                          // 64 KB
  constexpr size_t OFF_SQ64 = OFF_SQ   + (size_t)N_NODES * 4;             // 128 KB
  constexpr size_t OFF_XH   = OFF_SQ64 + (size_t)N_NODES * 8;             // 2 MB
  constexpr size_t OFF_CNT  = OFF_XH   + (size_t)N_NODES * F_IN * 2;      // 64 KB
  constexpr size_t OFF_CAND = OFF_CNT  + (size_t)N_NODES * 4;             // 8 MB
  constexpr size_t OFF_SUBG = OFF_CAND + (size_t)N_NODES * 128 * 4;       // 32 MB
  // subg is dead after k_filter; knn/Q/h live inside its 32 MB afterwards
  constexpr size_t OFF_KNN  = OFF_SUBG;                                   // 1 MB
  constexpr size_t OFF_Q    = OFF_SUBG + (size_t)N_NODES * K_NN * 4;      // 8 MB
  constexpr size_t OFF_H    = OFF_Q    + (size_t)N_NODES * H_DIM * 4;     // 8 MB
  float*     sq   = (float*)    (ws + OFF_SQ);
  double*    sq64 = (double*)   (ws + OFF_SQ64);
  _Float16*  xh   = (_Float16*) (ws + OFF_XH);
  unsigned*  cnt  = (unsigned*) (ws + OFF_CNT);
  int*       cand = (int*)      (ws + OFF_CAND);
  char*      subg = (char*)     (ws + OFF_SUBG);
  int*       knn  = (int*)      (ws + OFF_KNN);
  float*     Q    = (float*)    (ws + OFF_Q);
  float*     h    = (float*)    (ws + OFF_H);
  float*     P    = (float*)    (ws + OFF_CAND);  // P aliases cand (dead after rescore)
  float*     hw   = P;                            // hw aliases P (dead after edgeconv)

  k_prep    <<<N_NODES / 256, 256, 0, stream>>>(x, sq, sq64, xh, cnt);
  k_gemm    <<<2048,          256, 0, stream>>>(xh, sq, subg);
  k_filter  <<<N_NODES / 4,   256, 0, stream>>>(xh, sq, subg, cnt, cand);
  k_rescore <<<N_NODES,       128, 0, stream>>>(x, sq64, cand, cnt, knn);
  k_lin12   <<<N_NODES / 32,  256, 0, stream>>>(x, w1, b1, P, Q);
  k_edgeconv<<<N_NODES / 32,  256, 0, stream>>>(P, Q, w2, b2, knn, h);
  k_hw      <<<N_NODES / 32,  256, 0, stream>>>(h, gw, hw);
  k_heads   <<<N_NODES / 32,  256, 0, stream>>>(hw, knn, gb, gow, gob, ow, obv, out);
}

// Round 9
// 349.411 us; speedup vs baseline: 1.7956x; 1.1351x over previous
//
#include <hip/hip_runtime.h>
#include <hip/hip_fp16.h>
#include <cfloat>
#include <cmath>
#include <string.h>

// GNN_Combo pipeline. Round 9: f16 gather tables (Ph/Qh/hwh, each 4 MB ->
// per-XCD-L2-resident), pipelined edgeconv gathers, coalesced f16 heads
// gather. kNN path (gemm->filter->rescore) unchanged from round 7b.
// N=16384 nodes, F=64 in-features, H=128 hidden, K=16 neighbors, O=10 classes.

#define N_NODES 16384
#define F_IN    64
#define H_DIM   128
#define K_NN    16
#define O_DIM   10

typedef _Float16 half8  __attribute__((ext_vector_type(8)));
typedef _Float16 half4v __attribute__((ext_vector_type(4)));
typedef _Float16 half2v __attribute__((ext_vector_type(2)));
typedef float    floatx4 __attribute__((ext_vector_type(4)));

__device__ __forceinline__ void async_copy16(void* lds, const void* g) {
  __builtin_amdgcn_global_load_lds(
      (const __attribute__((address_space(1))) unsigned int*)g,
      (__attribute__((address_space(3))) unsigned int*)lds, 16, 0, 0);
}

__device__ __forceinline__ unsigned pack2h(float a, float b) {
  half2v p; p[0] = (_Float16)a; p[1] = (_Float16)b;
  unsigned u; __builtin_memcpy(&u, &p, 4); return u;
}
__device__ __forceinline__ float unpacklo(unsigned u) {
  half2v p; __builtin_memcpy(&p, &u, 4); return (float)p[0];
}
__device__ __forceinline__ float unpackhi(unsigned u) {
  half2v p; __builtin_memcpy(&p, &u, 4); return (float)p[1];
}

// ---------------------------------------------------------------- k_prep ----
__global__ __launch_bounds__(256) void k_prep(const float* __restrict__ x,
                                              float* __restrict__ sq,
                                              double* __restrict__ sq64,
                                              _Float16* __restrict__ xh,
                                              unsigned* __restrict__ cnt) {
  const int i = blockIdx.x * 256 + threadIdx.x;
  if (i >= N_NODES) return;
  const float4* r = (const float4*)(x + i * F_IN);
  float s = 0.f; double sd = 0.0;
#pragma unroll
  for (int q = 0; q < 16; ++q) {
    const float4 v = r[q];
    s += v.x*v.x + v.y*v.y + v.z*v.z + v.w*v.w;
    sd += (double)v.x*v.x + (double)v.y*v.y + (double)v.z*v.z + (double)v.w*v.w;
    half4v hv;
    hv[0] = (_Float16)v.x; hv[1] = (_Float16)v.y;
    hv[2] = (_Float16)v.z; hv[3] = (_Float16)v.w;
    *(half4v*)(xh + (size_t)i * F_IN + 4 * q) = hv;
  }
  sq[i] = s; sq64[i] = sd; cnt[i] = 0;
}

// ---------------------------------------------------------------- k_gemm ----
// (unchanged from round 7b) Transposed MFMA; per-(row,16-col-subtile) f16 mins.
__global__ __launch_bounds__(256) void k_gemm(const _Float16* __restrict__ xh,
                                              const float* __restrict__ sq,
                                              char* __restrict__ subg) {
  __shared__ __align__(16) _Float16 stage[128 * 64];  // 16 KB, swizzled
  __shared__ float sqs[128];
  const int tid = threadIdx.x;
  const int wv = tid >> 6, l = tid & 63;
  const int lane16 = l & 15, quad = l >> 4;
  const int rowblk = (blockIdx.x >> 5) * 256;
  const int seg = blockIdx.x & 31;
  const int rw = rowblk + wv * 64;

  half8 B[4][2];
#pragma unroll
  for (int s = 0; s < 4; ++s) {
    const _Float16* bp = xh + (size_t)(rw + s * 16 + lane16) * F_IN + quad * 8;
    B[s][0] = *(const half8*)(bp);
    B[s][1] = *(const half8*)(bp + 32);
  }

  const int lcol8 = l >> 3;
  const int lchk  = (l & 7) ^ lcol8;
  const size_t lgoff = (size_t)lcol8 * F_IN + lchk * 8;

  for (int tile = 0; tile < 4; ++tile) {
    const int c0 = seg * 512 + tile * 128;
    __syncthreads();
    if (tid < 128) sqs[tid] = sq[c0 + tid];
#pragma unroll
    for (int q = 0; q < 4; ++q) {
      const int grp = wv * 4 + q;
      async_copy16(stage + grp * 512,
                   xh + (size_t)(c0 + grp * 8) * F_IN + lgoff);
    }
    __syncthreads();

    float sprev[4];
    unsigned pk[4][4];
#pragma unroll
    for (int st = 0; st < 8; ++st) {
      const _Float16* base = stage + (st * 16 + lane16) * 64;
      const int sw = lane16 & 7;
      const half8 A0 = *(const half8*)(base + ((quad ^ sw) * 8));
      const half8 A1 = *(const half8*)(base + (((4 + quad) ^ sw) * 8));
      const floatx4 sq4 = *(const floatx4*)(sqs + st * 16 + quad * 4);
      floatx4 acc[4];
#pragma unroll
      for (int s = 0; s < 4; ++s) acc[s] = (floatx4)0.f;
#pragma unroll
      for (int s = 0; s < 4; ++s)
        acc[s] = __builtin_amdgcn_mfma_f32_16x16x32_f16(A0, B[s][0], acc[s], 0, 0, 0);
#pragma unroll
      for (int s = 0; s < 4; ++s)
        acc[s] = __builtin_amdgcn_mfma_f32_16x16x32_f16(A1, B[s][1], acc[s], 0, 0, 0);
#pragma unroll
      for (int s = 0; s < 4; ++s) {
        const float k0 = fmaf(-2.f, acc[s][0], sq4[0]);
        const float k1 = fmaf(-2.f, acc[s][1], sq4[1]);
        const float k2 = fmaf(-2.f, acc[s][2], sq4[2]);
        const float k3 = fmaf(-2.f, acc[s][3], sq4[3]);
        float m = fminf(fminf(k0, k1), fminf(k2, k3));
        m = fminf(m, __shfl_xor(m, 16, 64));
        m = fminf(m, __shfl_xor(m, 32, 64));
        if ((st & 1) == 0) sprev[s] = m;
        else pk[s][st >> 1] = pack2h(sprev[s], m);
      }
    }
    unsigned o0 = pk[0][0], o1 = pk[0][1], o2 = pk[0][2], o3 = pk[0][3];
    if (quad == 1) { o0 = pk[1][0]; o1 = pk[1][1]; o2 = pk[1][2]; o3 = pk[1][3]; }
    if (quad == 2) { o0 = pk[2][0]; o1 = pk[2][1]; o2 = pk[2][2]; o3 = pk[2][3]; }
    if (quad == 3) { o0 = pk[3][0]; o1 = pk[3][1]; o2 = pk[3][2]; o3 = pk[3][3]; }
    const int row = rw + quad * 16 + lane16;
    uint4 ov; ov.x = o0; ov.y = o1; ov.z = o2; ov.w = o3;
    *(uint4*)(subg + ((size_t)row * 1024 + seg * 32 + tile * 8) * 2) = ov;
  }
}

// -------------------------------------------------------------- k_filter ----
// (unchanged from round 7b)
__global__ __launch_bounds__(256) void k_filter(const _Float16* __restrict__ xh,
                                                const float* __restrict__ sq,
                                                const char* __restrict__ subg,
                                                unsigned* __restrict__ cnt,
                                                int* __restrict__ cand) {
  const int l = threadIdx.x & 63;
  const int i = blockIdx.x * 4 + (threadIdx.x >> 6);
  const int part = l & 3, c = l >> 2;

  float xi[16];
  {
    const half8* xp = (const half8*)(xh + (size_t)i * F_IN + part * 16);
    const half8 a = xp[0], b = xp[1];
#pragma unroll
    for (int j = 0; j < 8; ++j) { xi[j] = (float)a[j]; xi[8 + j] = (float)b[j]; }
  }
  float subs[16];
  {
    const uint4 a = *(const uint4*)(subg + ((size_t)i * 1024 + l * 16) * 2);
    const uint4 b = *(const uint4*)(subg + ((size_t)i * 1024 + l * 16) * 2 + 16);
    subs[0] = unpacklo(a.x); subs[1] = unpackhi(a.x);
    subs[2] = unpacklo(a.y); subs[3] = unpackhi(a.y);
    subs[4] = unpacklo(a.z); subs[5] = unpackhi(a.z);
    subs[6] = unpacklo(a.w); subs[7] = unpackhi(a.w);
    subs[8] = unpacklo(b.x); subs[9] = unpackhi(b.x);
    subs[10] = unpacklo(b.y); subs[11] = unpackhi(b.y);
    subs[12] = unpacklo(b.z); subs[13] = unpackhi(b.z);
    subs[14] = unpacklo(b.w); subs[15] = unpackhi(b.w);
  }
  float cmin = subs[0];
#pragma unroll
  for (int t = 1; t < 16; ++t) cmin = fminf(cmin, subs[t]);
  int rank = 0;
#pragma unroll 4
  for (int j = 0; j < 64; ++j) {
    const float vj = __shfl(cmin, j, 64);
    rank += (vj < cmin) || (vj == cmin && j < l);
  }
  const unsigned long long rm = __ballot(rank == 15);
  const int srcl = __ffsll((long long)rm) - 1;
  const float thr = __shfl(cmin, srcl, 64) + 0.25f;

  unsigned selmask = 0;
#pragma unroll
  for (int t = 0; t < 16; ++t) selmask |= (subs[t] <= thr) ? (1u << t) : 0u;

  unsigned long long act;
  while ((act = __ballot(selmask != 0)) != 0ull) {
    const int src = __ffsll((long long)act) - 1;
    unsigned m = __shfl(selmask, src, 64);
    if (l == src) selmask = 0;
    while (m) {
      const int b = __ffs(m) - 1; m &= m - 1;
      const int sid = src * 16 + b;
      const int cg = sid * 16 + c;
      float d = 0.f;
      {
        const half8* gp = (const half8*)(xh + (size_t)cg * F_IN + part * 16);
        const half8 g0 = gp[0], g1 = gp[1];
#pragma unroll
        for (int j = 0; j < 8; ++j) {
          d = fmaf(xi[j], (float)g0[j], d);
          d = fmaf(xi[8 + j], (float)g1[j], d);
        }
      }
      d += __shfl_xor(d, 1, 64);
      d += __shfl_xor(d, 2, 64);
      const float key = fmaf(-2.f, d, sq[cg]);
      const bool pred = (part == 0) && (key <= thr);
      const unsigned long long am = __ballot(pred);
      if (am) {
        const int ldr = __ffsll((long long)am) - 1;
        unsigned base = 0;
        if (l == ldr) base = atomicAdd(&cnt[i], (unsigned)__popcll(am));
        base = __shfl(base, ldr, 64);
        if (pred) {
          const unsigned idx = base + (unsigned)__popcll(am & ((1ull << l) - 1ull));
          if (idx < 128u) cand[(size_t)i * 128 + idx] = cg;
        }
      }
    }
  }
}

// ------------------------------------------------------------- k_rescore ----
__global__ __launch_bounds__(128) void k_rescore(const float* __restrict__ x,
                                                 const double* __restrict__ sq64,
                                                 const int* __restrict__ cand,
                                                 const unsigned* __restrict__ cnt,
                                                 int* __restrict__ knn) {
  __shared__ float  xi[F_IN];
  __shared__ double keys[128];
  __shared__ int    ids[128];
  const int i = blockIdx.x, t = threadIdx.x;
  const unsigned cv = cnt[i];
  const int n = (int)(cv < 128u ? cv : 128u);
  if (t < F_IN) xi[t] = x[i * F_IN + t];
  __syncthreads();
  double key = 1e300; int id = 0x7fffffff;
  if (t < n) {
    id = cand[(size_t)i * 128 + t];
    const float4* xc4 = (const float4*)(x + (size_t)id * F_IN);
    double d0 = 0.0, d1 = 0.0, d2 = 0.0, d3 = 0.0;
#pragma unroll
    for (int q = 0; q < 16; ++q) {
      const float4 v = xc4[q];
      d0 += (double)xi[4*q+0] * (double)v.x;
      d1 += (double)xi[4*q+1] * (double)v.y;
      d2 += (double)xi[4*q+2] * (double)v.z;
      d3 += (double)xi[4*q+3] * (double)v.w;
    }
    key = sq64[id] - 2.0 * ((d0 + d1) + (d2 + d3));
  }
  keys[t] = key; ids[t] = id;
  __syncthreads();
  int rank = 0;
  for (int cix = 0; cix < n; ++cix) {
    const double kc = keys[cix]; const int ic = ids[cix];
    rank += (kc < key) || (kc == key && ic < id);
  }
  if (t < n && rank < K_NN) knn[i * K_NN + rank] = id;
}

// --------------------------------------------------------------- k_lin12 ----
// One pass: P = x@(W1top-W1bot)+b1 -> f16 Ph; Q = x@W1bot -> f16 Qh.
__global__ __launch_bounds__(256, 2) void k_lin12(const float* __restrict__ x,
                                                  const float* __restrict__ w1,
                                                  const float* __restrict__ b1,
                                                  _Float16* __restrict__ Ph,
                                                  _Float16* __restrict__ Qh) {
  __shared__ float wl[2 * F_IN][H_DIM];   // 64 KB
  for (int s = threadIdx.x; s < 2 * F_IN * H_DIM; s += 256) wl[s >> 7][s & 127] = w1[s];
  __syncthreads();
  const int node = blockIdx.x * 32 + (threadIdx.x & 31);
  const int ob = (threadIdx.x >> 5) * 16;
  float accR[16], accQ[16];
#pragma unroll
  for (int o = 0; o < 16; ++o) { accR[o] = 0.f; accQ[o] = 0.f; }
  const float4* xr = (const float4*)(x + node * F_IN);
#define L1STEP(ff, xs) { \
    const float* wt_ = &wl[(ff)][ob]; \
    const float* wb_ = &wl[(ff) + F_IN][ob]; \
    _Pragma("unroll") \
    for (int o = 0; o < 16; o += 4) { \
      const float4 t4 = *(const float4*)(wt_ + o); \
      const float4 b4 = *(const float4*)(wb_ + o); \
      accR[o+0] = fmaf((xs), t4.x, accR[o+0]); accQ[o+0] = fmaf((xs), b4.x, accQ[o+0]); \
      accR[o+1] = fmaf((xs), t4.y, accR[o+1]); accQ[o+1] = fmaf((xs), b4.y, accQ[o+1]); \
      accR[o+2] = fmaf((xs), t4.z, accR[o+2]); accQ[o+2] = fmaf((xs), b4.z, accQ[o+2]); \
      accR[o+3] = fmaf((xs), t4.w, accR[o+3]); accQ[o+3] = fmaf((xs), b4.w, accQ[o+3]); } }
#pragma unroll 2
  for (int q = 0; q < 16; ++q) {
    const float4 xv = xr[q];
    L1STEP(4*q+0, xv.x); L1STEP(4*q+1, xv.y); L1STEP(4*q+2, xv.z); L1STEP(4*q+3, xv.w);
  }
#undef L1STEP
  _Float16* pp = Ph + (size_t)node * H_DIM + ob;
  _Float16* qp = Qh + (size_t)node * H_DIM + ob;
#pragma unroll
  for (int o = 0; o < 16; o += 4) {
    half4v hp, hq;
#pragma unroll
    for (int u = 0; u < 4; ++u) {
      hp[u] = (_Float16)(accR[o+u] - accQ[o+u] + b1[ob + o + u]);
      hq[u] = (_Float16)accQ[o+u];
    }
    *(half4v*)(pp + o) = hp;
    *(half4v*)(qp + o) = hq;
  }
}

// ------------------------------------------------------------ k_edgeconv ----
// f16 gathers (Qh 4 MB: per-XCD-L2 resident), knn pre-load, cross-node
// software pipeline: node it+1's P/Q gathers issue before node it's LDS
// build + MFMA, hiding gather latency behind ~full node compute.
__global__ __launch_bounds__(256, 2) void k_edgeconv(const _Float16* __restrict__ Ph,
                                                     const _Float16* __restrict__ Qh,
                                                     const float* __restrict__ w2,
                                                     const float* __restrict__ b2,
                                                     const int* __restrict__ knn,
                                                     float* __restrict__ h) {
  __shared__ __align__(16) _Float16 wt[H_DIM * 128];   // 32 KB, swizzled
  __shared__ __align__(16) _Float16 afr[4][2048];      // 16 KB, per-wave A frags
  const int tid = threadIdx.x;
  const int wv = tid >> 6, l = tid & 63;
  const int lane16 = l & 15, quad = l >> 4;

  {  // stage W2^T as f16 (swizzled chunk position)
    const int n = tid >> 1, part = tid & 1;
    const float* wsrc = w2 + n;
    _Float16* wdst = wt + n * 128;
#pragma unroll
    for (int c = 0; c < 8; ++c) {
      half8 hv;
#pragma unroll
      for (int u = 0; u < 8; ++u)
        hv[u] = (_Float16)wsrc[(size_t)(part * 64 + c * 8 + u) * H_DIM];
      *(half8*)(wdst + (((part * 8 + c) ^ (n & 15)) * 8)) = hv;
    }
  }
  __syncthreads();

  float b2r[8];
#pragma unroll
  for (int tile = 0; tile < 8; ++tile) b2r[tile] = b2[tile * 16 + lane16];

  const int i0 = blockIdx.x * 32 + wv * 8;
  int js[8];
#pragma unroll
  for (int it = 0; it < 8; ++it) js[it] = knn[(i0 + it) * K_NN + lane16];

  _Float16* aw = afr[wv];
  half8 pc[4], qc[4];
  {
    const half8* pr = (const half8*)(Ph + (size_t)i0 * H_DIM + quad * 32);
    const half8* qr = (const half8*)(Qh + (size_t)js[0] * H_DIM + quad * 32);
#pragma unroll
    for (int c = 0; c < 4; ++c) { pc[c] = pr[c]; qc[c] = qr[c]; }
  }
  for (int it = 0; it < 8; ++it) {
    const int i = i0 + it;
    half8 pn[4], qn[4];
    if (it < 7) {   // issue next node's gathers before current's LDS build
      const half8* pr = (const half8*)(Ph + (size_t)(i + 1) * H_DIM + quad * 32);
      const half8* qr = (const half8*)(Qh + (size_t)js[it + 1] * H_DIM + quad * 32);
#pragma unroll
      for (int c = 0; c < 4; ++c) { pn[c] = pr[c]; qn[c] = qr[c]; }
    }
    // ---- build A = relu(Ph_i + Qh_j) in fragment order (f16 math) ----
#pragma unroll
    for (int c = 0; c < 4; ++c) {
      half8 z = pc[c] + qc[c];
      half8 r;
#pragma unroll
      for (int u = 0; u < 8; ++u) r[u] = z[u] > (_Float16)0 ? z[u] : (_Float16)0;
      *(half8*)(aw + quad * 512 + c * 128 + lane16 * 8) = r;
    }
    half8 A[4];
#pragma unroll
    for (int kb = 0; kb < 4; ++kb) A[kb] = *(const half8*)(aw + kb * 512 + l * 8);
    floatx4 acc[8];
#pragma unroll
    for (int tile = 0; tile < 8; ++tile) acc[tile] = (floatx4)0.f;
#pragma unroll
    for (int kb = 0; kb < 4; ++kb) {
#pragma unroll
      for (int tile = 0; tile < 8; ++tile) {
        const half8 B = *(const half8*)(wt + (tile * 16 + lane16) * 128 +
                                        (((kb * 4 + quad) ^ lane16) * 8));
        acc[tile] = __builtin_amdgcn_mfma_f32_16x16x32_f16(A[kb], B, acc[tile], 0, 0, 0);
      }
    }
    float lse[4];
#pragma unroll
    for (int r = 0; r < 4; ++r) {
      float mx = acc[0][r] + b2r[0];
#pragma unroll
      for (int tile = 1; tile < 8; ++tile) mx = fmaxf(mx, acc[tile][r] + b2r[tile]);
      mx = fmaxf(mx, __shfl_xor(mx, 1, 64));
      mx = fmaxf(mx, __shfl_xor(mx, 2, 64));
      mx = fmaxf(mx, __shfl_xor(mx, 4, 64));
      mx = fmaxf(mx, __shfl_xor(mx, 8, 64));
      float e = 0.f;
#pragma unroll
      for (int tile = 0; tile < 8; ++tile) e += __expf(acc[tile][r] + b2r[tile] - mx);
      e += __shfl_xor(e, 1, 64);
      e += __shfl_xor(e, 2, 64);
      e += __shfl_xor(e, 4, 64);
      e += __shfl_xor(e, 8, 64);
      lse[r] = mx + __logf(e);
    }
#pragma unroll
    for (int tile = 0; tile < 8; ++tile) {
      float v = acc[tile][0] + b2r[tile] - lse[0];
#pragma unroll
      for (int r = 1; r < 4; ++r) v = fmaxf(v, acc[tile][r] + b2r[tile] - lse[r]);
      v = fmaxf(v, __shfl_xor(v, 16, 64));
      v = fmaxf(v, __shfl_xor(v, 32, 64));
      if (quad == 0) h[(size_t)i * H_DIM + tile * 16 + lane16] = v;
    }
#pragma unroll
    for (int c = 0; c < 4; ++c) { pc[c] = pn[c]; qc[c] = qn[c]; }
  }
}

// ----------------------------------------------------------------- k_hw -----
// hw = h @ gcn_w, output f16 (hwh 4 MB -> L2-resident for k_heads gathers).
__global__ __launch_bounds__(256) void k_hw(const float* __restrict__ h,
                                            const float* __restrict__ gw,
                                            _Float16* __restrict__ hwh) {
  __shared__ float wl[H_DIM][H_DIM];   // 64 KB
  for (int s = threadIdx.x; s < H_DIM * H_DIM; s += 256) wl[s >> 7][s & 127] = gw[s];
  __syncthreads();
  const int node = blockIdx.x * 32 + (threadIdx.x & 31);
  const int ob = (threadIdx.x >> 5) * 16;
  float acc[16];
#pragma unroll
  for (int o = 0; o < 16; ++o) acc[o] = 0.f;
  const float4* hr = (const float4*)(h + node * H_DIM);
#define HWSTEP(ff, xs) { \
    const float* wr = &wl[(ff)][ob]; \
    _Pragma("unroll") \
    for (int o = 0; o < 16; o += 4) { const float4 w4 = *(const float4*)(wr + o); \
      acc[o+0] = fmaf((xs), w4.x, acc[o+0]); \
      acc[o+1] = fmaf((xs), w4.y, acc[o+1]); \
      acc[o+2] = fmaf((xs), w4.z, acc[o+2]); \
      acc[o+3] = fmaf((xs), w4.w, acc[o+3]); } }
#pragma unroll 2
  for (int q = 0; q < 32; ++q) {
    const float4 hv = hr[q];
    HWSTEP(4*q+0, hv.x); HWSTEP(4*q+1, hv.y); HWSTEP(4*q+2, hv.z); HWSTEP(4*q+3, hv.w);
  }
#undef HWSTEP
  _Float16* dp = hwh + (size_t)node * H_DIM + ob;
#pragma unroll
  for (int o = 0; o < 16; o += 4) {
    half4v hv;
#pragma unroll
    for (int u = 0; u < 4; ++u) hv[u] = (_Float16)acc[o + u];
    *(half4v*)(dp + o) = hv;
  }
}

// --------------------------------------------------------------- k_heads ----
// Lane l owns channels (2l, 2l+1): one coalesced 4-B load per lane per
// neighbor row (256 B/row total, hwh L2-resident).
__global__ __launch_bounds__(256) void k_heads(const _Float16* __restrict__ hwh,
                                               const int* __restrict__ knn,
                                               const float* __restrict__ gb,
                                               const float* __restrict__ gow,
                                               const float* __restrict__ gob,
                                               const float* __restrict__ ow,
                                               const float* __restrict__ obv,
                                               float* __restrict__ out) {
  __shared__ unsigned int wgo[H_DIM][64];  // 32 KB: (gow[f][2l], gow[f][2l+1]) f16
  __shared__ float hbuf[4][H_DIM];         // 2 KB
  for (int s = threadIdx.x; s < H_DIM * 64; s += 256) {
    const int f = s >> 6, l = s & 63;
    wgo[f][l] = pack2h(gow[f * H_DIM + 2 * l], gow[f * H_DIM + 2 * l + 1]);
  }
  __syncthreads();
  const int wv = threadIdx.x >> 6, l = threadIdx.x & 63;
  const unsigned* hw32 = (const unsigned*)hwh;   // row = 64 uints
  const float gbl = gb[2 * l], gbh = gb[2 * l + 1];
  const float gobl = gob[2 * l], gobh = gob[2 * l + 1];
  for (int it = 0; it < 8; ++it) {
    const int i = blockIdx.x * 32 + wv * 8 + it;
    const int* kr = knn + i * K_NN;
    unsigned u = hw32[(size_t)i * 64 + l];       // self-loop
    float s0 = unpacklo(u), s1 = unpackhi(u);
#pragma unroll
    for (int m = 0; m < K_NN; ++m) {
      const unsigned um = hw32[(size_t)kr[m] * 64 + l];
      s0 += unpacklo(um);
      s1 += unpackhi(um);
    }
    const float hg0 = s0 * (1.0f / 17.0f) + gbl;   // deg == 17 by construction
    const float hg1 = s1 * (1.0f / 17.0f) + gbh;
    hbuf[wv][2 * l] = hg0; hbuf[wv][2 * l + 1] = hg1;   // per-wave slice
    float z0 = gobl, z1 = gobh;
#pragma unroll 4
    for (int f = 0; f < H_DIM; ++f) {
      const float hv = hbuf[wv][f];
      const unsigned int wvv = wgo[f][l];
      z0 = fmaf(hv, unpacklo(wvv), z0);
      z1 = fmaf(hv, unpackhi(wvv), z1);
    }
    float mx = fmaxf(z0, z1);
#pragma unroll
    for (int s = 1; s < 64; s <<= 1) mx = fmaxf(mx, __shfl_xor(mx, s, 64));
    const float e0 = __expf(z0 - mx), e1 = __expf(z1 - mx);
    float sm = e0 + e1;
#pragma unroll
    for (int s = 1; s < 64; s <<= 1) sm += __shfl_xor(sm, s, 64);
    const float h20 = e0 / sm, h21 = e1 / sm;
    float zc[O_DIM];
#pragma unroll
    for (int c = 0; c < O_DIM; ++c) {
      float a = h20 * ow[(2 * l) * O_DIM + c] + h21 * ow[(2 * l + 1) * O_DIM + c];
#pragma unroll
      for (int s = 1; s < 64; s <<= 1) a += __shfl_xor(a, s, 64);
      zc[c] = a + obv[c];
    }
    float m10 = zc[0];
#pragma unroll
    for (int c = 1; c < O_DIM; ++c) m10 = fmaxf(m10, zc[c]);
    float es[O_DIM]; float s10 = 0.f;
#pragma unroll
    for (int c = 0; c < O_DIM; ++c) { es[c] = __expf(zc[c] - m10); s10 += es[c]; }
    const float inv = 1.0f / s10;
    if (l < O_DIM) {
      float v = es[0];
#pragma unroll
      for (int c = 1; c < O_DIM; ++c) if (l == c) v = es[c];
      out[i * O_DIM + l] = v * inv;
    }
  }
}

// ---------------------------------------------------------------------------
extern "C" void kernel_launch(void* const* d_in, const int* in_sizes, int n_in,
                              void* d_out, int out_size, void* d_ws, size_t ws_size,
                              hipStream_t stream) {
  (void)in_sizes; (void)n_in; (void)out_size; (void)ws_size;
  const float* x   = (const float*)d_in[0];
  const float* w1  = (const float*)d_in[2];
  const float* b1  = (const float*)d_in[3];
  const float* w2  = (const float*)d_in[4];
  const float* b2  = (const float*)d_in[5];
  const float* gw  = (const float*)d_in[6];
  const float* gb  = (const float*)d_in[7];
  const float* gow = (const float*)d_in[8];
  const float* gob = (const float*)d_in[9];
  const float* ow  = (const float*)d_in[10];
  const float* obv = (const float*)d_in[11];
  float* out = (float*)d_out;

  char* ws = (char*)d_ws;
  constexpr size_t MB = 1024 * 1024;
  constexpr size_t OFF_SQ   = 0;                                          // 64 KB
  constexpr size_t OFF_SQ64 = OFF_SQ   + (size_t)N_NODES * 4;             // 128 KB
  constexpr size_t OFF_XH   = OFF_SQ64 + (size_t)N_NODES * 8;             // 2 MB
  constexpr size_t OFF_CNT  = OFF_XH   + (size_t)N_NODES * F_IN * 2;      // 64 KB
  constexpr size_t OFF_CAND = OFF_CNT  + (size_t)N_NODES * 4;             // 8 MB
  constexpr size_t OFF_SUBG = OFF_CAND + (size_t)N_NODES * 128 * 4;       // 32 MB
  // cand (8 MB) dead after k_rescore -> Ph/Qh (4 MB each) live there.
  // subg (32 MB) dead after k_filter -> knn | h | hwh live there.
  constexpr size_t OFF_KNN  = OFF_SUBG;                                   // 1 MB
  constexpr size_t OFF_H    = OFF_SUBG + 1 * MB;                          // 8 MB f32
  constexpr size_t OFF_HWH  = OFF_SUBG + 9 * MB;                          // 4 MB f16
  float*     sq   = (float*)    (ws + OFF_SQ);
  double*    sq64 = (double*)   (ws + OFF_SQ64);
  _Float16*  xh   = (_Float16*) (ws + OFF_XH);
  unsigned*  cnt  = (unsigned*) (ws + OFF_CNT);
  int*       cand = (int*)      (ws + OFF_CAND);
  char*      subg = (char*)     (ws + OFF_SUBG);
  int*       knn  = (int*)      (ws + OFF_KNN);
  float*     h    = (float*)    (ws + OFF_H);
  _Float16*  hwh  = (_Float16*) (ws + OFF_HWH);
  _Float16*  Ph   = (_Float16*) (ws + OFF_CAND);
  _Float16*  Qh   = (_Float16*) (ws + OFF_CAND + 4 * MB);

  k_prep    <<<N_NODES / 256, 256, 0, stream>>>(x, sq, sq64, xh, cnt);
  k_gemm    <<<2048,          256, 0, stream>>>(xh, sq, subg);
  k_filter  <<<N_NODES / 4,   256, 0, stream>>>(xh, sq, subg, cnt, cand);
  k_rescore <<<N_NODES,       128, 0, stream>>>(x, sq64, cand, cnt, knn);
  k_lin12   <<<N_NODES / 32,  256, 0, stream>>>(x, w1, b1, Ph, Qh);
  k_edgeconv<<<N_NODES / 32,  256, 0, stream>>>(Ph, Qh, w2, b2, knn, h);
  k_hw      <<<N_NODES / 32,  256, 0, stream>>>(h, gw, hwh);
  k_heads   <<<N_NODES / 32,  256, 0, stream>>>(hwh, knn, gb, gow, gob, ow, obv, out);
}

// Round 10
// 332.629 us; speedup vs baseline: 1.8862x; 1.0505x over previous
//
#include <hip/hip_runtime.h>
#include <hip/hip_fp16.h>
#include <cfloat>
#include <cmath>
#include <string.h>

// GNN_Combo pipeline. Round 10: k_gemm subg writes batched to one 64-B
// burst/row (kills 6x write amplification seen in WRITE_SIZE=196MB);
// k_filter dots via v_dot2_f32_f16 (fdot2) -- 8 instr replace 16 cvt+16 fma.
// N=16384 nodes, F=64 in-features, H=128 hidden, K=16 neighbors, O=10 classes.

#define N_NODES 16384
#define F_IN    64
#define H_DIM   128
#define K_NN    16
#define O_DIM   10

typedef _Float16 half8  __attribute__((ext_vector_type(8)));
typedef _Float16 half4v __attribute__((ext_vector_type(4)));
typedef _Float16 half2v __attribute__((ext_vector_type(2)));
typedef __fp16   fp16x2 __attribute__((ext_vector_type(2)));
typedef float    floatx4 __attribute__((ext_vector_type(4)));

__device__ __forceinline__ void async_copy16(void* lds, const void* g) {
  __builtin_amdgcn_global_load_lds(
      (const __attribute__((address_space(1))) unsigned int*)g,
      (__attribute__((address_space(3))) unsigned int*)lds, 16, 0, 0);
}

__device__ __forceinline__ unsigned pack2h(float a, float b) {
  half2v p; p[0] = (_Float16)a; p[1] = (_Float16)b;
  unsigned u; __builtin_memcpy(&u, &p, 4); return u;
}
__device__ __forceinline__ float unpacklo(unsigned u) {
  half2v p; __builtin_memcpy(&p, &u, 4); return (float)p[0];
}
__device__ __forceinline__ float unpackhi(unsigned u) {
  half2v p; __builtin_memcpy(&p, &u, 4); return (float)p[1];
}
__device__ __forceinline__ fp16x2 as_h2(unsigned u) {
  fp16x2 p; __builtin_memcpy(&p, &u, 4); return p;
}

// ---------------------------------------------------------------- k_prep ----
__global__ __launch_bounds__(256) void k_prep(const float* __restrict__ x,
                                              float* __restrict__ sq,
                                              double* __restrict__ sq64,
                                              _Float16* __restrict__ xh,
                                              unsigned* __restrict__ cnt) {
  const int i = blockIdx.x * 256 + threadIdx.x;
  if (i >= N_NODES) return;
  const float4* r = (const float4*)(x + i * F_IN);
  float s = 0.f; double sd = 0.0;
#pragma unroll
  for (int q = 0; q < 16; ++q) {
    const float4 v = r[q];
    s += v.x*v.x + v.y*v.y + v.z*v.z + v.w*v.w;
    sd += (double)v.x*v.x + (double)v.y*v.y + (double)v.z*v.z + (double)v.w*v.w;
    half4v hv;
    hv[0] = (_Float16)v.x; hv[1] = (_Float16)v.y;
    hv[2] = (_Float16)v.z; hv[3] = (_Float16)v.w;
    *(half4v*)(xh + (size_t)i * F_IN + 4 * q) = hv;
  }
  sq[i] = s; sq64[i] = sd; cnt[i] = 0;
}

// ---------------------------------------------------------------- k_gemm ----
// Transposed MFMA (round 7b structure). Per-row submins for all 4 tiles are
// held in registers and written as ONE contiguous 64-B burst per row at the
// end -> full-line HBM writes (no read-modify-write amplification).
__global__ __launch_bounds__(256) void k_gemm(const _Float16* __restrict__ xh,
                                              const float* __restrict__ sq,
                                              char* __restrict__ subg) {
  __shared__ __align__(16) _Float16 stage[128 * 64];  // 16 KB, swizzled
  __shared__ float sqs[128];
  const int tid = threadIdx.x;
  const int wv = tid >> 6, l = tid & 63;
  const int lane16 = l & 15, quad = l >> 4;
  const int rowblk = (blockIdx.x >> 5) * 256;
  const int seg = blockIdx.x & 31;
  const int rw = rowblk + wv * 64;

  half8 B[4][2];
#pragma unroll
  for (int s = 0; s < 4; ++s) {
    const _Float16* bp = xh + (size_t)(rw + s * 16 + lane16) * F_IN + quad * 8;
    B[s][0] = *(const half8*)(bp);
    B[s][1] = *(const half8*)(bp + 32);
  }

  const int lcol8 = l >> 3;
  const int lchk  = (l & 7) ^ lcol8;
  const size_t lgoff = (size_t)lcol8 * F_IN + lchk * 8;

  unsigned sel[16];   // [tile*4 + pair] -- this lane's row (rowset=quad)

#pragma unroll
  for (int tile = 0; tile < 4; ++tile) {
    const int c0 = seg * 512 + tile * 128;
    __syncthreads();
    if (tid < 128) sqs[tid] = sq[c0 + tid];
#pragma unroll
    for (int q = 0; q < 4; ++q) {
      const int grp = wv * 4 + q;
      async_copy16(stage + grp * 512,
                   xh + (size_t)(c0 + grp * 8) * F_IN + lgoff);
    }
    __syncthreads();

    float sprev[4];
    unsigned pk[4][4];
#pragma unroll
    for (int st = 0; st < 8; ++st) {
      const _Float16* base = stage + (st * 16 + lane16) * 64;
      const int sw = lane16 & 7;
      const half8 A0 = *(const half8*)(base + ((quad ^ sw) * 8));
      const half8 A1 = *(const half8*)(base + (((4 + quad) ^ sw) * 8));
      const floatx4 sq4 = *(const floatx4*)(sqs + st * 16 + quad * 4);
      floatx4 acc[4];
#pragma unroll
      for (int s = 0; s < 4; ++s) acc[s] = (floatx4)0.f;
#pragma unroll
      for (int s = 0; s < 4; ++s)
        acc[s] = __builtin_amdgcn_mfma_f32_16x16x32_f16(A0, B[s][0], acc[s], 0, 0, 0);
#pragma unroll
      for (int s = 0; s < 4; ++s)
        acc[s] = __builtin_amdgcn_mfma_f32_16x16x32_f16(A1, B[s][1], acc[s], 0, 0, 0);
#pragma unroll
      for (int s = 0; s < 4; ++s) {
        const float k0 = fmaf(-2.f, acc[s][0], sq4[0]);
        const float k1 = fmaf(-2.f, acc[s][1], sq4[1]);
        const float k2 = fmaf(-2.f, acc[s][2], sq4[2]);
        const float k3 = fmaf(-2.f, acc[s][3], sq4[3]);
        float m = fminf(fminf(k0, k1), fminf(k2, k3));
        m = fminf(m, __shfl_xor(m, 16, 64));
        m = fminf(m, __shfl_xor(m, 32, 64));
        if ((st & 1) == 0) sprev[s] = m;
        else pk[s][st >> 1] = pack2h(sprev[s], m);
      }
    }
    // keep only this lane's rowset (quad) for the batched write
#pragma unroll
    for (int t = 0; t < 4; ++t) {
      unsigned o = pk[0][t];
      if (quad == 1) o = pk[1][t];
      if (quad == 2) o = pk[2][t];
      if (quad == 3) o = pk[3][t];
      sel[tile * 4 + t] = o;
    }
  }
  // one 64-B contiguous burst per row (4 x uint4, back-to-back)
  const int row = rw + quad * 16 + lane16;
  char* dst = subg + ((size_t)row * 1024 + seg * 32) * 2;
#pragma unroll
  for (int t = 0; t < 4; ++t) {
    uint4 ov; ov.x = sel[t*4+0]; ov.y = sel[t*4+1]; ov.z = sel[t*4+2]; ov.w = sel[t*4+3];
    *(uint4*)(dst + t * 16) = ov;
  }
}

// -------------------------------------------------------------- k_filter ----
// One wave per row; dots via v_dot2_f32_f16 (fdot2).
__global__ __launch_bounds__(256) void k_filter(const _Float16* __restrict__ xh,
                                                const float* __restrict__ sq,
                                                const char* __restrict__ subg,
                                                unsigned* __restrict__ cnt,
                                                int* __restrict__ cand) {
  const int l = threadIdx.x & 63;
  const int i = blockIdx.x * 4 + (threadIdx.x >> 6);
  const int part = l & 3, c = l >> 2;

  // xi fragment: dims [part*16, part*16+16) as 8 packed f16 pairs
  fp16x2 xi2[8];
  {
    const uint4* xp = (const uint4*)(xh + (size_t)i * F_IN + part * 16);
    const uint4 a = xp[0], b = xp[1];
    xi2[0] = as_h2(a.x); xi2[1] = as_h2(a.y); xi2[2] = as_h2(a.z); xi2[3] = as_h2(a.w);
    xi2[4] = as_h2(b.x); xi2[5] = as_h2(b.y); xi2[6] = as_h2(b.z); xi2[7] = as_h2(b.w);
  }
  float subs[16];
  {
    const uint4 a = *(const uint4*)(subg + ((size_t)i * 1024 + l * 16) * 2);
    const uint4 b = *(const uint4*)(subg + ((size_t)i * 1024 + l * 16) * 2 + 16);
    subs[0] = unpacklo(a.x); subs[1] = unpackhi(a.x);
    subs[2] = unpacklo(a.y); subs[3] = unpackhi(a.y);
    subs[4] = unpacklo(a.z); subs[5] = unpackhi(a.z);
    subs[6] = unpacklo(a.w); subs[7] = unpackhi(a.w);
    subs[8] = unpacklo(b.x); subs[9] = unpackhi(b.x);
    subs[10] = unpacklo(b.y); subs[11] = unpackhi(b.y);
    subs[12] = unpacklo(b.z); subs[13] = unpackhi(b.z);
    subs[14] = unpacklo(b.w); subs[15] = unpackhi(b.w);
  }
  float cmin = subs[0];
#pragma unroll
  for (int t = 1; t < 16; ++t) cmin = fminf(cmin, subs[t]);
  int rank = 0;
#pragma unroll 4
  for (int j = 0; j < 64; ++j) {
    const float vj = __shfl(cmin, j, 64);
    rank += (vj < cmin) || (vj == cmin && j < l);
  }
  const unsigned long long rm = __ballot(rank == 15);
  const int srcl = __ffsll((long long)rm) - 1;
  const float thr = __shfl(cmin, srcl, 64) + 0.25f;

  unsigned selmask = 0;
#pragma unroll
  for (int t = 0; t < 16; ++t) selmask |= (subs[t] <= thr) ? (1u << t) : 0u;

  unsigned long long act;
  while ((act = __ballot(selmask != 0)) != 0ull) {
    const int src = __ffsll((long long)act) - 1;
    unsigned m = __shfl(selmask, src, 64);
    if (l == src) selmask = 0;
    while (m) {
      const int b = __ffs(m) - 1; m &= m - 1;
      const int sid = src * 16 + b;
      const int cg = sid * 16 + c;
      float d = 0.f;
      {
        const uint4* gp = (const uint4*)(xh + (size_t)cg * F_IN + part * 16);
        const uint4 g0 = gp[0], g1 = gp[1];
        d = __builtin_amdgcn_fdot2(xi2[0], as_h2(g0.x), d, false);
        d = __builtin_amdgcn_fdot2(xi2[1], as_h2(g0.y), d, false);
        d = __builtin_amdgcn_fdot2(xi2[2], as_h2(g0.z), d, false);
        d = __builtin_amdgcn_fdot2(xi2[3], as_h2(g0.w), d, false);
        d = __builtin_amdgcn_fdot2(xi2[4], as_h2(g1.x), d, false);
        d = __builtin_amdgcn_fdot2(xi2[5], as_h2(g1.y), d, false);
        d = __builtin_amdgcn_fdot2(xi2[6], as_h2(g1.z), d, false);
        d = __builtin_amdgcn_fdot2(xi2[7], as_h2(g1.w), d, false);
      }
      d += __shfl_xor(d, 1, 64);
      d += __shfl_xor(d, 2, 64);
      const float key = fmaf(-2.f, d, sq[cg]);
      const bool pred = (part == 0) && (key <= thr);
      const unsigned long long am = __ballot(pred);
      if (am) {
        const int ldr = __ffsll((long long)am) - 1;
        unsigned base = 0;
        if (l == ldr) base = atomicAdd(&cnt[i], (unsigned)__popcll(am));
        base = __shfl(base, ldr, 64);
        if (pred) {
          const unsigned idx = base + (unsigned)__popcll(am & ((1ull << l) - 1ull));
          if (idx < 128u) cand[(size_t)i * 128 + idx] = cg;
        }
      }
    }
  }
}

// ------------------------------------------------------------- k_rescore ----
__global__ __launch_bounds__(128) void k_rescore(const float* __restrict__ x,
                                                 const double* __restrict__ sq64,
                                                 const int* __restrict__ cand,
                                                 const unsigned* __restrict__ cnt,
                                                 int* __restrict__ knn) {
  __shared__ float  xi[F_IN];
  __shared__ double keys[128];
  __shared__ int    ids[128];
  const int i = blockIdx.x, t = threadIdx.x;
  const unsigned cv = cnt[i];
  const int n = (int)(cv < 128u ? cv : 128u);
  if (t < F_IN) xi[t] = x[i * F_IN + t];
  __syncthreads();
  double key = 1e300; int id = 0x7fffffff;
  if (t < n) {
    id = cand[(size_t)i * 128 + t];
    const float4* xc4 = (const float4*)(x + (size_t)id * F_IN);
    double d0 = 0.0, d1 = 0.0, d2 = 0.0, d3 = 0.0;
#pragma unroll
    for (int q = 0; q < 16; ++q) {
      const float4 v = xc4[q];
      d0 += (double)xi[4*q+0] * (double)v.x;
      d1 += (double)xi[4*q+1] * (double)v.y;
      d2 += (double)xi[4*q+2] * (double)v.z;
      d3 += (double)xi[4*q+3] * (double)v.w;
    }
    key = sq64[id] - 2.0 * ((d0 + d1) + (d2 + d3));
  }
  keys[t] = key; ids[t] = id;
  __syncthreads();
  int rank = 0;
  for (int cix = 0; cix < n; ++cix) {
    const double kc = keys[cix]; const int ic = ids[cix];
    rank += (kc < key) || (kc == key && ic < id);
  }
  if (t < n && rank < K_NN) knn[i * K_NN + rank] = id;
}

// --------------------------------------------------------------- k_lin12 ----
__global__ __launch_bounds__(256, 2) void k_lin12(const float* __restrict__ x,
                                                  const float* __restrict__ w1,
                                                  const float* __restrict__ b1,
                                                  _Float16* __restrict__ Ph,
                                                  _Float16* __restrict__ Qh) {
  __shared__ float wl[2 * F_IN][H_DIM];   // 64 KB
  for (int s = threadIdx.x; s < 2 * F_IN * H_DIM; s += 256) wl[s >> 7][s & 127] = w1[s];
  __syncthreads();
  const int node = blockIdx.x * 32 + (threadIdx.x & 31);
  const int ob = (threadIdx.x >> 5) * 16;
  float accR[16], accQ[16];
#pragma unroll
  for (int o = 0; o < 16; ++o) { accR[o] = 0.f; accQ[o] = 0.f; }
  const float4* xr = (const float4*)(x + node * F_IN);
#define L1STEP(ff, xs) { \
    const float* wt_ = &wl[(ff)][ob]; \
    const float* wb_ = &wl[(ff) + F_IN][ob]; \
    _Pragma("unroll") \
    for (int o = 0; o < 16; o += 4) { \
      const float4 t4 = *(const float4*)(wt_ + o); \
      const float4 b4 = *(const float4*)(wb_ + o); \
      accR[o+0] = fmaf((xs), t4.x, accR[o+0]); accQ[o+0] = fmaf((xs), b4.x, accQ[o+0]); \
      accR[o+1] = fmaf((xs), t4.y, accR[o+1]); accQ[o+1] = fmaf((xs), b4.y, accQ[o+1]); \
      accR[o+2] = fmaf((xs), t4.z, accR[o+2]); accQ[o+2] = fmaf((xs), b4.z, accQ[o+2]); \
      accR[o+3] = fmaf((xs), t4.w, accR[o+3]); accQ[o+3] = fmaf((xs), b4.w, accQ[o+3]); } }
#pragma unroll 2
  for (int q = 0; q < 16; ++q) {
    const float4 xv = xr[q];
    L1STEP(4*q+0, xv.x); L1STEP(4*q+1, xv.y); L1STEP(4*q+2, xv.z); L1STEP(4*q+3, xv.w);
  }
#undef L1STEP
  _Float16* pp = Ph + (size_t)node * H_DIM + ob;
  _Float16* qp = Qh + (size_t)node * H_DIM + ob;
#pragma unroll
  for (int o = 0; o < 16; o += 4) {
    half4v hp, hq;
#pragma unroll
    for (int u = 0; u < 4; ++u) {
      hp[u] = (_Float16)(accR[o+u] - accQ[o+u] + b1[ob + o + u]);
      hq[u] = (_Float16)accQ[o+u];
    }
    *(half4v*)(pp + o) = hp;
    *(half4v*)(qp + o) = hq;
  }
}

// ------------------------------------------------------------ k_edgeconv ----
__global__ __launch_bounds__(256, 2) void k_edgeconv(const _Float16* __restrict__ Ph,
                                                     const _Float16* __restrict__ Qh,
                                                     const float* __restrict__ w2,
                                                     const float* __restrict__ b2,
                                                     const int* __restrict__ knn,
                                                     float* __restrict__ h) {
  __shared__ __align__(16) _Float16 wt[H_DIM * 128];   // 32 KB, swizzled
  __shared__ __align__(16) _Float16 afr[4][2048];      // 16 KB, per-wave A frags
  const int tid = threadIdx.x;
  const int wv = tid >> 6, l = tid & 63;
  const int lane16 = l & 15, quad = l >> 4;

  {
    const int n = tid >> 1, part = tid & 1;
    const float* wsrc = w2 + n;
    _Float16* wdst = wt + n * 128;
#pragma unroll
    for (int c = 0; c < 8; ++c) {
      half8 hv;
#pragma unroll
      for (int u = 0; u < 8; ++u)
        hv[u] = (_Float16)wsrc[(size_t)(part * 64 + c * 8 + u) * H_DIM];
      *(half8*)(wdst + (((part * 8 + c) ^ (n & 15)) * 8)) = hv;
    }
  }
  __syncthreads();

  float b2r[8];
#pragma unroll
  for (int tile = 0; tile < 8; ++tile) b2r[tile] = b2[tile * 16 + lane16];

  const int i0 = blockIdx.x * 32 + wv * 8;
  int js[8];
#pragma unroll
  for (int it = 0; it < 8; ++it) js[it] = knn[(i0 + it) * K_NN + lane16];

  _Float16* aw = afr[wv];
  half8 pc[4], qc[4];
  {
    const half8* pr = (const half8*)(Ph + (size_t)i0 * H_DIM + quad * 32);
    const half8* qr = (const half8*)(Qh + (size_t)js[0] * H_DIM + quad * 32);
#pragma unroll
    for (int c = 0; c < 4; ++c) { pc[c] = pr[c]; qc[c] = qr[c]; }
  }
  for (int it = 0; it < 8; ++it) {
    const int i = i0 + it;
    half8 pn[4], qn[4];
    if (it < 7) {
      const half8* pr = (const half8*)(Ph + (size_t)(i + 1) * H_DIM + quad * 32);
      const half8* qr = (const half8*)(Qh + (size_t)js[it + 1] * H_DIM + quad * 32);
#pragma unroll
      for (int c = 0; c < 4; ++c) { pn[c] = pr[c]; qn[c] = qr[c]; }
    }
#pragma unroll
    for (int c = 0; c < 4; ++c) {
      half8 z = pc[c] + qc[c];
      half8 r;
#pragma unroll
      for (int u = 0; u < 8; ++u) r[u] = z[u] > (_Float16)0 ? z[u] : (_Float16)0;
      *(half8*)(aw + quad * 512 + c * 128 + lane16 * 8) = r;
    }
    half8 A[4];
#pragma unroll
    for (int kb = 0; kb < 4; ++kb) A[kb] = *(const half8*)(aw + kb * 512 + l * 8);
    floatx4 acc[8];
#pragma unroll
    for (int tile = 0; tile < 8; ++tile) acc[tile] = (floatx4)0.f;
#pragma unroll
    for (int kb = 0; kb < 4; ++kb) {
#pragma unroll
      for (int tile = 0; tile < 8; ++tile) {
        const half8 B = *(const half8*)(wt + (tile * 16 + lane16) * 128 +
                                        (((kb * 4 + quad) ^ lane16) * 8));
        acc[tile] = __builtin_amdgcn_mfma_f32_16x16x32_f16(A[kb], B, acc[tile], 0, 0, 0);
      }
    }
    float lse[4];
#pragma unroll
    for (int r = 0; r < 4; ++r) {
      float mx = acc[0][r] + b2r[0];
#pragma unroll
      for (int tile = 1; tile < 8; ++tile) mx = fmaxf(mx, acc[tile][r] + b2r[tile]);
      mx = fmaxf(mx, __shfl_xor(mx, 1, 64));
      mx = fmaxf(mx, __shfl_xor(mx, 2, 64));
      mx = fmaxf(mx, __shfl_xor(mx, 4, 64));
      mx = fmaxf(mx, __shfl_xor(mx, 8, 64));
      float e = 0.f;
#pragma unroll
      for (int tile = 0; tile < 8; ++tile) e += __expf(acc[tile][r] + b2r[tile] - mx);
      e += __shfl_xor(e, 1, 64);
      e += __shfl_xor(e, 2, 64);
      e += __shfl_xor(e, 4, 64);
      e += __shfl_xor(e, 8, 64);
      lse[r] = mx + __logf(e);
    }
#pragma unroll
    for (int tile = 0; tile < 8; ++tile) {
      float v = acc[tile][0] + b2r[tile] - lse[0];
#pragma unroll
      for (int r = 1; r < 4; ++r) v = fmaxf(v, acc[tile][r] + b2r[tile] - lse[r]);
      v = fmaxf(v, __shfl_xor(v, 16, 64));
      v = fmaxf(v, __shfl_xor(v, 32, 64));
      if (quad == 0) h[(size_t)i * H_DIM + tile * 16 + lane16] = v;
    }
#pragma unroll
    for (int c = 0; c < 4; ++c) { pc[c] = pn[c]; qc[c] = qn[c]; }
  }
}

// ----------------------------------------------------------------- k_hw -----
__global__ __launch_bounds__(256) void k_hw(const float* __restrict__ h,
                                            const float* __restrict__ gw,
                                            _Float16* __restrict__ hwh) {
  __shared__ float wl[H_DIM][H_DIM];   // 64 KB
  for (int s = threadIdx.x; s < H_DIM * H_DIM; s += 256) wl[s >> 7][s & 127] = gw[s];
  __syncthreads();
  const int node = blockIdx.x * 32 + (threadIdx.x & 31);
  const int ob = (threadIdx.x >> 5) * 16;
  float acc[16];
#pragma unroll
  for (int o = 0; o < 16; ++o) acc[o] = 0.f;
  const float4* hr = (const float4*)(h + node * H_DIM);
#define HWSTEP(ff, xs) { \
    const float* wr = &wl[(ff)][ob]; \
    _Pragma("unroll") \
    for (int o = 0; o < 16; o += 4) { const float4 w4 = *(const float4*)(wr + o); \
      acc[o+0] = fmaf((xs), w4.x, acc[o+0]); \
      acc[o+1] = fmaf((xs), w4.y, acc[o+1]); \
      acc[o+2] = fmaf((xs), w4.z, acc[o+2]); \
      acc[o+3] = fmaf((xs), w4.w, acc[o+3]); } }
#pragma unroll 2
  for (int q = 0; q < 32; ++q) {
    const float4 hv = hr[q];
    HWSTEP(4*q+0, hv.x); HWSTEP(4*q+1, hv.y); HWSTEP(4*q+2, hv.z); HWSTEP(4*q+3, hv.w);
  }
#undef HWSTEP
  _Float16* dp = hwh + (size_t)node * H_DIM + ob;
#pragma unroll
  for (int o = 0; o < 16; o += 4) {
    half4v hv;
#pragma unroll
    for (int u = 0; u < 4; ++u) hv[u] = (_Float16)acc[o + u];
    *(half4v*)(dp + o) = hv;
  }
}

// --------------------------------------------------------------- k_heads ----
__global__ __launch_bounds__(256) void k_heads(const _Float16* __restrict__ hwh,
                                               const int* __restrict__ knn,
                                               const float* __restrict__ gb,
                                               const float* __restrict__ gow,
                                               const float* __restrict__ gob,
                                               const float* __restrict__ ow,
                                               const float* __restrict__ obv,
                                               float* __restrict__ out) {
  __shared__ unsigned int wgo[H_DIM][64];  // 32 KB: (gow[f][2l], gow[f][2l+1]) f16
  __shared__ float hbuf[4][H_DIM];         // 2 KB
  for (int s = threadIdx.x; s < H_DIM * 64; s += 256) {
    const int f = s >> 6, l = s & 63;
    wgo[f][l] = pack2h(gow[f * H_DIM + 2 * l], gow[f * H_DIM + 2 * l + 1]);
  }
  __syncthreads();
  const int wv = threadIdx.x >> 6, l = threadIdx.x & 63;
  const unsigned* hw32 = (const unsigned*)hwh;   // row = 64 uints
  const float gbl = gb[2 * l], gbh = gb[2 * l + 1];
  const float gobl = gob[2 * l], gobh = gob[2 * l + 1];
  for (int it = 0; it < 8; ++it) {
    const int i = blockIdx.x * 32 + wv * 8 + it;
    const int* kr = knn + i * K_NN;
    unsigned u = hw32[(size_t)i * 64 + l];       // self-loop
    float s0 = unpacklo(u), s1 = unpackhi(u);
#pragma unroll
    for (int m = 0; m < K_NN; ++m) {
      const unsigned um = hw32[(size_t)kr[m] * 64 + l];
      s0 += unpacklo(um);
      s1 += unpackhi(um);
    }
    const float hg0 = s0 * (1.0f / 17.0f) + gbl;   // deg == 17 by construction
    const float hg1 = s1 * (1.0f / 17.0f) + gbh;
    hbuf[wv][2 * l] = hg0; hbuf[wv][2 * l + 1] = hg1;
    float z0 = gobl, z1 = gobh;
#pragma unroll 4
    for (int f = 0; f < H_DIM; ++f) {
      const float hv = hbuf[wv][f];
      const unsigned int wvv = wgo[f][l];
      z0 = fmaf(hv, unpacklo(wvv), z0);
      z1 = fmaf(hv, unpackhi(wvv), z1);
    }
    float mx = fmaxf(z0, z1);
#pragma unroll
    for (int s = 1; s < 64; s <<= 1) mx = fmaxf(mx, __shfl_xor(mx, s, 64));
    const float e0 = __expf(z0 - mx), e1 = __expf(z1 - mx);
    float sm = e0 + e1;
#pragma unroll
    for (int s = 1; s < 64; s <<= 1) sm += __shfl_xor(sm, s, 64);
    const float h20 = e0 / sm, h21 = e1 / sm;
    float zc[O_DIM];
#pragma unroll
    for (int c = 0; c < O_DIM; ++c) {
      float a = h20 * ow[(2 * l) * O_DIM + c] + h21 * ow[(2 * l + 1) * O_DIM + c];
#pragma unroll
      for (int s = 1; s < 64; s <<= 1) a += __shfl_xor(a, s, 64);
      zc[c] = a + obv[c];
    }
    float m10 = zc[0];
#pragma unroll
    for (int c = 1; c < O_DIM; ++c) m10 = fmaxf(m10, zc[c]);
    float es[O_DIM]; float s10 = 0.f;
#pragma unroll
    for (int c = 0; c < O_DIM; ++c) { es[c] = __expf(zc[c] - m10); s10 += es[c]; }
    const float inv = 1.0f / s10;
    if (l < O_DIM) {
      float v = es[0];
#pragma unroll
      for (int c = 1; c < O_DIM; ++c) if (l == c) v = es[c];
      out[i * O_DIM + l] = v * inv;
    }
  }
}

// ---------------------------------------------------------------------------
extern "C" void kernel_launch(void* const* d_in, const int* in_sizes, int n_in,
                              void* d_out, int out_size, void* d_ws, size_t ws_size,
                              hipStream_t stream) {
  (void)in_sizes; (void)n_in; (void)out_size; (void)ws_size;
  const float* x   = (const float*)d_in[0];
  const float* w1  = (const float*)d_in[2];
  const float* b1  = (const float*)d_in[3];
  const float* w2  = (const float*)d_in[4];
  const float* b2  = (const float*)d_in[5];
  const float* gw  = (const float*)d_in[6];
  const float* gb  = (const float*)d_in[7];
  const float* gow = (const float*)d_in[8];
  const float* gob = (const float*)d_in[9];
  const float* ow  = (const float*)d_in[10];
  const float* obv = (const float*)d_in[11];
  float* out = (float*)d_out;

  char* ws = (char*)d_ws;
  constexpr size_t MB = 1024 * 1024;
  constexpr size_t OFF_SQ   = 0;                                          // 64 KB
  constexpr size_t OFF_SQ64 = OFF_SQ   + (size_t)N_NODES * 4;             // 128 KB
  constexpr size_t OFF_XH   = OFF_SQ64 + (size_t)N_NODES * 8;             // 2 MB
  constexpr size_t OFF_CNT  = OFF_XH   + (size_t)N_NODES * F_IN * 2;      // 64 KB
  constexpr size_t OFF_CAND = OFF_CNT  + (size_t)N_NODES * 4;             // 8 MB
  constexpr size_t OFF_SUBG = OFF_CAND + (size_t)N_NODES * 128 * 4;       // 32 MB
  constexpr size_t OFF_KNN  = OFF_SUBG;                                   // 1 MB
  constexpr size_t OFF_H    = OFF_SUBG + 1 * MB;                          // 8 MB f32
  constexpr size_t OFF_HWH  = OFF_SUBG + 9 * MB;                          // 4 MB f16
  float*     sq   = (float*)    (ws + OFF_SQ);
  double*    sq64 = (double*)   (ws + OFF_SQ64);
  _Float16*  xh   = (_Float16*) (ws + OFF_XH);
  unsigned*  cnt  = (unsigned*) (ws + OFF_CNT);
  int*       cand = (int*)      (ws + OFF_CAND);
  char*      subg = (char*)     (ws + OFF_SUBG);
  int*       knn  = (int*)      (ws + OFF_KNN);
  float*     h    = (float*)    (ws + OFF_H);
  _Float16*  hwh  = (_Float16*) (ws + OFF_HWH);
  _Float16*  Ph   = (_Float16*) (ws + OFF_CAND);
  _Float16*  Qh   = (_Float16*) (ws + OFF_CAND + 4 * MB);

  k_prep    <<<N_NODES / 256, 256, 0, stream>>>(x, sq, sq64, xh, cnt);
  k_gemm    <<<2048,          256, 0, stream>>>(xh, sq, subg);
  k_filter  <<<N_NODES / 4,   256, 0, stream>>>(xh, sq, subg, cnt, cand);
  k_rescore <<<N_NODES,       128, 0, stream>>>(x, sq64, cand, cnt, knn);
  k_lin12   <<<N_NODES / 32,  256, 0, stream>>>(x, w1, b1, Ph, Qh);
  k_edgeconv<<<N_NODES / 32,  256, 0, stream>>>(Ph, Qh, w2, b2, knn, h);
  k_hw      <<<N_NODES / 32,  256, 0, stream>>>(h, gw, hwh);
  k_heads   <<<N_NODES / 32,  256, 0, stream>>>(hwh, knn, gb, gow, gob, ow, obv, out);
}

// Round 11
// 331.549 us; speedup vs baseline: 1.8923x; 1.0033x over previous
//
#include <hip/hip_runtime.h>
#include <hip/hip_fp16.h>
#include <cfloat>
#include <cmath>
#include <string.h>

// GNN_Combo pipeline. Round 11: subg layout [seg][row][64B]; k_gemm writes
// transposed through LDS so every store INSTRUCTION is lane-contiguous
// (round 10 showed L2 does not merge 16-B stores: WRITE = #stores x 64 B).
// N=16384 nodes, F=64 in-features, H=128 hidden, K=16 neighbors, O=10 classes.

#define N_NODES 16384
#define F_IN    64
#define H_DIM   128
#define K_NN    16
#define O_DIM   10

typedef _Float16 half8  __attribute__((ext_vector_type(8)));
typedef _Float16 half4v __attribute__((ext_vector_type(4)));
typedef _Float16 half2v __attribute__((ext_vector_type(2)));
typedef __fp16   fp16x2 __attribute__((ext_vector_type(2)));
typedef float    floatx4 __attribute__((ext_vector_type(4)));

__device__ __forceinline__ void async_copy16(void* lds, const void* g) {
  __builtin_amdgcn_global_load_lds(
      (const __attribute__((address_space(1))) unsigned int*)g,
      (__attribute__((address_space(3))) unsigned int*)lds, 16, 0, 0);
}

__device__ __forceinline__ unsigned pack2h(float a, float b) {
  half2v p; p[0] = (_Float16)a; p[1] = (_Float16)b;
  unsigned u; __builtin_memcpy(&u, &p, 4); return u;
}
__device__ __forceinline__ float unpacklo(unsigned u) {
  half2v p; __builtin_memcpy(&p, &u, 4); return (float)p[0];
}
__device__ __forceinline__ float unpackhi(unsigned u) {
  half2v p; __builtin_memcpy(&p, &u, 4); return (float)p[1];
}
__device__ __forceinline__ fp16x2 as_h2(unsigned u) {
  fp16x2 p; __builtin_memcpy(&p, &u, 4); return p;
}

// ---------------------------------------------------------------- k_prep ----
__global__ __launch_bounds__(256) void k_prep(const float* __restrict__ x,
                                              float* __restrict__ sq,
                                              double* __restrict__ sq64,
                                              _Float16* __restrict__ xh,
                                              unsigned* __restrict__ cnt) {
  const int i = blockIdx.x * 256 + threadIdx.x;
  if (i >= N_NODES) return;
  const float4* r = (const float4*)(x + i * F_IN);
  float s = 0.f; double sd = 0.0;
#pragma unroll
  for (int q = 0; q < 16; ++q) {
    const float4 v = r[q];
    s += v.x*v.x + v.y*v.y + v.z*v.z + v.w*v.w;
    sd += (double)v.x*v.x + (double)v.y*v.y + (double)v.z*v.z + (double)v.w*v.w;
    half4v hv;
    hv[0] = (_Float16)v.x; hv[1] = (_Float16)v.y;
    hv[2] = (_Float16)v.z; hv[3] = (_Float16)v.w;
    *(half4v*)(xh + (size_t)i * F_IN + 4 * q) = hv;
  }
  sq[i] = s; sq64[i] = sd; cnt[i] = 0;
}

// ---------------------------------------------------------------- k_gemm ----
// Transposed MFMA. Output subg[seg][row][32 f16]: each wave owns rows
// [rw, rw+64) of one seg -> a contiguous 4-KB span. Submins are bounced
// through LDS scratch (sc[k*64 + lane], lane == local row) so each of the 4
// dwordx4 store instructions writes a lane-contiguous 1-KB slice.
__global__ __launch_bounds__(256) void k_gemm(const _Float16* __restrict__ xh,
                                              const float* __restrict__ sq,
                                              char* __restrict__ subg) {
  __shared__ __align__(16) _Float16 stage[128 * 64];  // 16 KB: tiles, then scratch
  __shared__ float sqs[128];
  const int tid = threadIdx.x;
  const int wv = tid >> 6, l = tid & 63;
  const int lane16 = l & 15, quad = l >> 4;
  const int rowblk = (blockIdx.x >> 5) * 256;
  const int seg = blockIdx.x & 31;
  const int rw = rowblk + wv * 64;

  half8 B[4][2];
#pragma unroll
  for (int s = 0; s < 4; ++s) {
    const _Float16* bp = xh + (size_t)(rw + s * 16 + lane16) * F_IN + quad * 8;
    B[s][0] = *(const half8*)(bp);
    B[s][1] = *(const half8*)(bp + 32);
  }

  const int lcol8 = l >> 3;
  const int lchk  = (l & 7) ^ lcol8;
  const size_t lgoff = (size_t)lcol8 * F_IN + lchk * 8;

  unsigned sel[16];   // [tile*4 + pair] -- this lane's row (r_local == l)

#pragma unroll
  for (int tile = 0; tile < 4; ++tile) {
    const int c0 = seg * 512 + tile * 128;
    __syncthreads();
    if (tid < 128) sqs[tid] = sq[c0 + tid];
#pragma unroll
    for (int q = 0; q < 4; ++q) {
      const int grp = wv * 4 + q;
      async_copy16(stage + grp * 512,
                   xh + (size_t)(c0 + grp * 8) * F_IN + lgoff);
    }
    __syncthreads();

    float sprev[4];
    unsigned pk[4][4];
#pragma unroll
    for (int st = 0; st < 8; ++st) {
      const _Float16* base = stage + (st * 16 + lane16) * 64;
      const int sw = lane16 & 7;
      const half8 A0 = *(const half8*)(base + ((quad ^ sw) * 8));
      const half8 A1 = *(const half8*)(base + (((4 + quad) ^ sw) * 8));
      const floatx4 sq4 = *(const floatx4*)(sqs + st * 16 + quad * 4);
      floatx4 acc[4];
#pragma unroll
      for (int s = 0; s < 4; ++s) acc[s] = (floatx4)0.f;
#pragma unroll
      for (int s = 0; s < 4; ++s)
        acc[s] = __builtin_amdgcn_mfma_f32_16x16x32_f16(A0, B[s][0], acc[s], 0, 0, 0);
#pragma unroll
      for (int s = 0; s < 4; ++s)
        acc[s] = __builtin_amdgcn_mfma_f32_16x16x32_f16(A1, B[s][1], acc[s], 0, 0, 0);
#pragma unroll
      for (int s = 0; s < 4; ++s) {
        const float k0 = fmaf(-2.f, acc[s][0], sq4[0]);
        const float k1 = fmaf(-2.f, acc[s][1], sq4[1]);
        const float k2 = fmaf(-2.f, acc[s][2], sq4[2]);
        const float k3 = fmaf(-2.f, acc[s][3], sq4[3]);
        float m = fminf(fminf(k0, k1), fminf(k2, k3));
        m = fminf(m, __shfl_xor(m, 16, 64));
        m = fminf(m, __shfl_xor(m, 32, 64));
        if ((st & 1) == 0) sprev[s] = m;
        else pk[s][st >> 1] = pack2h(sprev[s], m);
      }
    }
#pragma unroll
    for (int t = 0; t < 4; ++t) {
      unsigned o = pk[0][t];
      if (quad == 1) o = pk[1][t];
      if (quad == 2) o = pk[2][t];
      if (quad == 3) o = pk[3][t];
      sel[tile * 4 + t] = o;
    }
  }
  // ---- LDS transpose -> 4 lane-contiguous 1-KB store instructions ----
  __syncthreads();   // all waves done reading stage tiles
  {
    unsigned* sc = (unsigned*)stage + wv * 1024;   // 4 KB per wave
#pragma unroll
    for (int k = 0; k < 16; ++k) sc[k * 64 + l] = sel[k];   // conflict-free
    char* dstw = subg + ((size_t)seg * N_NODES + rw) * 64;
#pragma unroll
    for (int t = 0; t < 4; ++t) {
      const int rl = t * 16 + (l >> 2);
      uint4 ov;
      ov.x = sc[((l & 3) * 4 + 0) * 64 + rl];
      ov.y = sc[((l & 3) * 4 + 1) * 64 + rl];
      ov.z = sc[((l & 3) * 4 + 2) * 64 + rl];
      ov.w = sc[((l & 3) * 4 + 3) * 64 + rl];
      *(uint4*)(dstw + t * 1024 + l * 16) = ov;
    }
  }
}

// -------------------------------------------------------------- k_filter ----
// One wave per row; dots via v_dot2_f32_f16 (fdot2). subg layout [seg][row][64B].
__global__ __launch_bounds__(256) void k_filter(const _Float16* __restrict__ xh,
                                                const float* __restrict__ sq,
                                                const char* __restrict__ subg,
                                                unsigned* __restrict__ cnt,
                                                int* __restrict__ cand) {
  const int l = threadIdx.x & 63;
  const int i = blockIdx.x * 4 + (threadIdx.x >> 6);
  const int part = l & 3, c = l >> 2;

  fp16x2 xi2[8];
  {
    const uint4* xp = (const uint4*)(xh + (size_t)i * F_IN + part * 16);
    const uint4 a = xp[0], b = xp[1];
    xi2[0] = as_h2(a.x); xi2[1] = as_h2(a.y); xi2[2] = as_h2(a.z); xi2[3] = as_h2(a.w);
    xi2[4] = as_h2(b.x); xi2[5] = as_h2(b.y); xi2[6] = as_h2(b.z); xi2[7] = as_h2(b.w);
  }
  float subs[16];
  {
    const char* sp = subg + ((size_t)(l >> 1) * N_NODES + i) * 64 + (l & 1) * 32;
    const uint4 a = *(const uint4*)(sp);
    const uint4 b = *(const uint4*)(sp + 16);
    subs[0] = unpacklo(a.x); subs[1] = unpackhi(a.x);
    subs[2] = unpacklo(a.y); subs[3] = unpackhi(a.y);
    subs[4] = unpacklo(a.z); subs[5] = unpackhi(a.z);
    subs[6] = unpacklo(a.w); subs[7] = unpackhi(a.w);
    subs[8] = unpacklo(b.x); subs[9] = unpackhi(b.x);
    subs[10] = unpacklo(b.y); subs[11] = unpackhi(b.y);
    subs[12] = unpacklo(b.z); subs[13] = unpackhi(b.z);
    subs[14] = unpacklo(b.w); subs[15] = unpackhi(b.w);
  }
  float cmin = subs[0];
#pragma unroll
  for (int t = 1; t < 16; ++t) cmin = fminf(cmin, subs[t]);
  int rank = 0;
#pragma unroll 4
  for (int j = 0; j < 64; ++j) {
    const float vj = __shfl(cmin, j, 64);
    rank += (vj < cmin) || (vj == cmin && j < l);
  }
  const unsigned long long rm = __ballot(rank == 15);
  const int srcl = __ffsll((long long)rm) - 1;
  const float thr = __shfl(cmin, srcl, 64) + 0.25f;

  unsigned selmask = 0;
#pragma unroll
  for (int t = 0; t < 16; ++t) selmask |= (subs[t] <= thr) ? (1u << t) : 0u;

  unsigned long long act;
  while ((act = __ballot(selmask != 0)) != 0ull) {
    const int src = __ffsll((long long)act) - 1;
    unsigned m = __shfl(selmask, src, 64);
    if (l == src) selmask = 0;
    while (m) {
      const int b = __ffs(m) - 1; m &= m - 1;
      const int sid = src * 16 + b;
      const int cg = sid * 16 + c;
      float d = 0.f;
      {
        const uint4* gp = (const uint4*)(xh + (size_t)cg * F_IN + part * 16);
        const uint4 g0 = gp[0], g1 = gp[1];
        d = __builtin_amdgcn_fdot2(xi2[0], as_h2(g0.x), d, false);
        d = __builtin_amdgcn_fdot2(xi2[1], as_h2(g0.y), d, false);
        d = __builtin_amdgcn_fdot2(xi2[2], as_h2(g0.z), d, false);
        d = __builtin_amdgcn_fdot2(xi2[3], as_h2(g0.w), d, false);
        d = __builtin_amdgcn_fdot2(xi2[4], as_h2(g1.x), d, false);
        d = __builtin_amdgcn_fdot2(xi2[5], as_h2(g1.y), d, false);
        d = __builtin_amdgcn_fdot2(xi2[6], as_h2(g1.z), d, false);
        d = __builtin_amdgcn_fdot2(xi2[7], as_h2(g1.w), d, false);
      }
      d += __shfl_xor(d, 1, 64);
      d += __shfl_xor(d, 2, 64);
      const float key = fmaf(-2.f, d, sq[cg]);
      const bool pred = (part == 0) && (key <= thr);
      const unsigned long long am = __ballot(pred);
      if (am) {
        const int ldr = __ffsll((long long)am) - 1;
        unsigned base = 0;
        if (l == ldr) base = atomicAdd(&cnt[i], (unsigned)__popcll(am));
        base = __shfl(base, ldr, 64);
        if (pred) {
          const unsigned idx = base + (unsigned)__popcll(am & ((1ull << l) - 1ull));
          if (idx < 128u) cand[(size_t)i * 128 + idx] = cg;
        }
      }
    }
  }
}

// ------------------------------------------------------------- k_rescore ----
__global__ __launch_bounds__(128) void k_rescore(const float* __restrict__ x,
                                                 const double* __restrict__ sq64,
                                                 const int* __restrict__ cand,
                                                 const unsigned* __restrict__ cnt,
                                                 int* __restrict__ knn) {
  __shared__ float  xi[F_IN];
  __shared__ double keys[128];
  __shared__ int    ids[128];
  const int i = blockIdx.x, t = threadIdx.x;
  const unsigned cv = cnt[i];
  const int n = (int)(cv < 128u ? cv : 128u);
  if (t < F_IN) xi[t] = x[i * F_IN + t];
  __syncthreads();
  double key = 1e300; int id = 0x7fffffff;
  if (t < n) {
    id = cand[(size_t)i * 128 + t];
    const float4* xc4 = (const float4*)(x + (size_t)id * F_IN);
    double d0 = 0.0, d1 = 0.0, d2 = 0.0, d3 = 0.0;
#pragma unroll
    for (int q = 0; q < 16; ++q) {
      const float4 v = xc4[q];
      d0 += (double)xi[4*q+0] * (double)v.x;
      d1 += (double)xi[4*q+1] * (double)v.y;
      d2 += (double)xi[4*q+2] * (double)v.z;
      d3 += (double)xi[4*q+3] * (double)v.w;
    }
    key = sq64[id] - 2.0 * ((d0 + d1) + (d2 + d3));
  }
  keys[t] = key; ids[t] = id;
  __syncthreads();
  int rank = 0;
  for (int cix = 0; cix < n; ++cix) {
    const double kc = keys[cix]; const int ic = ids[cix];
    rank += (kc < key) || (kc == key && ic < id);
  }
  if (t < n && rank < K_NN) knn[i * K_NN + rank] = id;
}

// --------------------------------------------------------------- k_lin12 ----
__global__ __launch_bounds__(256, 2) void k_lin12(const float* __restrict__ x,
                                                  const float* __restrict__ w1,
                                                  const float* __restrict__ b1,
                                                  _Float16* __restrict__ Ph,
                                                  _Float16* __restrict__ Qh) {
  __shared__ float wl[2 * F_IN][H_DIM];   // 64 KB
  for (int s = threadIdx.x; s < 2 * F_IN * H_DIM; s += 256) wl[s >> 7][s & 127] = w1[s];
  __syncthreads();
  const int node = blockIdx.x * 32 + (threadIdx.x & 31);
  const int ob = (threadIdx.x >> 5) * 16;
  float accR[16], accQ[16];
#pragma unroll
  for (int o = 0; o < 16; ++o) { accR[o] = 0.f; accQ[o] = 0.f; }
  const float4* xr = (const float4*)(x + node * F_IN);
#define L1STEP(ff, xs) { \
    const float* wt_ = &wl[(ff)][ob]; \
    const float* wb_ = &wl[(ff) + F_IN][ob]; \
    _Pragma("unroll") \
    for (int o = 0; o < 16; o += 4) { \
      const float4 t4 = *(const float4*)(wt_ + o); \
      const float4 b4 = *(const float4*)(wb_ + o); \
      accR[o+0] = fmaf((xs), t4.x, accR[o+0]); accQ[o+0] = fmaf((xs), b4.x, accQ[o+0]); \
      accR[o+1] = fmaf((xs), t4.y, accR[o+1]); accQ[o+1] = fmaf((xs), b4.y, accQ[o+1]); \
      accR[o+2] = fmaf((xs), t4.z, accR[o+2]); accQ[o+2] = fmaf((xs), b4.z, accQ[o+2]); \
      accR[o+3] = fmaf((xs), t4.w, accR[o+3]); accQ[o+3] = fmaf((xs), b4.w, accQ[o+3]); } }
#pragma unroll 2
  for (int q = 0; q < 16; ++q) {
    const float4 xv = xr[q];
    L1STEP(4*q+0, xv.x); L1STEP(4*q+1, xv.y); L1STEP(4*q+2, xv.z); L1STEP(4*q+3, xv.w);
  }
#undef L1STEP
  _Float16* pp = Ph + (size_t)node * H_DIM + ob;
  _Float16* qp = Qh + (size_t)node * H_DIM + ob;
#pragma unroll
  for (int o = 0; o < 16; o += 4) {
    half4v hp, hq;
#pragma unroll
    for (int u = 0; u < 4; ++u) {
      hp[u] = (_Float16)(accR[o+u] - accQ[o+u] + b1[ob + o + u]);
      hq[u] = (_Float16)accQ[o+u];
    }
    *(half4v*)(pp + o) = hp;
    *(half4v*)(qp + o) = hq;
  }
}

// ------------------------------------------------------------ k_edgeconv ----
__global__ __launch_bounds__(256, 2) void k_edgeconv(const _Float16* __restrict__ Ph,
                                                     const _Float16* __restrict__ Qh,
                                                     const float* __restrict__ w2,
                                                     const float* __restrict__ b2,
                                                     const int* __restrict__ knn,
                                                     float* __restrict__ h) {
  __shared__ __align__(16) _Float16 wt[H_DIM * 128];   // 32 KB, swizzled
  __shared__ __align__(16) _Float16 afr[4][2048];      // 16 KB, per-wave A frags
  const int tid = threadIdx.x;
  const int wv = tid >> 6, l = tid & 63;
  const int lane16 = l & 15, quad = l >> 4;

  {
    const int n = tid >> 1, part = tid & 1;
    const float* wsrc = w2 + n;
    _Float16* wdst = wt + n * 128;
#pragma unroll
    for (int c = 0; c < 8; ++c) {
      half8 hv;
#pragma unroll
      for (int u = 0; u < 8; ++u)
        hv[u] = (_Float16)wsrc[(size_t)(part * 64 + c * 8 + u) * H_DIM];
      *(half8*)(wdst + (((part * 8 + c) ^ (n & 15)) * 8)) = hv;
    }
  }
  __syncthreads();

  float b2r[8];
#pragma unroll
  for (int tile = 0; tile < 8; ++tile) b2r[tile] = b2[tile * 16 + lane16];

  const int i0 = blockIdx.x * 32 + wv * 8;
  int js[8];
#pragma unroll
  for (int it = 0; it < 8; ++it) js[it] = knn[(i0 + it) * K_NN + lane16];

  _Float16* aw = afr[wv];
  half8 pc[4], qc[4];
  {
    const half8* pr = (const half8*)(Ph + (size_t)i0 * H_DIM + quad * 32);
    const half8* qr = (const half8*)(Qh + (size_t)js[0] * H_DIM + quad * 32);
#pragma unroll
    for (int c = 0; c < 4; ++c) { pc[c] = pr[c]; qc[c] = qr[c]; }
  }
  for (int it = 0; it < 8; ++it) {
    const int i = i0 + it;
    half8 pn[4], qn[4];
    if (it < 7) {
      const half8* pr = (const half8*)(Ph + (size_t)(i + 1) * H_DIM + quad * 32);
      const half8* qr = (const half8*)(Qh + (size_t)js[it + 1] * H_DIM + quad * 32);
#pragma unroll
      for (int c = 0; c < 4; ++c) { pn[c] = pr[c]; qn[c] = qr[c]; }
    }
#pragma unroll
    for (int c = 0; c < 4; ++c) {
      half8 z = pc[c] + qc[c];
      half8 r;
#pragma unroll
      for (int u = 0; u < 8; ++u) r[u] = z[u] > (_Float16)0 ? z[u] : (_Float16)0;
      *(half8*)(aw + quad * 512 + c * 128 + lane16 * 8) = r;
    }
    half8 A[4];
#pragma unroll
    for (int kb = 0; kb < 4; ++kb) A[kb] = *(const half8*)(aw + kb * 512 + l * 8);
    floatx4 acc[8];
#pragma unroll
    for (int tile = 0; tile < 8; ++tile) acc[tile] = (floatx4)0.f;
#pragma unroll
    for (int kb = 0; kb < 4; ++kb) {
#pragma unroll
      for (int tile = 0; tile < 8; ++tile) {
        const half8 B = *(const half8*)(wt + (tile * 16 + lane16) * 128 +
                                        (((kb * 4 + quad) ^ lane16) * 8));
        acc[tile] = __builtin_amdgcn_mfma_f32_16x16x32_f16(A[kb], B, acc[tile], 0, 0, 0);
      }
    }
    float lse[4];
#pragma unroll
    for (int r = 0; r < 4; ++r) {
      float mx = acc[0][r] + b2r[0];
#pragma unroll
      for (int tile = 1; tile < 8; ++tile) mx = fmaxf(mx, acc[tile][r] + b2r[tile]);
      mx = fmaxf(mx, __shfl_xor(mx, 1, 64));
      mx = fmaxf(mx, __shfl_xor(mx, 2, 64));
      mx = fmaxf(mx, __shfl_xor(mx, 4, 64));
      mx = fmaxf(mx, __shfl_xor(mx, 8, 64));
      float e = 0.f;
#pragma unroll
      for (int tile = 0; tile < 8; ++tile) e += __expf(acc[tile][r] + b2r[tile] - mx);
      e += __shfl_xor(e, 1, 64);
      e += __shfl_xor(e, 2, 64);
      e += __shfl_xor(e, 4, 64);
      e += __shfl_xor(e, 8, 64);
      lse[r] = mx + __logf(e);
    }
#pragma unroll
    for (int tile = 0; tile < 8; ++tile) {
      float v = acc[tile][0] + b2r[tile] - lse[0];
#pragma unroll
      for (int r = 1; r < 4; ++r) v = fmaxf(v, acc[tile][r] + b2r[tile] - lse[r]);
      v = fmaxf(v, __shfl_xor(v, 16, 64));
      v = fmaxf(v, __shfl_xor(v, 32, 64));
      if (quad == 0) h[(size_t)i * H_DIM + tile * 16 + lane16] = v;
    }
#pragma unroll
    for (int c = 0; c < 4; ++c) { pc[c] = pn[c]; qc[c] = qn[c]; }
  }
}

// ----------------------------------------------------------------- k_hw -----
__global__ __launch_bounds__(256) void k_hw(const float* __restrict__ h,
                                            const float* __restrict__ gw,
                                            _Float16* __restrict__ hwh) {
  __shared__ float wl[H_DIM][H_DIM];   // 64 KB
  for (int s = threadIdx.x; s < H_DIM * H_DIM; s += 256) wl[s >> 7][s & 127] = gw[s];
  __syncthreads();
  const int node = blockIdx.x * 32 + (threadIdx.x & 31);
  const int ob = (threadIdx.x >> 5) * 16;
  float acc[16];
#pragma unroll
  for (int o = 0; o < 16; ++o) acc[o] = 0.f;
  const float4* hr = (const float4*)(h + node * H_DIM);
#define HWSTEP(ff, xs) { \
    const float* wr = &wl[(ff)][ob]; \
    _Pragma("unroll") \
    for (int o = 0; o < 16; o += 4) { const float4 w4 = *(const float4*)(wr + o); \
      acc[o+0] = fmaf((xs), w4.x, acc[o+0]); \
      acc[o+1] = fmaf((xs), w4.y, acc[o+1]); \
      acc[o+2] = fmaf((xs), w4.z, acc[o+2]); \
      acc[o+3] = fmaf((xs), w4.w, acc[o+3]); } }
#pragma unroll 2
  for (int q = 0; q < 32; ++q) {
    const float4 hv = hr[q];
    HWSTEP(4*q+0, hv.x); HWSTEP(4*q+1, hv.y); HWSTEP(4*q+2, hv.z); HWSTEP(4*q+3, hv.w);
  }
#undef HWSTEP
  _Float16* dp = hwh + (size_t)node * H_DIM + ob;
#pragma unroll
  for (int o = 0; o < 16; o += 4) {
    half4v hv;
#pragma unroll
    for (int u = 0; u < 4; ++u) hv[u] = (_Float16)acc[o + u];
    *(half4v*)(dp + o) = hv;
  }
}

// --------------------------------------------------------------- k_heads ----
__global__ __launch_bounds__(256) void k_heads(const _Float16* __restrict__ hwh,
                                               const int* __restrict__ knn,
                                               const float* __restrict__ gb,
                                               const float* __restrict__ gow,
                                               const float* __restrict__ gob,
                                               const float* __restrict__ ow,
                                               const float* __restrict__ obv,
                                               float* __restrict__ out) {
  __shared__ unsigned int wgo[H_DIM][64];  // 32 KB
  __shared__ float hbuf[4][H_DIM];         // 2 KB
  for (int s = threadIdx.x; s < H_DIM * 64; s += 256) {
    const int f = s >> 6, l = s & 63;
    wgo[f][l] = pack2h(gow[f * H_DIM + 2 * l], gow[f * H_DIM + 2 * l + 1]);
  }
  __syncthreads();
  const int wv = threadIdx.x >> 6, l = threadIdx.x & 63;
  const unsigned* hw32 = (const unsigned*)hwh;
  const float gbl = gb[2 * l], gbh = gb[2 * l + 1];
  const float gobl = gob[2 * l], gobh = gob[2 * l + 1];
  for (int it = 0; it < 8; ++it) {
    const int i = blockIdx.x * 32 + wv * 8 + it;
    const int* kr = knn + i * K_NN;
    unsigned u = hw32[(size_t)i * 64 + l];
    float s0 = unpacklo(u), s1 = unpackhi(u);
#pragma unroll
    for (int m = 0; m < K_NN; ++m) {
      const unsigned um = hw32[(size_t)kr[m] * 64 + l];
      s0 += unpacklo(um);
      s1 += unpackhi(um);
    }
    const float hg0 = s0 * (1.0f / 17.0f) + gbl;
    const float hg1 = s1 * (1.0f / 17.0f) + gbh;
    hbuf[wv][2 * l] = hg0; hbuf[wv][2 * l + 1] = hg1;
    float z0 = gobl, z1 = gobh;
#pragma unroll 4
    for (int f = 0; f < H_DIM; ++f) {
      const float hv = hbuf[wv][f];
      const unsigned int wvv = wgo[f][l];
      z0 = fmaf(hv, unpacklo(wvv), z0);
      z1 = fmaf(hv, unpackhi(wvv), z1);
    }
    float mx = fmaxf(z0, z1);
#pragma unroll
    for (int s = 1; s < 64; s <<= 1) mx = fmaxf(mx, __shfl_xor(mx, s, 64));
    const float e0 = __expf(z0 - mx), e1 = __expf(z1 - mx);
    float sm = e0 + e1;
#pragma unroll
    for (int s = 1; s < 64; s <<= 1) sm += __shfl_xor(sm, s, 64);
    const float h20 = e0 / sm, h21 = e1 / sm;
    float zc[O_DIM];
#pragma unroll
    for (int c = 0; c < O_DIM; ++c) {
      float a = h20 * ow[(2 * l) * O_DIM + c] + h21 * ow[(2 * l + 1) * O_DIM + c];
#pragma unroll
      for (int s = 1; s < 64; s <<= 1) a += __shfl_xor(a, s, 64);
      zc[c] = a + obv[c];
    }
    float m10 = zc[0];
#pragma unroll
    for (int c = 1; c < O_DIM; ++c) m10 = fmaxf(m10, zc[c]);
    float es[O_DIM]; float s10 = 0.f;
#pragma unroll
    for (int c = 0; c < O_DIM; ++c) { es[c] = __expf(zc[c] - m10); s10 += es[c]; }
    const float inv = 1.0f / s10;
    if (l < O_DIM) {
      float v = es[0];
#pragma unroll
      for (int c = 1; c < O_DIM; ++c) if (l == c) v = es[c];
      out[i * O_DIM + l] = v * inv;
    }
  }
}

// ---------------------------------------------------------------------------
extern "C" void kernel_launch(void* const* d_in, const int* in_sizes, int n_in,
                              void* d_out, int out_size, void* d_ws, size_t ws_size,
                              hipStream_t stream) {
  (void)in_sizes; (void)n_in; (void)out_size; (void)ws_size;
  const float* x   = (const float*)d_in[0];
  const float* w1  = (const float*)d_in[2];
  const float* b1  = (const float*)d_in[3];
  const float* w2  = (const float*)d_in[4];
  const float* b2  = (const float*)d_in[5];
  const float* gw  = (const float*)d_in[6];
  const float* gb  = (const float*)d_in[7];
  const float* gow = (const float*)d_in[8];
  const float* gob = (const float*)d_in[9];
  const float* ow  = (const float*)d_in[10];
  const float* obv = (const float*)d_in[11];
  float* out = (float*)d_out;

  char* ws = (char*)d_ws;
  constexpr size_t MB = 1024 * 1024;
  constexpr size_t OFF_SQ   = 0;                                          // 64 KB
  constexpr size_t OFF_SQ64 = OFF_SQ   + (size_t)N_NODES * 4;             // 128 KB
  constexpr size_t OFF_XH   = OFF_SQ64 + (size_t)N_NODES * 8;             // 2 MB
  constexpr size_t OFF_CNT  = OFF_XH   + (size_t)N_NODES * F_IN * 2;      // 64 KB
  constexpr size_t OFF_CAND = OFF_CNT  + (size_t)N_NODES * 4;             // 8 MB
  constexpr size_t OFF_SUBG = OFF_CAND + (size_t)N_NODES * 128 * 4;       // 32 MB
  constexpr size_t OFF_KNN  = OFF_SUBG;                                   // 1 MB
  constexpr size_t OFF_H    = OFF_SUBG + 1 * MB;                          // 8 MB f32
  constexpr size_t OFF_HWH  = OFF_SUBG + 9 * MB;                          // 4 MB f16
  float*     sq   = (float*)    (ws + OFF_SQ);
  double*    sq64 = (double*)   (ws + OFF_SQ64);
  _Float16*  xh   = (_Float16*) (ws + OFF_XH);
  unsigned*  cnt  = (unsigned*) (ws + OFF_CNT);
  int*       cand = (int*)      (ws + OFF_CAND);
  char*      subg = (char*)     (ws + OFF_SUBG);
  int*       knn  = (int*)      (ws + OFF_KNN);
  float*     h    = (float*)    (ws + OFF_H);
  _Float16*  hwh  = (_Float16*) (ws + OFF_HWH);
  _Float16*  Ph   = (_Float16*) (ws + OFF_CAND);
  _Float16*  Qh   = (_Float16*) (ws + OFF_CAND + 4 * MB);

  k_prep    <<<N_NODES / 256, 256, 0, stream>>>(x, sq, sq64, xh, cnt);
  k_gemm    <<<2048,          256, 0, stream>>>(xh, sq, subg);
  k_filter  <<<N_NODES / 4,   256, 0, stream>>>(xh, sq, subg, cnt, cand);
  k_rescore <<<N_NODES,       128, 0, stream>>>(x, sq64, cand, cnt, knn);
  k_lin12   <<<N_NODES / 32,  256, 0, stream>>>(x, w1, b1, Ph, Qh);
  k_edgeconv<<<N_NODES / 32,  256, 0, stream>>>(Ph, Qh, w2, b2, knn, h);
  k_hw      <<<N_NODES / 32,  256, 0, stream>>>(h, gw, hwh);
  k_heads   <<<N_NODES / 32,  256, 0, stream>>>(hwh, knn, gb, gow, gob, ow, obv, out);
}